// Round 10
// baseline (458.968 us; speedup 1.0000x reference)
//
#include <hip/hip_runtime.h>
#include <hip/hip_bf16.h>
#include <math.h>

typedef __attribute__((ext_vector_type(8))) short short8;
typedef __attribute__((ext_vector_type(4))) float floatx4;
typedef unsigned short ushortT;

__device__ inline short f2bf(float v) {
    __hip_bfloat16 h = __float2bfloat16(v);
    union { __hip_bfloat16 h; short s; } u; u.h = h; return u.s;
}

// ---------------- workspace layout (bytes), all disjoint ----------------
#define OFF_C2    0
#define OFF_PAD4  8388608
#define OFF_FICH  12849152
#define OFF_PAD2  21237760
#define OFF_PAD3  29890560
#define OFF_WP2   32120832
#define OFF_WP3   32194560
#define OFF_WP4   32342016
#define OFF_DS    32636928
#define OFF_IT    33161216
#define OFF_ST    33947648
#define OFF_AC    33949696

#define PAD2_BYTES 8652800
#define PAD3_BYTES 2230272
#define PAD4_BYTES 4460544

// ---------------- conv1: fp32 direct (Cin=3), writes bf16 NHWC padded --------
__global__ __launch_bounds__(256) void conv1_bf16(
    const float* __restrict__ in, const float* __restrict__ w,
    const float* __restrict__ b, short* __restrict__ outp)
{
    int bid = blockIdx.x;                 // 4n x 8ocg x 8ty x 8tx
    int txt = bid & 7; bid >>= 3;
    int tyt = bid & 7; bid >>= 3;
    int ocg = bid & 7; bid >>= 3;
    int n = bid;
    int x0 = txt * 16, y0 = tyt * 16;
    int tid = threadIdx.x;
    int tx = tid & 15, ty = tid >> 4;

    __shared__ float lds[3 * 720];
    for (int i = tid; i < 972; i += 256) {
        int cc = i / 324; int rem = i - cc * 324;
        int r = rem / 18, c = rem - r * 18;
        int y = y0 - 1 + r, x = x0 - 1 + c;
        float v = 0.f;
        if ((unsigned)y < 128u && (unsigned)x < 128u)
            v = in[((size_t)(n * 3 + cc) * 128 + y) * 128 + x];
        lds[cc * 720 + r * 40 + c] = v;
    }
    __syncthreads();

    float acc[8];
#pragma unroll
    for (int oc = 0; oc < 8; ++oc) acc[oc] = 0.f;
    const float* w_g = w + (size_t)(ocg * 8) * 27;
#pragma unroll
    for (int cc = 0; cc < 3; ++cc) {
        const float* base = &lds[cc * 720 + ty * 40 + tx];
        float i00 = base[0],  i01 = base[1],  i02 = base[2];
        float i10 = base[40], i11 = base[41], i12 = base[42];
        float i20 = base[80], i21 = base[81], i22 = base[82];
        const float* wp = w_g + cc * 9;
#pragma unroll
        for (int oc = 0; oc < 8; ++oc) {
            const float* wq = wp + oc * 27;
            float a = acc[oc];
            a = fmaf(wq[0], i00, a); a = fmaf(wq[1], i01, a); a = fmaf(wq[2], i02, a);
            a = fmaf(wq[3], i10, a); a = fmaf(wq[4], i11, a); a = fmaf(wq[5], i12, a);
            a = fmaf(wq[6], i20, a); a = fmaf(wq[7], i21, a); a = fmaf(wq[8], i22, a);
            acc[oc] = a;
        }
    }
    int oy = y0 + ty, ox = x0 + tx;
    short* o = outp + ((size_t)(n * 130 + oy + 1) * 130 + ox + 1) * 64 + ocg * 8;
#pragma unroll
    for (int oc = 0; oc < 8; ++oc) {
        float v = fmaxf(acc[oc] + b[ocg * 8 + oc], 0.f);
        o[oc] = f2bf(v);
    }
}

// ---------------- weight prepack into MFMA B-fragment order ------------------
__global__ void prepack_w(const float* __restrict__ w, short* __restrict__ wp,
                          int CIN, int NTALL, int total)
{
    int e = blockIdx.x * 256 + threadIdx.x;
    if (e >= total) return;
    int j = e & 7; int L = (e >> 3) & 63; int rest = e >> 9;
    int nt = rest % NTALL; int rest2 = rest / NTALL;
    int KT = CIN / 32;
    int kt = rest2 % KT; int t = rest2 / KT;
    int oc = nt * 16 + (L & 15);
    int ci = kt * 32 + (L >> 4) * 8 + j;
    wp[e] = f2bf(w[((size_t)oc * CIN + ci) * 9 + t]);
}

// ---------------- MFMA implicit-GEMM 3x3 conv --------------------------------
template<int CIN, int COUT, int H, int W, int OUTMODE>
__global__ __launch_bounds__(256) void conv_mfma(
    const short* __restrict__ inp, const short* __restrict__ wp,
    const float* __restrict__ bias, void* __restrict__ outv)
{
    constexpr int KT = CIN / 32;
    constexpr int NTALL = COUT / 16;
    constexpr int NTB = COUT / 64;
    constexpr int TPR = W / 32;
    constexpr int Hp = H + 2, Wp = W + 2;

    int bm = blockIdx.x / NTB;
    int bn = blockIdx.x - bm * NTB;
    int n = bm / (H * TPR);
    int rem = bm - n * (H * TPR);
    int y = rem / TPR;
    int x0 = (rem - y * TPR) * 32;

    int tid = threadIdx.x;
    int wv = tid >> 6, lane = tid & 63;
    int lm = lane & 15, q = lane >> 4;
    int px0 = x0 + 16 * (wv & 1);
    int ntb = bn * 4 + (wv >> 1) * 2;

    floatx4 acc0 = {0.f, 0.f, 0.f, 0.f};
    floatx4 acc1 = {0.f, 0.f, 0.f, 0.f};

    const short* a_m = inp + lm * CIN + q * 8;
    const short* wbase = wp + ((size_t)ntb * 64 + lane) * 8;

    for (int kt = 0; kt < KT; ++kt) {
        int kofs = kt * 32;
#pragma unroll
        for (int r = 0; r < 3; ++r) {
            const short* arow = a_m + (size_t)((n * Hp + y + r) * Wp + px0) * CIN + kofs;
#pragma unroll
            for (int s = 0; s < 3; ++s) {
                short8 av = *(const short8*)(arow + s * CIN);
                const short* bp = wbase + (size_t)(((r * 3 + s) * KT + kt) * NTALL) * 512;
                short8 b0 = *(const short8*)bp;
                short8 b1 = *(const short8*)(bp + 512);
                acc0 = __builtin_amdgcn_mfma_f32_16x16x32_bf16(av, b0, acc0, 0, 0, 0);
                acc1 = __builtin_amdgcn_mfma_f32_16x16x32_bf16(av, b1, acc1, 0, 0, 0);
            }
        }
    }

#pragma unroll
    for (int half = 0; half < 2; ++half) {
        floatx4 a = half ? acc1 : acc0;
        int oc = (ntb + half) * 16 + lm;
        float bs = bias[oc];
#pragma unroll
        for (int i = 0; i < 4; ++i) {
            int px = px0 + q * 4 + i;
            float v = fmaxf(a[i] + bs, 0.f);
            if constexpr (OUTMODE == 0) {
                ((short*)outv)[((size_t)(n * H + y) * W + px) * COUT + oc] = f2bf(v);
            } else if constexpr (OUTMODE == 1) {
                ((short*)outv)[((size_t)(n * Hp + y + 1) * Wp + px + 1) * COUT + oc] = f2bf(v);
            } else {
                ((float*)outv)[((size_t)(n * H + y) * W + px) * COUT + oc] = v;
            }
        }
    }
}

// ---------------- 2x2 maxpool, bf16 NHWC -> padded NHWC ----------------------
__global__ __launch_bounds__(256) void maxpool_nhwc(const ushortT* __restrict__ in,
                                                    ushortT* __restrict__ outp)
{
    int gid = blockIdx.x * 256 + threadIdx.x;   // 131072 = 4*64*64*8
    int c8 = gid & 7; int rest = gid >> 3;
    int xo = rest & 63, yo = (rest >> 6) & 63, n = rest >> 12;
    const ushortT* p = in + ((size_t)(n * 128 + yo * 2) * 128 + xo * 2) * 64 + c8 * 8;
    const ushortT* p01 = p + 64;
    const ushortT* p10 = p + 128 * 64;
    const ushortT* p11 = p10 + 64;
    ushortT* o = outp + ((size_t)(n * 66 + yo + 1) * 66 + xo + 1) * 64 + c8 * 8;
#pragma unroll
    for (int j = 0; j < 8; ++j) {
        ushortT a = p[j] > p01[j] ? p[j] : p01[j];
        ushortT b = p10[j] > p11[j] ? p10[j] : p11[j];
        o[j] = a > b ? a : b;
    }
}

// ---------------- BN over NHWC fich ----------------
__global__ __launch_bounds__(256) void bnsum_nhwc(const float* __restrict__ x,
                                                  float* __restrict__ sums)
{
    int c = threadIdx.x & 127;
    int h = threadIdx.x >> 7;
    int p0 = blockIdx.x * 64 + h * 32;
    float s = 0.f, s2 = 0.f;
    for (int p = p0; p < p0 + 32; ++p) {
        float v = x[(size_t)p * 128 + c];
        s += v; s2 = fmaf(v, v, s2);
    }
    atomicAdd(&sums[c], s);
    atomicAdd(&sums[128 + c], s2);
}

__global__ void stats_fin(const float* __restrict__ sums, float* __restrict__ st)
{
    int c = threadIdx.x;   // 128
    float mean = sums[c] * (1.f / 16384.f);
    float var = sums[128 + c] * (1.f / 16384.f) - mean * mean;
    st[c] = 1.f / sqrtf(var + 1e-5f);
}

__global__ __launch_bounds__(256) void scale_fich(float* __restrict__ x,
                                                  const float* __restrict__ st)
{
    int i = blockIdx.x * 256 + threadIdx.x;    // 524288 float4s
    float4 v = ((float4*)x)[i];
    int c0 = (i * 4) & 127;
    v.x *= st[c0]; v.y *= st[c0 + 1]; v.z *= st[c0 + 2]; v.w *= st[c0 + 3];
    ((float4*)x)[i] = v;
}

// ---------------- image-branch prep ----------------
__global__ __launch_bounds__(256) void avgpool2_k(const float* __restrict__ in,
                                                  float* __restrict__ out, int total)
{
    int tid = blockIdx.x * 256 + threadIdx.x;
    if (tid >= total) return;
    int wo = tid & 63, ho = (tid >> 6) & 63, ch = tid >> 12;
    const float* p = in + (size_t)ch * 16384 + (size_t)(ho * 2) * 128 + wo * 2;
    out[tid] = 0.25f * ((p[0] + p[1]) + (p[128] + p[129]));
}

__global__ __launch_bounds__(256) void bn_stats_k(const float* __restrict__ x,
                                                  float* __restrict__ stats,
                                                  int C, int HW, int N)
{
    int c = blockIdx.x, tid = threadIdx.x;
    int M = N * HW;
    double s = 0.0, s2 = 0.0;
    for (int i = tid; i < M; i += 256) {
        int n = i / HW, r = i - n * HW;
        float v = x[((size_t)(n * C + c)) * HW + r];
        s += v;
        s2 += (double)v * (double)v;
    }
    __shared__ double ls[256], ls2[256];
    ls[tid] = s; ls2[tid] = s2;
    __syncthreads();
    for (int st = 128; st > 0; st >>= 1) {
        if (tid < st) { ls[tid] += ls[tid + st]; ls2[tid] += ls2[tid + st]; }
        __syncthreads();
    }
    if (tid == 0) {
        double mean = ls[0] / M;
        double var = ls2[0] / M - mean * mean;
        stats[c] = (float)mean;
        stats[C + c] = (float)(1.0 / sqrt(var + 1e-5));
    }
}

__global__ __launch_bounds__(256) void norm_transpose_i_k(
    const float* __restrict__ x, const float* __restrict__ stats,
    float* __restrict__ it)
{
    int tid = blockIdx.x * 256 + threadIdx.x;   // 65536
    int n = tid >> 14;
    int hw = tid & 16383;
#pragma unroll
    for (int c = 0; c < 3; ++c) {
        float v = x[(((size_t)n * 3 + c) << 14) + hw];
        it[(size_t)tid * 3 + c] = (v - stats[c]) * stats[3 + c];
    }
}

__global__ void zero_k(float* acc)
{
    acc[threadIdx.x] = 0.f;    // 512 threads
}

// ---------------- modularity on VGG features ----------------
__global__ __launch_bounds__(64) void modularity64_v2(
    const float* __restrict__ xt,   // (4,64,64,128) scaled
    const float* __restrict__ seg,  // (4,8,64,64)
    float* __restrict__ acc)
{
    __shared__ float fl[12][12][20];
    __shared__ float sl[8][12][14];

    int t = threadIdx.x;
    int tx = t & 7, ty = t >> 3;
    int bid = blockIdx.x;
    int bx = bid & 7; bid >>= 3;
    int by = bid & 7; bid >>= 3;
    int n = bid;
    int x0 = bx * 8, y0 = by * 8;

    for (int i = t; i < 8 * 144; i += 64) {
        int k = i / 144;
        int rem = i - k * 144;
        int r = rem / 12, c = rem - r * 12;
        int y = y0 - 2 + r, x = x0 - 2 + c;
        float v = 0.f;
        if ((unsigned)y < 64u && (unsigned)x < 64u)
            v = seg[((size_t)(n * 8 + k) * 64 + y) * 64 + x];
        sl[k][r][c] = v;
    }

    float d2p[25];
#pragma unroll
    for (int di = 0; di < 5; ++di)
#pragma unroll
        for (int dj = 0; dj < 5; ++dj) {
            int y2 = y0 + ty + di - 2, x2 = x0 + tx + dj - 2;
            d2p[di * 5 + dj] = ((unsigned)y2 < 64u && (unsigned)x2 < 64u) ? 0.f : 1e30f;
        }

    for (int ch0 = 0; ch0 < 128; ch0 += 16) {
        __syncthreads();
        for (int i = t; i < 576; i += 64) {
            int pix = i >> 2, qq = i & 3;
            int r = pix / 12, c = pix - r * 12;
            int y = y0 - 2 + r, x = x0 - 2 + c;
            float4 v = make_float4(0.f, 0.f, 0.f, 0.f);
            if ((unsigned)y < 64u && (unsigned)x < 64u)
                v = *(const float4*)&xt[((size_t)((n * 64 + y) * 64 + x)) * 128 + ch0 + qq * 4];
            *(float4*)&fl[r][c][qq * 4] = v;
        }
        __syncthreads();

        float4 c0 = *(const float4*)&fl[ty + 2][tx + 2][0];
        float4 c1 = *(const float4*)&fl[ty + 2][tx + 2][4];
        float4 c2 = *(const float4*)&fl[ty + 2][tx + 2][8];
        float4 c3 = *(const float4*)&fl[ty + 2][tx + 2][12];
#pragma unroll
        for (int di = 0; di < 5; ++di)
#pragma unroll
            for (int dj = 0; dj < 5; ++dj) {
                const float* np = &fl[ty + di][tx + dj][0];
                float4 v0 = *(const float4*)(np + 0);
                float4 v1 = *(const float4*)(np + 4);
                float4 v2 = *(const float4*)(np + 8);
                float4 v3 = *(const float4*)(np + 12);
                float d = d2p[di * 5 + dj];
                float e;
                e = c0.x - v0.x; d = fmaf(e, e, d);
                e = c0.y - v0.y; d = fmaf(e, e, d);
                e = c0.z - v0.z; d = fmaf(e, e, d);
                e = c0.w - v0.w; d = fmaf(e, e, d);
                e = c1.x - v1.x; d = fmaf(e, e, d);
                e = c1.y - v1.y; d = fmaf(e, e, d);
                e = c1.z - v1.z; d = fmaf(e, e, d);
                e = c1.w - v1.w; d = fmaf(e, e, d);
                e = c2.x - v2.x; d = fmaf(e, e, d);
                e = c2.y - v2.y; d = fmaf(e, e, d);
                e = c2.z - v2.z; d = fmaf(e, e, d);
                e = c2.w - v2.w; d = fmaf(e, e, d);
                e = c3.x - v3.x; d = fmaf(e, e, d);
                e = c3.y - v3.y; d = fmaf(e, e, d);
                e = c3.z - v3.z; d = fmaf(e, e, d);
                e = c3.w - v3.w; d = fmaf(e, e, d);
                d2p[di * 5 + dj] = d;
            }
    }

    const float minus_inv2s2 = -1.0f / (2.0f * 0.02f * 0.02f);
    float wgt[25];
    float w1 = 0.f;
#pragma unroll
    for (int j = 0; j < 25; ++j) {
        wgt[j] = expf(d2p[j] * minus_inv2s2);
        w1 += wgt[j];
    }

#pragma unroll
    for (int k = 0; k < 8; ++k) {
        float s = 0.f;
#pragma unroll
        for (int di = 0; di < 5; ++di)
#pragma unroll
            for (int dj = 0; dj < 5; ++dj)
                s = fmaf(wgt[di * 5 + dj], sl[k][ty + di][tx + dj], s);
        float sc = sl[k][ty + 2][tx + 2];
        float numk = s * sc;
        float denk = w1 * sc;
#pragma unroll
        for (int sft = 32; sft > 0; sft >>= 1) {
            numk += __shfl_xor(numk, sft, 64);
            denk += __shfl_xor(denk, sft, 64);
        }
        if (t == 0) {
            atomicAdd(&acc[n * 8 + k], numk);
            atomicAdd(&acc[32 + n * 8 + k], denk);
        }
    }
}

// ---------------- modularity on images (v2: LDS-staged, 8x8 tile/64 thr) -----
__global__ __launch_bounds__(64) void modularity128_v2(
    const float* __restrict__ it,   // (4,128,128,3) normalized
    const float* __restrict__ seg,  // (4,8,128,128)
    float* __restrict__ acc)        // [64..95] num, [96..127] den
{
    __shared__ float il[12][12][4];    // 3 used + 1 pad
    __shared__ float sl[8][12][14];    // 12 used + 2 pad

    int t = threadIdx.x;
    int tx = t & 7, ty = t >> 3;
    int bid = blockIdx.x;              // n(4) x by(16) x bx(16)
    int bx = bid & 15; bid >>= 4;
    int by = bid & 15; bid >>= 4;
    int n = bid;
    int x0 = bx * 8, y0 = by * 8;

    // stage it tile (zero halo)
    for (int i = t; i < 144; i += 64) {
        int r = i / 12, c = i - r * 12;
        int y = y0 - 2 + r, x = x0 - 2 + c;
        float3 v = make_float3(0.f, 0.f, 0.f);
        if ((unsigned)y < 128u && (unsigned)x < 128u) {
            const float* p = it + ((size_t)((n * 128 + y) * 128 + x)) * 3;
            v.x = p[0]; v.y = p[1]; v.z = p[2];
        }
        il[r][c][0] = v.x; il[r][c][1] = v.y; il[r][c][2] = v.z;
    }
    // stage seg tile (zero halo)
    for (int i = t; i < 8 * 144; i += 64) {
        int k = i / 144;
        int rem = i - k * 144;
        int r = rem / 12, c = rem - r * 12;
        int y = y0 - 2 + r, x = x0 - 2 + c;
        float v = 0.f;
        if ((unsigned)y < 128u && (unsigned)x < 128u)
            v = seg[((size_t)(n * 8 + k) * 128 + y) * 128 + x];
        sl[k][r][c] = v;
    }
    __syncthreads();

    const float minus_inv2s2 = -1.0f / (2.0f * 0.2f * 0.2f); // -12.5
    float c0 = il[ty + 2][tx + 2][0];
    float c1 = il[ty + 2][tx + 2][1];
    float c2 = il[ty + 2][tx + 2][2];

    float wgt[25];
    float w1 = 0.f;
#pragma unroll
    for (int di = 0; di < 5; ++di)
#pragma unroll
        for (int dj = 0; dj < 5; ++dj) {
            int y2 = y0 + ty + di - 2, x2 = x0 + tx + dj - 2;
            float bias = ((unsigned)y2 < 128u && (unsigned)x2 < 128u) ? 0.f : 1e30f;
            const float* np = &il[ty + di][tx + dj][0];
            float e0 = c0 - np[0], e1 = c1 - np[1], e2 = c2 - np[2];
            float d = bias + fmaf(e2, e2, fmaf(e1, e1, e0 * e0));
            float wv = expf(d * minus_inv2s2);
            wgt[di * 5 + dj] = wv;
            w1 += wv;
        }

#pragma unroll
    for (int k = 0; k < 8; ++k) {
        float s = 0.f;
#pragma unroll
        for (int di = 0; di < 5; ++di)
#pragma unroll
            for (int dj = 0; dj < 5; ++dj)
                s = fmaf(wgt[di * 5 + dj], sl[k][ty + di][tx + dj], s);
        float sc = sl[k][ty + 2][tx + 2];
        float numk = s * sc;
        float denk = w1 * sc;
#pragma unroll
        for (int sft = 32; sft > 0; sft >>= 1) {
            numk += __shfl_xor(numk, sft, 64);
            denk += __shfl_xor(denk, sft, 64);
        }
        if (t == 0) {
            atomicAdd(&acc[64 + n * 8 + k], numk);
            atomicAdd(&acc[96 + n * 8 + k], denk);
        }
    }
}

__global__ void finalize_k(const float* __restrict__ acc, float* __restrict__ out)
{
    int l = threadIdx.x;
    float v = 0.f;
    if (l < 32) v = acc[l] / acc[32 + l] + acc[64 + l] / acc[96 + l];
#pragma unroll
    for (int s = 32; s > 0; s >>= 1) v += __shfl_xor(v, s, 64);
    if (l == 0) out[0] = v * (1.0f / 64.0f);
}

extern "C" void kernel_launch(void* const* d_in, const int* in_sizes, int n_in,
                              void* d_out, int out_size, void* d_ws, size_t ws_size,
                              hipStream_t stream)
{
    const float* images = (const float*)d_in[0];
    const float* seg    = (const float*)d_in[1];
    const float* w1 = (const float*)d_in[2]; const float* b1 = (const float*)d_in[3];
    const float* w2 = (const float*)d_in[4]; const float* b2 = (const float*)d_in[5];
    const float* w3 = (const float*)d_in[6]; const float* b3 = (const float*)d_in[7];
    const float* w4 = (const float*)d_in[8]; const float* b4 = (const float*)d_in[9];
    float* out = (float*)d_out;
    char* ws = (char*)d_ws;
    short* C2   = (short*)(ws + OFF_C2);
    short* PAD2 = (short*)(ws + OFF_PAD2);
    short* PAD3 = (short*)(ws + OFF_PAD3);
    short* PAD4 = (short*)(ws + OFF_PAD4);
    float* FICH = (float*)(ws + OFF_FICH);
    short* WP2  = (short*)(ws + OFF_WP2);
    short* WP3  = (short*)(ws + OFF_WP3);
    short* WP4  = (short*)(ws + OFF_WP4);
    float* DS   = (float*)(ws + OFF_DS);
    float* IT   = (float*)(ws + OFF_IT);
    float* ST   = (float*)(ws + OFF_ST);
    float* AC   = (float*)(ws + OFF_AC);

    // zero halos + accumulators
    hipMemsetAsync(PAD2, 0, PAD2_BYTES, stream);
    hipMemsetAsync(PAD3, 0, PAD3_BYTES, stream);
    hipMemsetAsync(PAD4, 0, PAD4_BYTES, stream);
    zero_k<<<1, 512, 0, stream>>>(AC);

    // weight prepack (bf16 fragment order)
    prepack_w<<<144, 256, 0, stream>>>(w2, WP2, 64, 4, 36864);
    prepack_w<<<288, 256, 0, stream>>>(w3, WP3, 64, 8, 73728);
    prepack_w<<<576, 256, 0, stream>>>(w4, WP4, 128, 8, 147456);

    // VGG stem
    conv1_bf16<<<2048, 256, 0, stream>>>(images, w1, b1, PAD2);
    conv_mfma<64, 64, 128, 128, 0><<<2048, 256, 0, stream>>>(PAD2, WP2, b2, C2);
    maxpool_nhwc<<<512, 256, 0, stream>>>((const ushortT*)C2, (ushortT*)PAD3);
    conv_mfma<64, 128, 64, 64, 1><<<1024, 256, 0, stream>>>(PAD3, WP3, b3, PAD4);
    conv_mfma<128, 128, 64, 64, 2><<<1024, 256, 0, stream>>>(PAD4, WP4, b4, FICH);

    // BN (scale-only; mean cancels in d2)
    bnsum_nhwc<<<256, 256, 0, stream>>>(FICH, AC + 128);
    stats_fin<<<1, 128, 0, stream>>>(AC + 128, ST);
    scale_fich<<<2048, 256, 0, stream>>>(FICH, ST);

    // image branch
    bn_stats_k<<<3, 256, 0, stream>>>(images, ST + 256, 3, 16384, 4);
    norm_transpose_i_k<<<256, 256, 0, stream>>>(images, ST + 256, IT);
    avgpool2_k<<<512, 256, 0, stream>>>(seg, DS, 131072);

    // modularity terms
    modularity64_v2<<<256, 64, 0, stream>>>(FICH, DS, AC);
    modularity128_v2<<<1024, 64, 0, stream>>>(IT, seg, AC);

    finalize_k<<<1, 64, 0, stream>>>(AC, out);
}

// Round 11
// 338.701 us; speedup vs baseline: 1.3551x; 1.3551x over previous
//
#include <hip/hip_runtime.h>
#include <hip/hip_bf16.h>
#include <math.h>

typedef __attribute__((ext_vector_type(8))) short short8;
typedef __attribute__((ext_vector_type(4))) float floatx4;
typedef unsigned short ushortT;

__device__ inline short f2bf(float v) {
    __hip_bfloat16 h = __float2bfloat16(v);
    union { __hip_bfloat16 h; short s; } u; u.h = h; return u.s;
}

// ---------------- workspace layout (bytes), all disjoint ----------------
#define OFF_C2    0
#define OFF_PAD4  8388608
#define OFF_FICH  12849152
#define OFF_PAD2  21237760
#define OFF_PAD3  29890560
#define OFF_WP2   32120832
#define OFF_WP3   32194560
#define OFF_WP4   32342016
#define OFF_DS    32636928
#define OFF_IT    33161216
#define OFF_ST    33947648   // [0..127] rstdF; [256..261] img mean/rstd
#define OFF_RED   33949696   // 128 floats: reduced (num,den) x 64
#define OFF_P64   33951744   // 256 x 16 floats mod64 partials   (16 KB)
#define OFF_P128  33968128   // 1024 x 16 floats mod128 partials (64 KB)
#define OFF_PBN   34033664   // 256 x 256 floats bnsum partials  (256 KB)

#define PAD2_BYTES 8652800
#define PAD3_BYTES 2230272
#define PAD4_BYTES 4460544

// ---------------- conv1: fp32 direct (Cin=3), writes bf16 NHWC padded --------
__global__ __launch_bounds__(256) void conv1_bf16(
    const float* __restrict__ in, const float* __restrict__ w,
    const float* __restrict__ b, short* __restrict__ outp)
{
    int bid = blockIdx.x;                 // 4n x 8ocg x 8ty x 8tx
    int txt = bid & 7; bid >>= 3;
    int tyt = bid & 7; bid >>= 3;
    int ocg = bid & 7; bid >>= 3;
    int n = bid;
    int x0 = txt * 16, y0 = tyt * 16;
    int tid = threadIdx.x;
    int tx = tid & 15, ty = tid >> 4;

    __shared__ float lds[3 * 720];
    for (int i = tid; i < 972; i += 256) {
        int cc = i / 324; int rem = i - cc * 324;
        int r = rem / 18, c = rem - r * 18;
        int y = y0 - 1 + r, x = x0 - 1 + c;
        float v = 0.f;
        if ((unsigned)y < 128u && (unsigned)x < 128u)
            v = in[((size_t)(n * 3 + cc) * 128 + y) * 128 + x];
        lds[cc * 720 + r * 40 + c] = v;
    }
    __syncthreads();

    float acc[8];
#pragma unroll
    for (int oc = 0; oc < 8; ++oc) acc[oc] = 0.f;
    const float* w_g = w + (size_t)(ocg * 8) * 27;
#pragma unroll
    for (int cc = 0; cc < 3; ++cc) {
        const float* base = &lds[cc * 720 + ty * 40 + tx];
        float i00 = base[0],  i01 = base[1],  i02 = base[2];
        float i10 = base[40], i11 = base[41], i12 = base[42];
        float i20 = base[80], i21 = base[81], i22 = base[82];
        const float* wp = w_g + cc * 9;
#pragma unroll
        for (int oc = 0; oc < 8; ++oc) {
            const float* wq = wp + oc * 27;
            float a = acc[oc];
            a = fmaf(wq[0], i00, a); a = fmaf(wq[1], i01, a); a = fmaf(wq[2], i02, a);
            a = fmaf(wq[3], i10, a); a = fmaf(wq[4], i11, a); a = fmaf(wq[5], i12, a);
            a = fmaf(wq[6], i20, a); a = fmaf(wq[7], i21, a); a = fmaf(wq[8], i22, a);
            acc[oc] = a;
        }
    }
    int oy = y0 + ty, ox = x0 + tx;
    short* o = outp + ((size_t)(n * 130 + oy + 1) * 130 + ox + 1) * 64 + ocg * 8;
#pragma unroll
    for (int oc = 0; oc < 8; ++oc) {
        float v = fmaxf(acc[oc] + b[ocg * 8 + oc], 0.f);
        o[oc] = f2bf(v);
    }
}

// ---------------- weight prepack into MFMA B-fragment order ------------------
__global__ void prepack_w(const float* __restrict__ w, short* __restrict__ wp,
                          int CIN, int NTALL, int total)
{
    int e = blockIdx.x * 256 + threadIdx.x;
    if (e >= total) return;
    int j = e & 7; int L = (e >> 3) & 63; int rest = e >> 9;
    int nt = rest % NTALL; int rest2 = rest / NTALL;
    int KT = CIN / 32;
    int kt = rest2 % KT; int t = rest2 / KT;
    int oc = nt * 16 + (L & 15);
    int ci = kt * 32 + (L >> 4) * 8 + j;
    wp[e] = f2bf(w[((size_t)oc * CIN + ci) * 9 + t]);
}

// ---------------- MFMA implicit-GEMM 3x3 conv --------------------------------
template<int CIN, int COUT, int H, int W, int OUTMODE>
__global__ __launch_bounds__(256) void conv_mfma(
    const short* __restrict__ inp, const short* __restrict__ wp,
    const float* __restrict__ bias, void* __restrict__ outv)
{
    constexpr int KT = CIN / 32;
    constexpr int NTALL = COUT / 16;
    constexpr int NTB = COUT / 64;
    constexpr int TPR = W / 32;
    constexpr int Hp = H + 2, Wp = W + 2;

    int bm = blockIdx.x / NTB;
    int bn = blockIdx.x - bm * NTB;
    int n = bm / (H * TPR);
    int rem = bm - n * (H * TPR);
    int y = rem / TPR;
    int x0 = (rem - y * TPR) * 32;

    int tid = threadIdx.x;
    int wv = tid >> 6, lane = tid & 63;
    int lm = lane & 15, q = lane >> 4;
    int px0 = x0 + 16 * (wv & 1);
    int ntb = bn * 4 + (wv >> 1) * 2;

    floatx4 acc0 = {0.f, 0.f, 0.f, 0.f};
    floatx4 acc1 = {0.f, 0.f, 0.f, 0.f};

    const short* a_m = inp + lm * CIN + q * 8;
    const short* wbase = wp + ((size_t)ntb * 64 + lane) * 8;

    for (int kt = 0; kt < KT; ++kt) {
        int kofs = kt * 32;
#pragma unroll
        for (int r = 0; r < 3; ++r) {
            const short* arow = a_m + (size_t)((n * Hp + y + r) * Wp + px0) * CIN + kofs;
#pragma unroll
            for (int s = 0; s < 3; ++s) {
                short8 av = *(const short8*)(arow + s * CIN);
                const short* bp = wbase + (size_t)(((r * 3 + s) * KT + kt) * NTALL) * 512;
                short8 b0 = *(const short8*)bp;
                short8 b1 = *(const short8*)(bp + 512);
                acc0 = __builtin_amdgcn_mfma_f32_16x16x32_bf16(av, b0, acc0, 0, 0, 0);
                acc1 = __builtin_amdgcn_mfma_f32_16x16x32_bf16(av, b1, acc1, 0, 0, 0);
            }
        }
    }

#pragma unroll
    for (int half = 0; half < 2; ++half) {
        floatx4 a = half ? acc1 : acc0;
        int oc = (ntb + half) * 16 + lm;
        float bs = bias[oc];
#pragma unroll
        for (int i = 0; i < 4; ++i) {
            int px = px0 + q * 4 + i;
            float v = fmaxf(a[i] + bs, 0.f);
            if constexpr (OUTMODE == 0) {
                ((short*)outv)[((size_t)(n * H + y) * W + px) * COUT + oc] = f2bf(v);
            } else if constexpr (OUTMODE == 1) {
                ((short*)outv)[((size_t)(n * Hp + y + 1) * Wp + px + 1) * COUT + oc] = f2bf(v);
            } else {
                ((float*)outv)[((size_t)(n * H + y) * W + px) * COUT + oc] = v;
            }
        }
    }
}

// ---------------- 2x2 maxpool, bf16 NHWC -> padded NHWC ----------------------
__global__ __launch_bounds__(256) void maxpool_nhwc(const ushortT* __restrict__ in,
                                                    ushortT* __restrict__ outp)
{
    int gid = blockIdx.x * 256 + threadIdx.x;   // 131072 = 4*64*64*8
    int c8 = gid & 7; int rest = gid >> 3;
    int xo = rest & 63, yo = (rest >> 6) & 63, n = rest >> 12;
    const ushortT* p = in + ((size_t)(n * 128 + yo * 2) * 128 + xo * 2) * 64 + c8 * 8;
    const ushortT* p01 = p + 64;
    const ushortT* p10 = p + 128 * 64;
    const ushortT* p11 = p10 + 64;
    ushortT* o = outp + ((size_t)(n * 66 + yo + 1) * 66 + xo + 1) * 64 + c8 * 8;
#pragma unroll
    for (int j = 0; j < 8; ++j) {
        ushortT a = p[j] > p01[j] ? p[j] : p01[j];
        ushortT b = p10[j] > p11[j] ? p10[j] : p11[j];
        o[j] = a > b ? a : b;
    }
}

// ---------------- BN over NHWC fich: per-block partials, no atomics ----------
__global__ __launch_bounds__(256) void bnsum_nhwc(const float* __restrict__ x,
                                                  float* __restrict__ part)
{
    int tid = threadIdx.x;
    int c = tid & 127;
    int h = tid >> 7;
    int p0 = blockIdx.x * 64 + h * 32;
    float s = 0.f, s2 = 0.f;
    for (int p = p0; p < p0 + 32; ++p) {
        float v = x[(size_t)p * 128 + c];
        s += v; s2 = fmaf(v, v, s2);
    }
    __shared__ float rs[256], rs2[256];
    rs[tid] = s; rs2[tid] = s2;
    __syncthreads();
    if (tid < 128) {
        part[(size_t)blockIdx.x * 256 + tid] = rs[tid] + rs[tid + 128];
        part[(size_t)blockIdx.x * 256 + 128 + tid] = rs2[tid] + rs2[tid + 128];
    }
}

// one block per channel: reduce 256 block-partials
__global__ __launch_bounds__(256) void stats_fin(const float* __restrict__ part,
                                                 float* __restrict__ st)
{
    int c = blockIdx.x;     // 128
    int t = threadIdx.x;    // 256 (one per bnsum block)
    float s  = part[(size_t)t * 256 + c];
    float s2 = part[(size_t)t * 256 + 128 + c];
    __shared__ float rs[256], rs2[256];
    rs[t] = s; rs2[t] = s2;
    __syncthreads();
    for (int k = 128; k > 0; k >>= 1) {
        if (t < k) { rs[t] += rs[t + k]; rs2[t] += rs2[t + k]; }
        __syncthreads();
    }
    if (t == 0) {
        float mean = rs[0] * (1.f / 16384.f);
        float var = rs2[0] * (1.f / 16384.f) - mean * mean;
        st[c] = 1.f / sqrtf(var + 1e-5f);
    }
}

__global__ __launch_bounds__(256) void scale_fich(float* __restrict__ x,
                                                  const float* __restrict__ st)
{
    int i = blockIdx.x * 256 + threadIdx.x;    // 524288 float4s
    float4 v = ((float4*)x)[i];
    int c0 = (i * 4) & 127;
    v.x *= st[c0]; v.y *= st[c0 + 1]; v.z *= st[c0 + 2]; v.w *= st[c0 + 3];
    ((float4*)x)[i] = v;
}

// ---------------- image-branch prep ----------------
__global__ __launch_bounds__(256) void avgpool2_k(const float* __restrict__ in,
                                                  float* __restrict__ out, int total)
{
    int tid = blockIdx.x * 256 + threadIdx.x;
    if (tid >= total) return;
    int wo = tid & 63, ho = (tid >> 6) & 63, ch = tid >> 12;
    const float* p = in + (size_t)ch * 16384 + (size_t)(ho * 2) * 128 + wo * 2;
    out[tid] = 0.25f * ((p[0] + p[1]) + (p[128] + p[129]));
}

__global__ __launch_bounds__(256) void bn_stats_k(const float* __restrict__ x,
                                                  float* __restrict__ stats,
                                                  int C, int HW, int N)
{
    int c = blockIdx.x, tid = threadIdx.x;
    int M = N * HW;
    double s = 0.0, s2 = 0.0;
    for (int i = tid; i < M; i += 256) {
        int n = i / HW, r = i - n * HW;
        float v = x[((size_t)(n * C + c)) * HW + r];
        s += v;
        s2 += (double)v * (double)v;
    }
    __shared__ double ls[256], ls2[256];
    ls[tid] = s; ls2[tid] = s2;
    __syncthreads();
    for (int st = 128; st > 0; st >>= 1) {
        if (tid < st) { ls[tid] += ls[tid + st]; ls2[tid] += ls2[tid + st]; }
        __syncthreads();
    }
    if (tid == 0) {
        double mean = ls[0] / M;
        double var = ls2[0] / M - mean * mean;
        stats[c] = (float)mean;
        stats[C + c] = (float)(1.0 / sqrt(var + 1e-5));
    }
}

__global__ __launch_bounds__(256) void norm_transpose_i_k(
    const float* __restrict__ x, const float* __restrict__ stats,
    float* __restrict__ it)
{
    int tid = blockIdx.x * 256 + threadIdx.x;   // 65536
    int n = tid >> 14;
    int hw = tid & 16383;
#pragma unroll
    for (int c = 0; c < 3; ++c) {
        float v = x[(((size_t)n * 3 + c) << 14) + hw];
        it[(size_t)tid * 3 + c] = (v - stats[c]) * stats[3 + c];
    }
}

// ---------------- modularity on VGG features (partials, no atomics) ----------
__global__ __launch_bounds__(64) void modularity64_v3(
    const float* __restrict__ xt,   // (4,64,64,128) scaled
    const float* __restrict__ seg,  // (4,8,64,64)
    float* __restrict__ part)       // [256][16]: (num,den) x 8k per block
{
    __shared__ float fl[12][12][20];
    __shared__ float sl[8][12][14];

    int t = threadIdx.x;
    int tx = t & 7, ty = t >> 3;
    int obid = blockIdx.x;
    int bid = obid;
    int bx = bid & 7; bid >>= 3;
    int by = bid & 7; bid >>= 3;
    int n = bid;
    int x0 = bx * 8, y0 = by * 8;

    for (int i = t; i < 8 * 144; i += 64) {
        int k = i / 144;
        int rem = i - k * 144;
        int r = rem / 12, c = rem - r * 12;
        int y = y0 - 2 + r, x = x0 - 2 + c;
        float v = 0.f;
        if ((unsigned)y < 64u && (unsigned)x < 64u)
            v = seg[((size_t)(n * 8 + k) * 64 + y) * 64 + x];
        sl[k][r][c] = v;
    }

    float d2p[25];
#pragma unroll
    for (int di = 0; di < 5; ++di)
#pragma unroll
        for (int dj = 0; dj < 5; ++dj) {
            int y2 = y0 + ty + di - 2, x2 = x0 + tx + dj - 2;
            d2p[di * 5 + dj] = ((unsigned)y2 < 64u && (unsigned)x2 < 64u) ? 0.f : 1e30f;
        }

    for (int ch0 = 0; ch0 < 128; ch0 += 16) {
        __syncthreads();
        for (int i = t; i < 576; i += 64) {
            int pix = i >> 2, qq = i & 3;
            int r = pix / 12, c = pix - r * 12;
            int y = y0 - 2 + r, x = x0 - 2 + c;
            float4 v = make_float4(0.f, 0.f, 0.f, 0.f);
            if ((unsigned)y < 64u && (unsigned)x < 64u)
                v = *(const float4*)&xt[((size_t)((n * 64 + y) * 64 + x)) * 128 + ch0 + qq * 4];
            *(float4*)&fl[r][c][qq * 4] = v;
        }
        __syncthreads();

        float4 c0 = *(const float4*)&fl[ty + 2][tx + 2][0];
        float4 c1 = *(const float4*)&fl[ty + 2][tx + 2][4];
        float4 c2 = *(const float4*)&fl[ty + 2][tx + 2][8];
        float4 c3 = *(const float4*)&fl[ty + 2][tx + 2][12];
#pragma unroll
        for (int di = 0; di < 5; ++di)
#pragma unroll
            for (int dj = 0; dj < 5; ++dj) {
                const float* np = &fl[ty + di][tx + dj][0];
                float4 v0 = *(const float4*)(np + 0);
                float4 v1 = *(const float4*)(np + 4);
                float4 v2 = *(const float4*)(np + 8);
                float4 v3 = *(const float4*)(np + 12);
                float d = d2p[di * 5 + dj];
                float e;
                e = c0.x - v0.x; d = fmaf(e, e, d);
                e = c0.y - v0.y; d = fmaf(e, e, d);
                e = c0.z - v0.z; d = fmaf(e, e, d);
                e = c0.w - v0.w; d = fmaf(e, e, d);
                e = c1.x - v1.x; d = fmaf(e, e, d);
                e = c1.y - v1.y; d = fmaf(e, e, d);
                e = c1.z - v1.z; d = fmaf(e, e, d);
                e = c1.w - v1.w; d = fmaf(e, e, d);
                e = c2.x - v2.x; d = fmaf(e, e, d);
                e = c2.y - v2.y; d = fmaf(e, e, d);
                e = c2.z - v2.z; d = fmaf(e, e, d);
                e = c2.w - v2.w; d = fmaf(e, e, d);
                e = c3.x - v3.x; d = fmaf(e, e, d);
                e = c3.y - v3.y; d = fmaf(e, e, d);
                e = c3.z - v3.z; d = fmaf(e, e, d);
                e = c3.w - v3.w; d = fmaf(e, e, d);
                d2p[di * 5 + dj] = d;
            }
    }

    const float minus_inv2s2 = -1.0f / (2.0f * 0.02f * 0.02f);
    float wgt[25];
    float w1 = 0.f;
#pragma unroll
    for (int j = 0; j < 25; ++j) {
        wgt[j] = expf(d2p[j] * minus_inv2s2);
        w1 += wgt[j];
    }

#pragma unroll
    for (int k = 0; k < 8; ++k) {
        float s = 0.f;
#pragma unroll
        for (int di = 0; di < 5; ++di)
#pragma unroll
            for (int dj = 0; dj < 5; ++dj)
                s = fmaf(wgt[di * 5 + dj], sl[k][ty + di][tx + dj], s);
        float sc = sl[k][ty + 2][tx + 2];
        float numk = s * sc;
        float denk = w1 * sc;
#pragma unroll
        for (int sft = 32; sft > 0; sft >>= 1) {
            numk += __shfl_xor(numk, sft, 64);
            denk += __shfl_xor(denk, sft, 64);
        }
        if (t == 0) {
            part[(size_t)obid * 16 + k * 2] = numk;
            part[(size_t)obid * 16 + k * 2 + 1] = denk;
        }
    }
}

// ---------------- modularity on images (partials, no atomics) ----------------
__global__ __launch_bounds__(64) void modularity128_v3(
    const float* __restrict__ it,   // (4,128,128,3) normalized
    const float* __restrict__ seg,  // (4,8,128,128)
    float* __restrict__ part)       // [1024][16]
{
    __shared__ float il[12][12][4];
    __shared__ float sl[8][12][14];

    int t = threadIdx.x;
    int tx = t & 7, ty = t >> 3;
    int obid = blockIdx.x;
    int bid = obid;                    // n(4) x by(16) x bx(16)
    int bx = bid & 15; bid >>= 4;
    int by = bid & 15; bid >>= 4;
    int n = bid;
    int x0 = bx * 8, y0 = by * 8;

    for (int i = t; i < 144; i += 64) {
        int r = i / 12, c = i - r * 12;
        int y = y0 - 2 + r, x = x0 - 2 + c;
        float3 v = make_float3(0.f, 0.f, 0.f);
        if ((unsigned)y < 128u && (unsigned)x < 128u) {
            const float* p = it + ((size_t)((n * 128 + y) * 128 + x)) * 3;
            v.x = p[0]; v.y = p[1]; v.z = p[2];
        }
        il[r][c][0] = v.x; il[r][c][1] = v.y; il[r][c][2] = v.z;
    }
    for (int i = t; i < 8 * 144; i += 64) {
        int k = i / 144;
        int rem = i - k * 144;
        int r = rem / 12, c = rem - r * 12;
        int y = y0 - 2 + r, x = x0 - 2 + c;
        float v = 0.f;
        if ((unsigned)y < 128u && (unsigned)x < 128u)
            v = seg[((size_t)(n * 8 + k) * 128 + y) * 128 + x];
        sl[k][r][c] = v;
    }
    __syncthreads();

    const float minus_inv2s2 = -1.0f / (2.0f * 0.2f * 0.2f); // -12.5
    float c0 = il[ty + 2][tx + 2][0];
    float c1 = il[ty + 2][tx + 2][1];
    float c2 = il[ty + 2][tx + 2][2];

    float wgt[25];
    float w1 = 0.f;
#pragma unroll
    for (int di = 0; di < 5; ++di)
#pragma unroll
        for (int dj = 0; dj < 5; ++dj) {
            int y2 = y0 + ty + di - 2, x2 = x0 + tx + dj - 2;
            float bias = ((unsigned)y2 < 128u && (unsigned)x2 < 128u) ? 0.f : 1e30f;
            const float* np = &il[ty + di][tx + dj][0];
            float e0 = c0 - np[0], e1 = c1 - np[1], e2 = c2 - np[2];
            float d = bias + fmaf(e2, e2, fmaf(e1, e1, e0 * e0));
            float wv = expf(d * minus_inv2s2);
            wgt[di * 5 + dj] = wv;
            w1 += wv;
        }

#pragma unroll
    for (int k = 0; k < 8; ++k) {
        float s = 0.f;
#pragma unroll
        for (int di = 0; di < 5; ++di)
#pragma unroll
            for (int dj = 0; dj < 5; ++dj)
                s = fmaf(wgt[di * 5 + dj], sl[k][ty + di][tx + dj], s);
        float sc = sl[k][ty + 2][tx + 2];
        float numk = s * sc;
        float denk = w1 * sc;
#pragma unroll
        for (int sft = 32; sft > 0; sft >>= 1) {
            numk += __shfl_xor(numk, sft, 64);
            denk += __shfl_xor(denk, sft, 64);
        }
        if (t == 0) {
            part[(size_t)obid * 16 + k * 2] = numk;
            part[(size_t)obid * 16 + k * 2 + 1] = denk;
        }
    }
}

// ---------------- reduce modularity partials: 64 blocks, one per (term,n,k) --
__global__ __launch_bounds__(256) void reduce_mod(const float* __restrict__ p64,
                                                  const float* __restrict__ p128,
                                                  float* __restrict__ red)
{
    int j = blockIdx.x;        // 0..31 VGG, 32..63 IMG
    int t = threadIdx.x;       // 256
    float num = 0.f, den = 0.f;
    if (j < 32) {
        int n = j >> 3, k = j & 7;
        if (t < 64) {
            const float* p = p64 + ((size_t)(n * 64 + t)) * 16 + k * 2;
            num = p[0]; den = p[1];
        }
    } else {
        int jj = j - 32;
        int n = jj >> 3, k = jj & 7;
        const float* p = p128 + ((size_t)(n * 256 + t)) * 16 + k * 2;
        num = p[0]; den = p[1];
    }
    __shared__ float ln[256], ld[256];
    ln[t] = num; ld[t] = den;
    __syncthreads();
    for (int s = 128; s > 0; s >>= 1) {
        if (t < s) { ln[t] += ln[t + s]; ld[t] += ld[t + s]; }
        __syncthreads();
    }
    if (t == 0) { red[j * 2] = ln[0]; red[j * 2 + 1] = ld[0]; }
}

__global__ void finalize_k(const float* __restrict__ red, float* __restrict__ out)
{
    int l = threadIdx.x;   // 64: l<32 -> VGG rel, l>=32 -> IMG rel
    float v = red[l * 2] / red[l * 2 + 1];
#pragma unroll
    for (int s = 32; s > 0; s >>= 1) v += __shfl_xor(v, s, 64);
    if (l == 0) out[0] = v * (1.0f / 64.0f);
}

extern "C" void kernel_launch(void* const* d_in, const int* in_sizes, int n_in,
                              void* d_out, int out_size, void* d_ws, size_t ws_size,
                              hipStream_t stream)
{
    const float* images = (const float*)d_in[0];
    const float* seg    = (const float*)d_in[1];
    const float* w1 = (const float*)d_in[2]; const float* b1 = (const float*)d_in[3];
    const float* w2 = (const float*)d_in[4]; const float* b2 = (const float*)d_in[5];
    const float* w3 = (const float*)d_in[6]; const float* b3 = (const float*)d_in[7];
    const float* w4 = (const float*)d_in[8]; const float* b4 = (const float*)d_in[9];
    float* out = (float*)d_out;
    char* ws = (char*)d_ws;
    short* C2   = (short*)(ws + OFF_C2);
    short* PAD2 = (short*)(ws + OFF_PAD2);
    short* PAD3 = (short*)(ws + OFF_PAD3);
    short* PAD4 = (short*)(ws + OFF_PAD4);
    float* FICH = (float*)(ws + OFF_FICH);
    short* WP2  = (short*)(ws + OFF_WP2);
    short* WP3  = (short*)(ws + OFF_WP3);
    short* WP4  = (short*)(ws + OFF_WP4);
    float* DS   = (float*)(ws + OFF_DS);
    float* IT   = (float*)(ws + OFF_IT);
    float* ST   = (float*)(ws + OFF_ST);
    float* RED  = (float*)(ws + OFF_RED);
    float* P64  = (float*)(ws + OFF_P64);
    float* P128 = (float*)(ws + OFF_P128);
    float* PBN  = (float*)(ws + OFF_PBN);

    // zero halos
    hipMemsetAsync(PAD2, 0, PAD2_BYTES, stream);
    hipMemsetAsync(PAD3, 0, PAD3_BYTES, stream);
    hipMemsetAsync(PAD4, 0, PAD4_BYTES, stream);

    // weight prepack (bf16 fragment order)
    prepack_w<<<144, 256, 0, stream>>>(w2, WP2, 64, 4, 36864);
    prepack_w<<<288, 256, 0, stream>>>(w3, WP3, 64, 8, 73728);
    prepack_w<<<576, 256, 0, stream>>>(w4, WP4, 128, 8, 147456);

    // VGG stem
    conv1_bf16<<<2048, 256, 0, stream>>>(images, w1, b1, PAD2);
    conv_mfma<64, 64, 128, 128, 0><<<2048, 256, 0, stream>>>(PAD2, WP2, b2, C2);
    maxpool_nhwc<<<512, 256, 0, stream>>>((const ushortT*)C2, (ushortT*)PAD3);
    conv_mfma<64, 128, 64, 64, 1><<<1024, 256, 0, stream>>>(PAD3, WP3, b3, PAD4);
    conv_mfma<128, 128, 64, 64, 2><<<1024, 256, 0, stream>>>(PAD4, WP4, b4, FICH);

    // BN (scale-only; mean cancels in d2) — partial-sum based, no atomics
    bnsum_nhwc<<<256, 256, 0, stream>>>(FICH, PBN);
    stats_fin<<<128, 256, 0, stream>>>(PBN, ST);
    scale_fich<<<2048, 256, 0, stream>>>(FICH, ST);

    // image branch
    bn_stats_k<<<3, 256, 0, stream>>>(images, ST + 256, 3, 16384, 4);
    norm_transpose_i_k<<<256, 256, 0, stream>>>(images, ST + 256, IT);
    avgpool2_k<<<512, 256, 0, stream>>>(seg, DS, 131072);

    // modularity terms -> per-block partials -> tree reduce
    modularity64_v3<<<256, 64, 0, stream>>>(FICH, DS, P64);
    modularity128_v3<<<1024, 64, 0, stream>>>(IT, seg, P128);
    reduce_mod<<<64, 256, 0, stream>>>(P64, P128, RED);

    finalize_k<<<1, 64, 0, stream>>>(RED, out);
}

// Round 12
// 255.885 us; speedup vs baseline: 1.7936x; 1.3236x over previous
//
#include <hip/hip_runtime.h>
#include <hip/hip_bf16.h>
#include <math.h>

typedef __attribute__((ext_vector_type(8))) short short8;
typedef __attribute__((ext_vector_type(4))) float floatx4;
typedef unsigned short ushortT;

__device__ inline short f2bf(float v) {
    __hip_bfloat16 h = __float2bfloat16(v);
    union { __hip_bfloat16 h; short s; } u; u.h = h; return u.s;
}

// ---------------- workspace layout (bytes), all disjoint ----------------
#define OFF_C2    0
#define OFF_PAD4  8388608
#define OFF_FICH  12849152
#define OFF_PAD2  21237760
#define OFF_PAD3  29890560
#define OFF_WP2   32120832
#define OFF_WP3   32194560
#define OFF_WP4   32342016
#define OFF_DS    32636928
#define OFF_IT    33161216
#define OFF_ST    33947648   // [0..127] rstdF; [256..261] img mean/rstd
#define OFF_RED   33949696   // 128 floats: reduced (num,den) x 64
#define OFF_P64   33951744   // 256 x 16 floats mod64 partials   (16 KB)
#define OFF_P128  33968128   // 1024 x 16 floats mod128 partials (64 KB)
#define OFF_PBN   34033664   // 256 x 256 floats bnsum partials  (256 KB)
#define OFF_PIMG  34295808   // 192 x 2 floats image bn partials

#define PAD2_BYTES 8652800
#define PAD3_BYTES 2230272
#define PAD4_BYTES 4460544

// ---------------- conv1: fp32 direct (Cin=3), writes bf16 NHWC padded --------
__global__ __launch_bounds__(256) void conv1_bf16(
    const float* __restrict__ in, const float* __restrict__ w,
    const float* __restrict__ b, short* __restrict__ outp)
{
    int bid = blockIdx.x;                 // 4n x 8ocg x 8ty x 8tx
    int txt = bid & 7; bid >>= 3;
    int tyt = bid & 7; bid >>= 3;
    int ocg = bid & 7; bid >>= 3;
    int n = bid;
    int x0 = txt * 16, y0 = tyt * 16;
    int tid = threadIdx.x;
    int tx = tid & 15, ty = tid >> 4;

    __shared__ float lds[3 * 720];
    for (int i = tid; i < 972; i += 256) {
        int cc = i / 324; int rem = i - cc * 324;
        int r = rem / 18, c = rem - r * 18;
        int y = y0 - 1 + r, x = x0 - 1 + c;
        float v = 0.f;
        if ((unsigned)y < 128u && (unsigned)x < 128u)
            v = in[((size_t)(n * 3 + cc) * 128 + y) * 128 + x];
        lds[cc * 720 + r * 40 + c] = v;
    }
    __syncthreads();

    float acc[8];
#pragma unroll
    for (int oc = 0; oc < 8; ++oc) acc[oc] = 0.f;
    const float* w_g = w + (size_t)(ocg * 8) * 27;
#pragma unroll
    for (int cc = 0; cc < 3; ++cc) {
        const float* base = &lds[cc * 720 + ty * 40 + tx];
        float i00 = base[0],  i01 = base[1],  i02 = base[2];
        float i10 = base[40], i11 = base[41], i12 = base[42];
        float i20 = base[80], i21 = base[81], i22 = base[82];
        const float* wp = w_g + cc * 9;
#pragma unroll
        for (int oc = 0; oc < 8; ++oc) {
            const float* wq = wp + oc * 27;
            float a = acc[oc];
            a = fmaf(wq[0], i00, a); a = fmaf(wq[1], i01, a); a = fmaf(wq[2], i02, a);
            a = fmaf(wq[3], i10, a); a = fmaf(wq[4], i11, a); a = fmaf(wq[5], i12, a);
            a = fmaf(wq[6], i20, a); a = fmaf(wq[7], i21, a); a = fmaf(wq[8], i22, a);
            acc[oc] = a;
        }
    }
    int oy = y0 + ty, ox = x0 + tx;
    short* o = outp + ((size_t)(n * 130 + oy + 1) * 130 + ox + 1) * 64 + ocg * 8;
#pragma unroll
    for (int oc = 0; oc < 8; ++oc) {
        float v = fmaxf(acc[oc] + b[ocg * 8 + oc], 0.f);
        o[oc] = f2bf(v);
    }
}

// ---------------- weight prepack into MFMA B-fragment order ------------------
__global__ void prepack_w(const float* __restrict__ w, short* __restrict__ wp,
                          int CIN, int NTALL, int total)
{
    int e = blockIdx.x * 256 + threadIdx.x;
    if (e >= total) return;
    int j = e & 7; int L = (e >> 3) & 63; int rest = e >> 9;
    int nt = rest % NTALL; int rest2 = rest / NTALL;
    int KT = CIN / 32;
    int kt = rest2 % KT; int t = rest2 / KT;
    int oc = nt * 16 + (L & 15);
    int ci = kt * 32 + (L >> 4) * 8 + j;
    wp[e] = f2bf(w[((size_t)oc * CIN + ci) * 9 + t]);
}

// ---------------- MFMA implicit-GEMM 3x3 conv --------------------------------
template<int CIN, int COUT, int H, int W, int OUTMODE>
__global__ __launch_bounds__(256) void conv_mfma(
    const short* __restrict__ inp, const short* __restrict__ wp,
    const float* __restrict__ bias, void* __restrict__ outv)
{
    constexpr int KT = CIN / 32;
    constexpr int NTALL = COUT / 16;
    constexpr int NTB = COUT / 64;
    constexpr int TPR = W / 32;
    constexpr int Hp = H + 2, Wp = W + 2;

    int bm = blockIdx.x / NTB;
    int bn = blockIdx.x - bm * NTB;
    int n = bm / (H * TPR);
    int rem = bm - n * (H * TPR);
    int y = rem / TPR;
    int x0 = (rem - y * TPR) * 32;

    int tid = threadIdx.x;
    int wv = tid >> 6, lane = tid & 63;
    int lm = lane & 15, q = lane >> 4;
    int px0 = x0 + 16 * (wv & 1);
    int ntb = bn * 4 + (wv >> 1) * 2;

    floatx4 acc0 = {0.f, 0.f, 0.f, 0.f};
    floatx4 acc1 = {0.f, 0.f, 0.f, 0.f};

    const short* a_m = inp + lm * CIN + q * 8;
    const short* wbase = wp + ((size_t)ntb * 64 + lane) * 8;

    for (int kt = 0; kt < KT; ++kt) {
        int kofs = kt * 32;
#pragma unroll
        for (int r = 0; r < 3; ++r) {
            const short* arow = a_m + (size_t)((n * Hp + y + r) * Wp + px0) * CIN + kofs;
#pragma unroll
            for (int s = 0; s < 3; ++s) {
                short8 av = *(const short8*)(arow + s * CIN);
                const short* bp = wbase + (size_t)(((r * 3 + s) * KT + kt) * NTALL) * 512;
                short8 b0 = *(const short8*)bp;
                short8 b1 = *(const short8*)(bp + 512);
                acc0 = __builtin_amdgcn_mfma_f32_16x16x32_bf16(av, b0, acc0, 0, 0, 0);
                acc1 = __builtin_amdgcn_mfma_f32_16x16x32_bf16(av, b1, acc1, 0, 0, 0);
            }
        }
    }

#pragma unroll
    for (int half = 0; half < 2; ++half) {
        floatx4 a = half ? acc1 : acc0;
        int oc = (ntb + half) * 16 + lm;
        float bs = bias[oc];
#pragma unroll
        for (int i = 0; i < 4; ++i) {
            int px = px0 + q * 4 + i;
            float v = fmaxf(a[i] + bs, 0.f);
            if constexpr (OUTMODE == 0) {
                ((short*)outv)[((size_t)(n * H + y) * W + px) * COUT + oc] = f2bf(v);
            } else if constexpr (OUTMODE == 1) {
                ((short*)outv)[((size_t)(n * Hp + y + 1) * Wp + px + 1) * COUT + oc] = f2bf(v);
            } else {
                ((float*)outv)[((size_t)(n * H + y) * W + px) * COUT + oc] = v;
            }
        }
    }
}

// ---------------- 2x2 maxpool, bf16 NHWC -> padded NHWC ----------------------
__global__ __launch_bounds__(256) void maxpool_nhwc(const ushortT* __restrict__ in,
                                                    ushortT* __restrict__ outp)
{
    int gid = blockIdx.x * 256 + threadIdx.x;   // 131072 = 4*64*64*8
    int c8 = gid & 7; int rest = gid >> 3;
    int xo = rest & 63, yo = (rest >> 6) & 63, n = rest >> 12;
    const ushortT* p = in + ((size_t)(n * 128 + yo * 2) * 128 + xo * 2) * 64 + c8 * 8;
    const ushortT* p01 = p + 64;
    const ushortT* p10 = p + 128 * 64;
    const ushortT* p11 = p10 + 64;
    ushortT* o = outp + ((size_t)(n * 66 + yo + 1) * 66 + xo + 1) * 64 + c8 * 8;
#pragma unroll
    for (int j = 0; j < 8; ++j) {
        ushortT a = p[j] > p01[j] ? p[j] : p01[j];
        ushortT b = p10[j] > p11[j] ? p10[j] : p11[j];
        o[j] = a > b ? a : b;
    }
}

// ---------------- BN over NHWC fich: per-block partials, no atomics ----------
__global__ __launch_bounds__(256) void bnsum_nhwc(const float* __restrict__ x,
                                                  float* __restrict__ part)
{
    int tid = threadIdx.x;
    int c = tid & 127;
    int h = tid >> 7;
    int p0 = blockIdx.x * 64 + h * 32;
    float s = 0.f, s2 = 0.f;
    for (int p = p0; p < p0 + 32; ++p) {
        float v = x[(size_t)p * 128 + c];
        s += v; s2 = fmaf(v, v, s2);
    }
    __shared__ float rs[256], rs2[256];
    rs[tid] = s; rs2[tid] = s2;
    __syncthreads();
    if (tid < 128) {
        part[(size_t)blockIdx.x * 256 + tid] = rs[tid] + rs[tid + 128];
        part[(size_t)blockIdx.x * 256 + 128 + tid] = rs2[tid] + rs2[tid + 128];
    }
}

// one block per channel: reduce 256 block-partials
__global__ __launch_bounds__(256) void stats_fin(const float* __restrict__ part,
                                                 float* __restrict__ st)
{
    int c = blockIdx.x;     // 128
    int t = threadIdx.x;    // 256
    float s  = part[(size_t)t * 256 + c];
    float s2 = part[(size_t)t * 256 + 128 + c];
    __shared__ float rs[256], rs2[256];
    rs[t] = s; rs2[t] = s2;
    __syncthreads();
    for (int k = 128; k > 0; k >>= 1) {
        if (t < k) { rs[t] += rs[t + k]; rs2[t] += rs2[t + k]; }
        __syncthreads();
    }
    if (t == 0) {
        float mean = rs[0] * (1.f / 16384.f);
        float var = rs2[0] * (1.f / 16384.f) - mean * mean;
        st[c] = 1.f / sqrtf(var + 1e-5f);
    }
}

__global__ __launch_bounds__(256) void scale_fich(float* __restrict__ x,
                                                  const float* __restrict__ st)
{
    int i = blockIdx.x * 256 + threadIdx.x;    // 524288 float4s
    float4 v = ((float4*)x)[i];
    int c0 = (i * 4) & 127;
    v.x *= st[c0]; v.y *= st[c0 + 1]; v.z *= st[c0 + 2]; v.w *= st[c0 + 3];
    ((float4*)x)[i] = v;
}

// ---------------- image BN: parallel partials (192 blocks) -------------------
__global__ __launch_bounds__(256) void bnsum_img(const float* __restrict__ x,
                                                 float* __restrict__ part)
{
    int b = blockIdx.x;          // c(3) x chunk(64)
    int c = b >> 6, chunk = b & 63;
    int t = threadIdx.x;
    int base = chunk * 1024 + t; // within 65536 per-channel elems
    float s = 0.f, s2 = 0.f;
#pragma unroll
    for (int k = 0; k < 4; ++k) {
        int i = base + k * 256;
        int n = i >> 14, hw = i & 16383;
        float v = x[(((size_t)(n * 3 + c)) << 14) + hw];
        s += v; s2 = fmaf(v, v, s2);
    }
    __shared__ float rs[256], rs2[256];
    rs[t] = s; rs2[t] = s2;
    __syncthreads();
    for (int k = 128; k > 0; k >>= 1) {
        if (t < k) { rs[t] += rs[t + k]; rs2[t] += rs2[t + k]; }
        __syncthreads();
    }
    if (t == 0) { part[b * 2] = rs[0]; part[b * 2 + 1] = rs2[0]; }
}

__global__ void stats_img_fin(const float* __restrict__ part, float* __restrict__ st)
{
    int t = threadIdx.x;          // 192 = 3 waves; wave w handles channel w
    int c = t >> 6, idx = t & 63;
    float s  = part[(c * 64 + idx) * 2];
    float s2 = part[(c * 64 + idx) * 2 + 1];
#pragma unroll
    for (int sh = 32; sh > 0; sh >>= 1) {
        s += __shfl_xor(s, sh, 64);
        s2 += __shfl_xor(s2, sh, 64);
    }
    if (idx == 0) {
        float mean = s * (1.f / 65536.f);
        float var = s2 * (1.f / 65536.f) - mean * mean;
        st[c] = mean;
        st[3 + c] = 1.f / sqrtf(var + 1e-5f);
    }
}

// ---------------- image-branch prep ----------------
__global__ __launch_bounds__(256) void avgpool2_k(const float* __restrict__ in,
                                                  float* __restrict__ out, int total)
{
    int tid = blockIdx.x * 256 + threadIdx.x;
    if (tid >= total) return;
    int wo = tid & 63, ho = (tid >> 6) & 63, ch = tid >> 12;
    const float* p = in + (size_t)ch * 16384 + (size_t)(ho * 2) * 128 + wo * 2;
    out[tid] = 0.25f * ((p[0] + p[1]) + (p[128] + p[129]));
}

__global__ __launch_bounds__(256) void norm_transpose_i_k(
    const float* __restrict__ x, const float* __restrict__ stats,
    float* __restrict__ it)
{
    int tid = blockIdx.x * 256 + threadIdx.x;   // 65536
    int n = tid >> 14;
    int hw = tid & 16383;
#pragma unroll
    for (int c = 0; c < 3; ++c) {
        float v = x[(((size_t)n * 3 + c) << 14) + hw];
        it[(size_t)tid * 3 + c] = (v - stats[c]) * stats[3 + c];
    }
}

// ---------------- modularity on VGG features (partials, no atomics) ----------
__global__ __launch_bounds__(64) void modularity64_v3(
    const float* __restrict__ xt,   // (4,64,64,128) scaled
    const float* __restrict__ seg,  // (4,8,64,64)
    float* __restrict__ part)       // [256][16]
{
    __shared__ float fl[12][12][20];
    __shared__ float sl[8][12][14];

    int t = threadIdx.x;
    int tx = t & 7, ty = t >> 3;
    int obid = blockIdx.x;
    int bid = obid;
    int bx = bid & 7; bid >>= 3;
    int by = bid & 7; bid >>= 3;
    int n = bid;
    int x0 = bx * 8, y0 = by * 8;

    for (int i = t; i < 8 * 144; i += 64) {
        int k = i / 144;
        int rem = i - k * 144;
        int r = rem / 12, c = rem - r * 12;
        int y = y0 - 2 + r, x = x0 - 2 + c;
        float v = 0.f;
        if ((unsigned)y < 64u && (unsigned)x < 64u)
            v = seg[((size_t)(n * 8 + k) * 64 + y) * 64 + x];
        sl[k][r][c] = v;
    }

    float d2p[25];
#pragma unroll
    for (int di = 0; di < 5; ++di)
#pragma unroll
        for (int dj = 0; dj < 5; ++dj) {
            int y2 = y0 + ty + di - 2, x2 = x0 + tx + dj - 2;
            d2p[di * 5 + dj] = ((unsigned)y2 < 64u && (unsigned)x2 < 64u) ? 0.f : 1e30f;
        }

    for (int ch0 = 0; ch0 < 128; ch0 += 16) {
        __syncthreads();
        for (int i = t; i < 576; i += 64) {
            int pix = i >> 2, qq = i & 3;
            int r = pix / 12, c = pix - r * 12;
            int y = y0 - 2 + r, x = x0 - 2 + c;
            float4 v = make_float4(0.f, 0.f, 0.f, 0.f);
            if ((unsigned)y < 64u && (unsigned)x < 64u)
                v = *(const float4*)&xt[((size_t)((n * 64 + y) * 64 + x)) * 128 + ch0 + qq * 4];
            *(float4*)&fl[r][c][qq * 4] = v;
        }
        __syncthreads();

        float4 c0 = *(const float4*)&fl[ty + 2][tx + 2][0];
        float4 c1 = *(const float4*)&fl[ty + 2][tx + 2][4];
        float4 c2 = *(const float4*)&fl[ty + 2][tx + 2][8];
        float4 c3 = *(const float4*)&fl[ty + 2][tx + 2][12];
#pragma unroll
        for (int di = 0; di < 5; ++di)
#pragma unroll
            for (int dj = 0; dj < 5; ++dj) {
                const float* np = &fl[ty + di][tx + dj][0];
                float4 v0 = *(const float4*)(np + 0);
                float4 v1 = *(const float4*)(np + 4);
                float4 v2 = *(const float4*)(np + 8);
                float4 v3 = *(const float4*)(np + 12);
                float d = d2p[di * 5 + dj];
                float e;
                e = c0.x - v0.x; d = fmaf(e, e, d);
                e = c0.y - v0.y; d = fmaf(e, e, d);
                e = c0.z - v0.z; d = fmaf(e, e, d);
                e = c0.w - v0.w; d = fmaf(e, e, d);
                e = c1.x - v1.x; d = fmaf(e, e, d);
                e = c1.y - v1.y; d = fmaf(e, e, d);
                e = c1.z - v1.z; d = fmaf(e, e, d);
                e = c1.w - v1.w; d = fmaf(e, e, d);
                e = c2.x - v2.x; d = fmaf(e, e, d);
                e = c2.y - v2.y; d = fmaf(e, e, d);
                e = c2.z - v2.z; d = fmaf(e, e, d);
                e = c2.w - v2.w; d = fmaf(e, e, d);
                e = c3.x - v3.x; d = fmaf(e, e, d);
                e = c3.y - v3.y; d = fmaf(e, e, d);
                e = c3.z - v3.z; d = fmaf(e, e, d);
                e = c3.w - v3.w; d = fmaf(e, e, d);
                d2p[di * 5 + dj] = d;
            }
    }

    const float minus_inv2s2 = -1.0f / (2.0f * 0.02f * 0.02f);
    float wgt[25];
    float w1 = 0.f;
#pragma unroll
    for (int j = 0; j < 25; ++j) {
        wgt[j] = expf(d2p[j] * minus_inv2s2);
        w1 += wgt[j];
    }

#pragma unroll
    for (int k = 0; k < 8; ++k) {
        float s = 0.f;
#pragma unroll
        for (int di = 0; di < 5; ++di)
#pragma unroll
            for (int dj = 0; dj < 5; ++dj)
                s = fmaf(wgt[di * 5 + dj], sl[k][ty + di][tx + dj], s);
        float sc = sl[k][ty + 2][tx + 2];
        float numk = s * sc;
        float denk = w1 * sc;
#pragma unroll
        for (int sft = 32; sft > 0; sft >>= 1) {
            numk += __shfl_xor(numk, sft, 64);
            denk += __shfl_xor(denk, sft, 64);
        }
        if (t == 0) {
            part[(size_t)obid * 16 + k * 2] = numk;
            part[(size_t)obid * 16 + k * 2 + 1] = denk;
        }
    }
}

// ---------------- modularity on images (partials, no atomics) ----------------
__global__ __launch_bounds__(64) void modularity128_v3(
    const float* __restrict__ it,   // (4,128,128,3) normalized
    const float* __restrict__ seg,  // (4,8,128,128)
    float* __restrict__ part)       // [1024][16]
{
    __shared__ float il[12][12][4];
    __shared__ float sl[8][12][14];

    int t = threadIdx.x;
    int tx = t & 7, ty = t >> 3;
    int obid = blockIdx.x;
    int bid = obid;                    // n(4) x by(16) x bx(16)
    int bx = bid & 15; bid >>= 4;
    int by = bid & 15; bid >>= 4;
    int n = bid;
    int x0 = bx * 8, y0 = by * 8;

    for (int i = t; i < 144; i += 64) {
        int r = i / 12, c = i - r * 12;
        int y = y0 - 2 + r, x = x0 - 2 + c;
        float3 v = make_float3(0.f, 0.f, 0.f);
        if ((unsigned)y < 128u && (unsigned)x < 128u) {
            const float* p = it + ((size_t)((n * 128 + y) * 128 + x)) * 3;
            v.x = p[0]; v.y = p[1]; v.z = p[2];
        }
        il[r][c][0] = v.x; il[r][c][1] = v.y; il[r][c][2] = v.z;
    }
    for (int i = t; i < 8 * 144; i += 64) {
        int k = i / 144;
        int rem = i - k * 144;
        int r = rem / 12, c = rem - r * 12;
        int y = y0 - 2 + r, x = x0 - 2 + c;
        float v = 0.f;
        if ((unsigned)y < 128u && (unsigned)x < 128u)
            v = seg[((size_t)(n * 8 + k) * 128 + y) * 128 + x];
        sl[k][r][c] = v;
    }
    __syncthreads();

    const float minus_inv2s2 = -1.0f / (2.0f * 0.2f * 0.2f); // -12.5
    float c0 = il[ty + 2][tx + 2][0];
    float c1 = il[ty + 2][tx + 2][1];
    float c2 = il[ty + 2][tx + 2][2];

    float wgt[25];
    float w1 = 0.f;
#pragma unroll
    for (int di = 0; di < 5; ++di)
#pragma unroll
        for (int dj = 0; dj < 5; ++dj) {
            int y2 = y0 + ty + di - 2, x2 = x0 + tx + dj - 2;
            float bias = ((unsigned)y2 < 128u && (unsigned)x2 < 128u) ? 0.f : 1e30f;
            const float* np = &il[ty + di][tx + dj][0];
            float e0 = c0 - np[0], e1 = c1 - np[1], e2 = c2 - np[2];
            float d = bias + fmaf(e2, e2, fmaf(e1, e1, e0 * e0));
            float wv = expf(d * minus_inv2s2);
            wgt[di * 5 + dj] = wv;
            w1 += wv;
        }

#pragma unroll
    for (int k = 0; k < 8; ++k) {
        float s = 0.f;
#pragma unroll
        for (int di = 0; di < 5; ++di)
#pragma unroll
            for (int dj = 0; dj < 5; ++dj)
                s = fmaf(wgt[di * 5 + dj], sl[k][ty + di][tx + dj], s);
        float sc = sl[k][ty + 2][tx + 2];
        float numk = s * sc;
        float denk = w1 * sc;
#pragma unroll
        for (int sft = 32; sft > 0; sft >>= 1) {
            numk += __shfl_xor(numk, sft, 64);
            denk += __shfl_xor(denk, sft, 64);
        }
        if (t == 0) {
            part[(size_t)obid * 16 + k * 2] = numk;
            part[(size_t)obid * 16 + k * 2 + 1] = denk;
        }
    }
}

// ---------------- reduce modularity partials ----------------
__global__ __launch_bounds__(256) void reduce_mod(const float* __restrict__ p64,
                                                  const float* __restrict__ p128,
                                                  float* __restrict__ red)
{
    int j = blockIdx.x;        // 0..31 VGG, 32..63 IMG
    int t = threadIdx.x;       // 256
    float num = 0.f, den = 0.f;
    if (j < 32) {
        int n = j >> 3, k = j & 7;
        if (t < 64) {
            const float* p = p64 + ((size_t)(n * 64 + t)) * 16 + k * 2;
            num = p[0]; den = p[1];
        }
    } else {
        int jj = j - 32;
        int n = jj >> 3, k = jj & 7;
        const float* p = p128 + ((size_t)(n * 256 + t)) * 16 + k * 2;
        num = p[0]; den = p[1];
    }
    __shared__ float ln[256], ld[256];
    ln[t] = num; ld[t] = den;
    __syncthreads();
    for (int s = 128; s > 0; s >>= 1) {
        if (t < s) { ln[t] += ln[t + s]; ld[t] += ld[t + s]; }
        __syncthreads();
    }
    if (t == 0) { red[j * 2] = ln[0]; red[j * 2 + 1] = ld[0]; }
}

__global__ void finalize_k(const float* __restrict__ red, float* __restrict__ out)
{
    int l = threadIdx.x;   // 64
    float v = red[l * 2] / red[l * 2 + 1];
#pragma unroll
    for (int s = 32; s > 0; s >>= 1) v += __shfl_xor(v, s, 64);
    if (l == 0) out[0] = v * (1.0f / 64.0f);
}

extern "C" void kernel_launch(void* const* d_in, const int* in_sizes, int n_in,
                              void* d_out, int out_size, void* d_ws, size_t ws_size,
                              hipStream_t stream)
{
    const float* images = (const float*)d_in[0];
    const float* seg    = (const float*)d_in[1];
    const float* w1 = (const float*)d_in[2]; const float* b1 = (const float*)d_in[3];
    const float* w2 = (const float*)d_in[4]; const float* b2 = (const float*)d_in[5];
    const float* w3 = (const float*)d_in[6]; const float* b3 = (const float*)d_in[7];
    const float* w4 = (const float*)d_in[8]; const float* b4 = (const float*)d_in[9];
    float* out = (float*)d_out;
    char* ws = (char*)d_ws;
    short* C2   = (short*)(ws + OFF_C2);
    short* PAD2 = (short*)(ws + OFF_PAD2);
    short* PAD3 = (short*)(ws + OFF_PAD3);
    short* PAD4 = (short*)(ws + OFF_PAD4);
    float* FICH = (float*)(ws + OFF_FICH);
    short* WP2  = (short*)(ws + OFF_WP2);
    short* WP3  = (short*)(ws + OFF_WP3);
    short* WP4  = (short*)(ws + OFF_WP4);
    float* DS   = (float*)(ws + OFF_DS);
    float* IT   = (float*)(ws + OFF_IT);
    float* ST   = (float*)(ws + OFF_ST);
    float* RED  = (float*)(ws + OFF_RED);
    float* P64  = (float*)(ws + OFF_P64);
    float* P128 = (float*)(ws + OFF_P128);
    float* PBN  = (float*)(ws + OFF_PBN);
    float* PIMG = (float*)(ws + OFF_PIMG);

    // zero halos
    hipMemsetAsync(PAD2, 0, PAD2_BYTES, stream);
    hipMemsetAsync(PAD3, 0, PAD3_BYTES, stream);
    hipMemsetAsync(PAD4, 0, PAD4_BYTES, stream);

    // weight prepack (bf16 fragment order)
    prepack_w<<<144, 256, 0, stream>>>(w2, WP2, 64, 4, 36864);
    prepack_w<<<288, 256, 0, stream>>>(w3, WP3, 64, 8, 73728);
    prepack_w<<<576, 256, 0, stream>>>(w4, WP4, 128, 8, 147456);

    // image BN stats early (overlaps with conv stem work)
    bnsum_img<<<192, 256, 0, stream>>>(images, PIMG);
    stats_img_fin<<<1, 192, 0, stream>>>(PIMG, ST + 256);

    // VGG stem
    conv1_bf16<<<2048, 256, 0, stream>>>(images, w1, b1, PAD2);
    conv_mfma<64, 64, 128, 128, 0><<<2048, 256, 0, stream>>>(PAD2, WP2, b2, C2);
    maxpool_nhwc<<<512, 256, 0, stream>>>((const ushortT*)C2, (ushortT*)PAD3);
    conv_mfma<64, 128, 64, 64, 1><<<1024, 256, 0, stream>>>(PAD3, WP3, b3, PAD4);
    conv_mfma<128, 128, 64, 64, 2><<<1024, 256, 0, stream>>>(PAD4, WP4, b4, FICH);

    // BN (scale-only; mean cancels in d2)
    bnsum_nhwc<<<256, 256, 0, stream>>>(FICH, PBN);
    stats_fin<<<128, 256, 0, stream>>>(PBN, ST);
    scale_fich<<<2048, 256, 0, stream>>>(FICH, ST);

    // image branch
    norm_transpose_i_k<<<256, 256, 0, stream>>>(images, ST + 256, IT);
    avgpool2_k<<<512, 256, 0, stream>>>(seg, DS, 131072);

    // modularity terms -> per-block partials -> tree reduce
    modularity64_v3<<<256, 64, 0, stream>>>(FICH, DS, P64);
    modularity128_v3<<<1024, 64, 0, stream>>>(IT, seg, P128);
    reduce_mod<<<64, 256, 0, stream>>>(P64, P128, RED);

    finalize_k<<<1, 64, 0, stream>>>(RED, out);
}

// Round 13
// 227.049 us; speedup vs baseline: 2.0215x; 1.1270x over previous
//
#include <hip/hip_runtime.h>
#include <hip/hip_bf16.h>
#include <math.h>

typedef __attribute__((ext_vector_type(8))) short short8;
typedef __attribute__((ext_vector_type(4))) float floatx4;
typedef unsigned short ushortT;

__device__ inline short f2bf(float v) {
    __hip_bfloat16 h = __float2bfloat16(v);
    union { __hip_bfloat16 h; short s; } u; u.h = h; return u.s;
}

// ---------------- workspace layout (bytes), all disjoint ----------------
#define OFF_C2    0
#define OFF_PAD4  8388608
#define OFF_FICH  12849152
#define OFF_PAD2  21237760
#define OFF_PAD3  29890560
#define OFF_WP2   32120832
#define OFF_WP3   32194560
#define OFF_WP4   32342016
#define OFF_DS    32636928
#define OFF_IT    33161216
#define OFF_ST    33947648   // [0..127] rstdF; [256..261] img mean/rstd
#define OFF_RED   33949696   // 128 floats: reduced (num,den) x 64
#define OFF_P64   33951744   // 256 x 16 floats mod64 partials   (16 KB)
#define OFF_P128  33968128   // 1024 x 16 floats mod128 partials (64 KB)
#define OFF_PBN   34033664   // 256 x 256 floats bnsum partials  (256 KB)
#define OFF_PIMG  34295808   // 192 x 2 floats image bn partials

#define PAD2_BYTES 8652800
#define PAD3_BYTES 2230272
#define PAD4_BYTES 4460544

// ---------------- conv1: fp32 direct (Cin=3), writes bf16 NHWC padded --------
__global__ __launch_bounds__(256) void conv1_bf16(
    const float* __restrict__ in, const float* __restrict__ w,
    const float* __restrict__ b, short* __restrict__ outp)
{
    int bid = blockIdx.x;                 // 4n x 8ocg x 8ty x 8tx
    int txt = bid & 7; bid >>= 3;
    int tyt = bid & 7; bid >>= 3;
    int ocg = bid & 7; bid >>= 3;
    int n = bid;
    int x0 = txt * 16, y0 = tyt * 16;
    int tid = threadIdx.x;
    int tx = tid & 15, ty = tid >> 4;

    __shared__ float lds[3 * 720];
    for (int i = tid; i < 972; i += 256) {
        int cc = i / 324; int rem = i - cc * 324;
        int r = rem / 18, c = rem - r * 18;
        int y = y0 - 1 + r, x = x0 - 1 + c;
        float v = 0.f;
        if ((unsigned)y < 128u && (unsigned)x < 128u)
            v = in[((size_t)(n * 3 + cc) * 128 + y) * 128 + x];
        lds[cc * 720 + r * 40 + c] = v;
    }
    __syncthreads();

    float acc[8];
#pragma unroll
    for (int oc = 0; oc < 8; ++oc) acc[oc] = 0.f;
    const float* w_g = w + (size_t)(ocg * 8) * 27;
#pragma unroll
    for (int cc = 0; cc < 3; ++cc) {
        const float* base = &lds[cc * 720 + ty * 40 + tx];
        float i00 = base[0],  i01 = base[1],  i02 = base[2];
        float i10 = base[40], i11 = base[41], i12 = base[42];
        float i20 = base[80], i21 = base[81], i22 = base[82];
        const float* wp = w_g + cc * 9;
#pragma unroll
        for (int oc = 0; oc < 8; ++oc) {
            const float* wq = wp + oc * 27;
            float a = acc[oc];
            a = fmaf(wq[0], i00, a); a = fmaf(wq[1], i01, a); a = fmaf(wq[2], i02, a);
            a = fmaf(wq[3], i10, a); a = fmaf(wq[4], i11, a); a = fmaf(wq[5], i12, a);
            a = fmaf(wq[6], i20, a); a = fmaf(wq[7], i21, a); a = fmaf(wq[8], i22, a);
            acc[oc] = a;
        }
    }
    int oy = y0 + ty, ox = x0 + tx;
    short* o = outp + ((size_t)(n * 130 + oy + 1) * 130 + ox + 1) * 64 + ocg * 8;
#pragma unroll
    for (int oc = 0; oc < 8; ++oc) {
        float v = fmaxf(acc[oc] + b[ocg * 8 + oc], 0.f);
        o[oc] = f2bf(v);
    }
}

// ---------------- weight prepack into MFMA B-fragment order ------------------
__global__ void prepack_w(const float* __restrict__ w, short* __restrict__ wp,
                          int CIN, int NTALL, int total)
{
    int e = blockIdx.x * 256 + threadIdx.x;
    if (e >= total) return;
    int j = e & 7; int L = (e >> 3) & 63; int rest = e >> 9;
    int nt = rest % NTALL; int rest2 = rest / NTALL;
    int KT = CIN / 32;
    int kt = rest2 % KT; int t = rest2 / KT;
    int oc = nt * 16 + (L & 15);
    int ci = kt * 32 + (L >> 4) * 8 + j;
    wp[e] = f2bf(w[((size_t)oc * CIN + ci) * 9 + t]);
}

// ---------------- MFMA implicit-GEMM 3x3 conv --------------------------------
template<int CIN, int COUT, int H, int W, int OUTMODE>
__global__ __launch_bounds__(256) void conv_mfma(
    const short* __restrict__ inp, const short* __restrict__ wp,
    const float* __restrict__ bias, void* __restrict__ outv)
{
    constexpr int KT = CIN / 32;
    constexpr int NTALL = COUT / 16;
    constexpr int NTB = COUT / 64;
    constexpr int TPR = W / 32;
    constexpr int Hp = H + 2, Wp = W + 2;

    int bm = blockIdx.x / NTB;
    int bn = blockIdx.x - bm * NTB;
    int n = bm / (H * TPR);
    int rem = bm - n * (H * TPR);
    int y = rem / TPR;
    int x0 = (rem - y * TPR) * 32;

    int tid = threadIdx.x;
    int wv = tid >> 6, lane = tid & 63;
    int lm = lane & 15, q = lane >> 4;
    int px0 = x0 + 16 * (wv & 1);
    int ntb = bn * 4 + (wv >> 1) * 2;

    floatx4 acc0 = {0.f, 0.f, 0.f, 0.f};
    floatx4 acc1 = {0.f, 0.f, 0.f, 0.f};

    const short* a_m = inp + lm * CIN + q * 8;
    const short* wbase = wp + ((size_t)ntb * 64 + lane) * 8;

    for (int kt = 0; kt < KT; ++kt) {
        int kofs = kt * 32;
#pragma unroll
        for (int r = 0; r < 3; ++r) {
            const short* arow = a_m + (size_t)((n * Hp + y + r) * Wp + px0) * CIN + kofs;
#pragma unroll
            for (int s = 0; s < 3; ++s) {
                short8 av = *(const short8*)(arow + s * CIN);
                const short* bp = wbase + (size_t)(((r * 3 + s) * KT + kt) * NTALL) * 512;
                short8 b0 = *(const short8*)bp;
                short8 b1 = *(const short8*)(bp + 512);
                acc0 = __builtin_amdgcn_mfma_f32_16x16x32_bf16(av, b0, acc0, 0, 0, 0);
                acc1 = __builtin_amdgcn_mfma_f32_16x16x32_bf16(av, b1, acc1, 0, 0, 0);
            }
        }
    }

#pragma unroll
    for (int half = 0; half < 2; ++half) {
        floatx4 a = half ? acc1 : acc0;
        int oc = (ntb + half) * 16 + lm;
        float bs = bias[oc];
#pragma unroll
        for (int i = 0; i < 4; ++i) {
            int px = px0 + q * 4 + i;
            float v = fmaxf(a[i] + bs, 0.f);
            if constexpr (OUTMODE == 0) {
                ((short*)outv)[((size_t)(n * H + y) * W + px) * COUT + oc] = f2bf(v);
            } else if constexpr (OUTMODE == 1) {
                ((short*)outv)[((size_t)(n * Hp + y + 1) * Wp + px + 1) * COUT + oc] = f2bf(v);
            } else {
                ((float*)outv)[((size_t)(n * H + y) * W + px) * COUT + oc] = v;
            }
        }
    }
}

// ---------------- 2x2 maxpool, bf16 NHWC -> padded NHWC ----------------------
__global__ __launch_bounds__(256) void maxpool_nhwc(const ushortT* __restrict__ in,
                                                    ushortT* __restrict__ outp)
{
    int gid = blockIdx.x * 256 + threadIdx.x;   // 131072 = 4*64*64*8
    int c8 = gid & 7; int rest = gid >> 3;
    int xo = rest & 63, yo = (rest >> 6) & 63, n = rest >> 12;
    const ushortT* p = in + ((size_t)(n * 128 + yo * 2) * 128 + xo * 2) * 64 + c8 * 8;
    const ushortT* p01 = p + 64;
    const ushortT* p10 = p + 128 * 64;
    const ushortT* p11 = p10 + 64;
    ushortT* o = outp + ((size_t)(n * 66 + yo + 1) * 66 + xo + 1) * 64 + c8 * 8;
#pragma unroll
    for (int j = 0; j < 8; ++j) {
        ushortT a = p[j] > p01[j] ? p[j] : p01[j];
        ushortT b = p10[j] > p11[j] ? p10[j] : p11[j];
        o[j] = a > b ? a : b;
    }
}

// ---------------- BN over NHWC fich: per-block partials, no atomics ----------
__global__ __launch_bounds__(256) void bnsum_nhwc(const float* __restrict__ x,
                                                  float* __restrict__ part)
{
    int tid = threadIdx.x;
    int c = tid & 127;
    int h = tid >> 7;
    int p0 = blockIdx.x * 64 + h * 32;
    float s = 0.f, s2 = 0.f;
    for (int p = p0; p < p0 + 32; ++p) {
        float v = x[(size_t)p * 128 + c];
        s += v; s2 = fmaf(v, v, s2);
    }
    __shared__ float rs[256], rs2[256];
    rs[tid] = s; rs2[tid] = s2;
    __syncthreads();
    if (tid < 128) {
        part[(size_t)blockIdx.x * 256 + tid] = rs[tid] + rs[tid + 128];
        part[(size_t)blockIdx.x * 256 + 128 + tid] = rs2[tid] + rs2[tid + 128];
    }
}

// one block per channel: reduce 256 block-partials
__global__ __launch_bounds__(256) void stats_fin(const float* __restrict__ part,
                                                 float* __restrict__ st)
{
    int c = blockIdx.x;     // 128
    int t = threadIdx.x;    // 256
    float s  = part[(size_t)t * 256 + c];
    float s2 = part[(size_t)t * 256 + 128 + c];
    __shared__ float rs[256], rs2[256];
    rs[t] = s; rs2[t] = s2;
    __syncthreads();
    for (int k = 128; k > 0; k >>= 1) {
        if (t < k) { rs[t] += rs[t + k]; rs2[t] += rs2[t + k]; }
        __syncthreads();
    }
    if (t == 0) {
        float mean = rs[0] * (1.f / 16384.f);
        float var = rs2[0] * (1.f / 16384.f) - mean * mean;
        st[c] = 1.f / sqrtf(var + 1e-5f);
    }
}

__global__ __launch_bounds__(256) void scale_fich(float* __restrict__ x,
                                                  const float* __restrict__ st)
{
    int i = blockIdx.x * 256 + threadIdx.x;    // 524288 float4s
    float4 v = ((float4*)x)[i];
    int c0 = (i * 4) & 127;
    v.x *= st[c0]; v.y *= st[c0 + 1]; v.z *= st[c0 + 2]; v.w *= st[c0 + 3];
    ((float4*)x)[i] = v;
}

// ---------------- image BN: parallel partials (192 blocks) -------------------
__global__ __launch_bounds__(256) void bnsum_img(const float* __restrict__ x,
                                                 float* __restrict__ part)
{
    int b = blockIdx.x;          // c(3) x chunk(64)
    int c = b >> 6, chunk = b & 63;
    int t = threadIdx.x;
    int base = chunk * 1024 + t;
    float s = 0.f, s2 = 0.f;
#pragma unroll
    for (int k = 0; k < 4; ++k) {
        int i = base + k * 256;
        int n = i >> 14, hw = i & 16383;
        float v = x[(((size_t)(n * 3 + c)) << 14) + hw];
        s += v; s2 = fmaf(v, v, s2);
    }
    __shared__ float rs[256], rs2[256];
    rs[t] = s; rs2[t] = s2;
    __syncthreads();
    for (int k = 128; k > 0; k >>= 1) {
        if (t < k) { rs[t] += rs[t + k]; rs2[t] += rs2[t + k]; }
        __syncthreads();
    }
    if (t == 0) { part[b * 2] = rs[0]; part[b * 2 + 1] = rs2[0]; }
}

__global__ void stats_img_fin(const float* __restrict__ part, float* __restrict__ st)
{
    int t = threadIdx.x;          // 192 = 3 waves
    int c = t >> 6, idx = t & 63;
    float s  = part[(c * 64 + idx) * 2];
    float s2 = part[(c * 64 + idx) * 2 + 1];
#pragma unroll
    for (int sh = 32; sh > 0; sh >>= 1) {
        s += __shfl_xor(s, sh, 64);
        s2 += __shfl_xor(s2, sh, 64);
    }
    if (idx == 0) {
        float mean = s * (1.f / 65536.f);
        float var = s2 * (1.f / 65536.f) - mean * mean;
        st[c] = mean;
        st[3 + c] = 1.f / sqrtf(var + 1e-5f);
    }
}

// ---------------- image-branch prep ----------------
__global__ __launch_bounds__(256) void avgpool2_k(const float* __restrict__ in,
                                                  float* __restrict__ out, int total)
{
    int tid = blockIdx.x * 256 + threadIdx.x;
    if (tid >= total) return;
    int wo = tid & 63, ho = (tid >> 6) & 63, ch = tid >> 12;
    const float* p = in + (size_t)ch * 16384 + (size_t)(ho * 2) * 128 + wo * 2;
    out[tid] = 0.25f * ((p[0] + p[1]) + (p[128] + p[129]));
}

__global__ __launch_bounds__(256) void norm_transpose_i_k(
    const float* __restrict__ x, const float* __restrict__ stats,
    float* __restrict__ it)
{
    int tid = blockIdx.x * 256 + threadIdx.x;   // 65536
    int n = tid >> 14;
    int hw = tid & 16383;
#pragma unroll
    for (int c = 0; c < 3; ++c) {
        float v = x[(((size_t)n * 3 + c) << 14) + hw];
        it[(size_t)tid * 3 + c] = (v - stats[c]) * stats[3 + c];
    }
}

// ---------------- modularity on VGG features v4 ------------------------------
// 256 threads / 4 waves per block, 256 blocks (8x8 px tile per block).
// Wave w owns channels [32w,32w+32) in 2 rounds of 16, staged into its OWN
// 12x12x20 LDS slab -> no block barrier in the channel loop. d2 partials are
// exchanged through the (reused) slab memory; sum+exp distributed over all
// 256 threads; epilogue: wave w reduces classes 2w,2w+1. 2 barriers total.
__global__ __launch_bounds__(256) void modularity64_v4(
    const float* __restrict__ xt,   // (4,64,64,128) scaled
    const float* __restrict__ seg,  // (4,8,64,64)
    float* __restrict__ part)       // [256][16]
{
    __shared__ float fl[4 * 2880];     // 4 slabs [12][12][20]; reused for d2/wgt
    __shared__ float sl[8][12][14];

    int tid = threadIdx.x;
    int w = tid >> 6, lane = tid & 63;
    int tx = lane & 7, ty = lane >> 3;
    int obid = blockIdx.x;
    int bid = obid;
    int bx = bid & 7; bid >>= 3;
    int by = bid & 7; bid >>= 3;
    int n = bid;
    int x0 = bx * 8, y0 = by * 8;

    // stage seg tile with all 256 threads
    for (int i = tid; i < 8 * 144; i += 256) {
        int k = i / 144;
        int rem = i - k * 144;
        int r = rem / 12, c = rem - r * 12;
        int y = y0 - 2 + r, x = x0 - 2 + c;
        float v = 0.f;
        if ((unsigned)y < 64u && (unsigned)x < 64u)
            v = seg[((size_t)(n * 8 + k) * 64 + y) * 64 + x];
        sl[k][r][c] = v;
    }

    float* slab = fl + w * 2880;

    float d2p[25];
#pragma unroll
    for (int di = 0; di < 5; ++di)
#pragma unroll
        for (int dj = 0; dj < 5; ++dj) {
            int y2 = y0 + ty + di - 2, x2 = x0 + tx + dj - 2;
            float bias = ((unsigned)y2 < 64u && (unsigned)x2 < 64u) ? 0.f : 1e30f;
            d2p[di * 5 + dj] = (w == 0) ? bias : 0.f;   // bias counted once
        }

    for (int r8 = 0; r8 < 2; ++r8) {
        int ch0 = w * 32 + r8 * 16;
        // stage own 12x12x16 slab (no block barrier: same-wave RAW only)
        for (int i = lane; i < 576; i += 64) {
            int pix = i >> 2, q = i & 3;
            int r = pix / 12, c = pix - r * 12;
            int y = y0 - 2 + r, x = x0 - 2 + c;
            float4 v = make_float4(0.f, 0.f, 0.f, 0.f);
            if ((unsigned)y < 64u && (unsigned)x < 64u)
                v = *(const float4*)&xt[((size_t)((n * 64 + y) * 64 + x)) * 128 + ch0 + q * 4];
            *(float4*)&slab[(r * 12 + c) * 20 + q * 4] = v;
        }

        const float* ctr = &slab[((ty + 2) * 12 + tx + 2) * 20];
        float4 c0 = *(const float4*)(ctr + 0);
        float4 c1 = *(const float4*)(ctr + 4);
        float4 c2 = *(const float4*)(ctr + 8);
        float4 c3 = *(const float4*)(ctr + 12);
#pragma unroll
        for (int di = 0; di < 5; ++di)
#pragma unroll
            for (int dj = 0; dj < 5; ++dj) {
                const float* np = &slab[((ty + di) * 12 + tx + dj) * 20];
                float4 v0 = *(const float4*)(np + 0);
                float4 v1 = *(const float4*)(np + 4);
                float4 v2 = *(const float4*)(np + 8);
                float4 v3 = *(const float4*)(np + 12);
                float d = d2p[di * 5 + dj];
                float e;
                e = c0.x - v0.x; d = fmaf(e, e, d);
                e = c0.y - v0.y; d = fmaf(e, e, d);
                e = c0.z - v0.z; d = fmaf(e, e, d);
                e = c0.w - v0.w; d = fmaf(e, e, d);
                e = c1.x - v1.x; d = fmaf(e, e, d);
                e = c1.y - v1.y; d = fmaf(e, e, d);
                e = c1.z - v1.z; d = fmaf(e, e, d);
                e = c1.w - v1.w; d = fmaf(e, e, d);
                e = c2.x - v2.x; d = fmaf(e, e, d);
                e = c2.y - v2.y; d = fmaf(e, e, d);
                e = c2.z - v2.z; d = fmaf(e, e, d);
                e = c2.w - v2.w; d = fmaf(e, e, d);
                e = c3.x - v3.x; d = fmaf(e, e, d);
                e = c3.y - v3.y; d = fmaf(e, e, d);
                e = c3.z - v3.z; d = fmaf(e, e, d);
                e = c3.w - v3.w; d = fmaf(e, e, d);
                d2p[di * 5 + dj] = d;
            }
    }

    // write d2 partials into own slab (each wave overwrites only its slab)
#pragma unroll
    for (int j = 0; j < 25; ++j) slab[lane * 25 + j] = d2p[j];
    __syncthreads();

    // sum across waves + exp, write wgt into slab 0 (distinct (px,j) per thread)
    const float minus_inv2s2 = -1.0f / (2.0f * 0.02f * 0.02f); // -1250
    for (int i = tid; i < 1600; i += 256) {
        float d = fl[i] + fl[2880 + i] + fl[5760 + i] + fl[8640 + i];
        fl[i] = expf(d * minus_inv2s2);
    }
    __syncthreads();

    // epilogue: lane = pixel; wave w handles classes 2w, 2w+1
    float wgt[25];
    float w1 = 0.f;
#pragma unroll
    for (int j = 0; j < 25; ++j) { wgt[j] = fl[lane * 25 + j]; w1 += wgt[j]; }
#pragma unroll
    for (int kk = 0; kk < 2; ++kk) {
        int k = w * 2 + kk;
        float s = 0.f;
#pragma unroll
        for (int di = 0; di < 5; ++di)
#pragma unroll
            for (int dj = 0; dj < 5; ++dj)
                s = fmaf(wgt[di * 5 + dj], sl[k][ty + di][tx + dj], s);
        float sc = sl[k][ty + 2][tx + 2];
        float numk = s * sc;
        float denk = w1 * sc;
#pragma unroll
        for (int sh = 32; sh > 0; sh >>= 1) {
            numk += __shfl_xor(numk, sh, 64);
            denk += __shfl_xor(denk, sh, 64);
        }
        if (lane == 0) {
            part[(size_t)obid * 16 + k * 2] = numk;
            part[(size_t)obid * 16 + k * 2 + 1] = denk;
        }
    }
}

// ---------------- modularity on images (partials, no atomics) ----------------
__global__ __launch_bounds__(64) void modularity128_v3(
    const float* __restrict__ it,   // (4,128,128,3) normalized
    const float* __restrict__ seg,  // (4,8,128,128)
    float* __restrict__ part)       // [1024][16]
{
    __shared__ float il[12][12][4];
    __shared__ float sl[8][12][14];

    int t = threadIdx.x;
    int tx = t & 7, ty = t >> 3;
    int obid = blockIdx.x;
    int bid = obid;                    // n(4) x by(16) x bx(16)
    int bx = bid & 15; bid >>= 4;
    int by = bid & 15; bid >>= 4;
    int n = bid;
    int x0 = bx * 8, y0 = by * 8;

    for (int i = t; i < 144; i += 64) {
        int r = i / 12, c = i - r * 12;
        int y = y0 - 2 + r, x = x0 - 2 + c;
        float3 v = make_float3(0.f, 0.f, 0.f);
        if ((unsigned)y < 128u && (unsigned)x < 128u) {
            const float* p = it + ((size_t)((n * 128 + y) * 128 + x)) * 3;
            v.x = p[0]; v.y = p[1]; v.z = p[2];
        }
        il[r][c][0] = v.x; il[r][c][1] = v.y; il[r][c][2] = v.z;
    }
    for (int i = t; i < 8 * 144; i += 64) {
        int k = i / 144;
        int rem = i - k * 144;
        int r = rem / 12, c = rem - r * 12;
        int y = y0 - 2 + r, x = x0 - 2 + c;
        float v = 0.f;
        if ((unsigned)y < 128u && (unsigned)x < 128u)
            v = seg[((size_t)(n * 8 + k) * 128 + y) * 128 + x];
        sl[k][r][c] = v;
    }
    __syncthreads();

    const float minus_inv2s2 = -1.0f / (2.0f * 0.2f * 0.2f); // -12.5
    float c0 = il[ty + 2][tx + 2][0];
    float c1 = il[ty + 2][tx + 2][1];
    float c2 = il[ty + 2][tx + 2][2];

    float wgt[25];
    float w1 = 0.f;
#pragma unroll
    for (int di = 0; di < 5; ++di)
#pragma unroll
        for (int dj = 0; dj < 5; ++dj) {
            int y2 = y0 + ty + di - 2, x2 = x0 + tx + dj - 2;
            float bias = ((unsigned)y2 < 128u && (unsigned)x2 < 128u) ? 0.f : 1e30f;
            const float* np = &il[ty + di][tx + dj][0];
            float e0 = c0 - np[0], e1 = c1 - np[1], e2 = c2 - np[2];
            float d = bias + fmaf(e2, e2, fmaf(e1, e1, e0 * e0));
            float wv = expf(d * minus_inv2s2);
            wgt[di * 5 + dj] = wv;
            w1 += wv;
        }

#pragma unroll
    for (int k = 0; k < 8; ++k) {
        float s = 0.f;
#pragma unroll
        for (int di = 0; di < 5; ++di)
#pragma unroll
            for (int dj = 0; dj < 5; ++dj)
                s = fmaf(wgt[di * 5 + dj], sl[k][ty + di][tx + dj], s);
        float sc = sl[k][ty + 2][tx + 2];
        float numk = s * sc;
        float denk = w1 * sc;
#pragma unroll
        for (int sft = 32; sft > 0; sft >>= 1) {
            numk += __shfl_xor(numk, sft, 64);
            denk += __shfl_xor(denk, sft, 64);
        }
        if (t == 0) {
            part[(size_t)obid * 16 + k * 2] = numk;
            part[(size_t)obid * 16 + k * 2 + 1] = denk;
        }
    }
}

// ---------------- reduce modularity partials ----------------
__global__ __launch_bounds__(256) void reduce_mod(const float* __restrict__ p64,
                                                  const float* __restrict__ p128,
                                                  float* __restrict__ red)
{
    int j = blockIdx.x;        // 0..31 VGG, 32..63 IMG
    int t = threadIdx.x;       // 256
    float num = 0.f, den = 0.f;
    if (j < 32) {
        int n = j >> 3, k = j & 7;
        if (t < 64) {
            const float* p = p64 + ((size_t)(n * 64 + t)) * 16 + k * 2;
            num = p[0]; den = p[1];
        }
    } else {
        int jj = j - 32;
        int n = jj >> 3, k = jj & 7;
        const float* p = p128 + ((size_t)(n * 256 + t)) * 16 + k * 2;
        num = p[0]; den = p[1];
    }
    __shared__ float ln[256], ld[256];
    ln[t] = num; ld[t] = den;
    __syncthreads();
    for (int s = 128; s > 0; s >>= 1) {
        if (t < s) { ln[t] += ln[t + s]; ld[t] += ld[t + s]; }
        __syncthreads();
    }
    if (t == 0) { red[j * 2] = ln[0]; red[j * 2 + 1] = ld[0]; }
}

__global__ void finalize_k(const float* __restrict__ red, float* __restrict__ out)
{
    int l = threadIdx.x;   // 64
    float v = red[l * 2] / red[l * 2 + 1];
#pragma unroll
    for (int s = 32; s > 0; s >>= 1) v += __shfl_xor(v, s, 64);
    if (l == 0) out[0] = v * (1.0f / 64.0f);
}

extern "C" void kernel_launch(void* const* d_in, const int* in_sizes, int n_in,
                              void* d_out, int out_size, void* d_ws, size_t ws_size,
                              hipStream_t stream)
{
    const float* images = (const float*)d_in[0];
    const float* seg    = (const float*)d_in[1];
    const float* w1 = (const float*)d_in[2]; const float* b1 = (const float*)d_in[3];
    const float* w2 = (const float*)d_in[4]; const float* b2 = (const float*)d_in[5];
    const float* w3 = (const float*)d_in[6]; const float* b3 = (const float*)d_in[7];
    const float* w4 = (const float*)d_in[8]; const float* b4 = (const float*)d_in[9];
    float* out = (float*)d_out;
    char* ws = (char*)d_ws;
    short* C2   = (short*)(ws + OFF_C2);
    short* PAD2 = (short*)(ws + OFF_PAD2);
    short* PAD3 = (short*)(ws + OFF_PAD3);
    short* PAD4 = (short*)(ws + OFF_PAD4);
    float* FICH = (float*)(ws + OFF_FICH);
    short* WP2  = (short*)(ws + OFF_WP2);
    short* WP3  = (short*)(ws + OFF_WP3);
    short* WP4  = (short*)(ws + OFF_WP4);
    float* DS   = (float*)(ws + OFF_DS);
    float* IT   = (float*)(ws + OFF_IT);
    float* ST   = (float*)(ws + OFF_ST);
    float* RED  = (float*)(ws + OFF_RED);
    float* P64  = (float*)(ws + OFF_P64);
    float* P128 = (float*)(ws + OFF_P128);
    float* PBN  = (float*)(ws + OFF_PBN);
    float* PIMG = (float*)(ws + OFF_PIMG);

    // zero halos
    hipMemsetAsync(PAD2, 0, PAD2_BYTES, stream);
    hipMemsetAsync(PAD3, 0, PAD3_BYTES, stream);
    hipMemsetAsync(PAD4, 0, PAD4_BYTES, stream);

    // weight prepack (bf16 fragment order)
    prepack_w<<<144, 256, 0, stream>>>(w2, WP2, 64, 4, 36864);
    prepack_w<<<288, 256, 0, stream>>>(w3, WP3, 64, 8, 73728);
    prepack_w<<<576, 256, 0, stream>>>(w4, WP4, 128, 8, 147456);

    // image BN stats early (overlaps with conv stem work)
    bnsum_img<<<192, 256, 0, stream>>>(images, PIMG);
    stats_img_fin<<<1, 192, 0, stream>>>(PIMG, ST + 256);

    // VGG stem
    conv1_bf16<<<2048, 256, 0, stream>>>(images, w1, b1, PAD2);
    conv_mfma<64, 64, 128, 128, 0><<<2048, 256, 0, stream>>>(PAD2, WP2, b2, C2);
    maxpool_nhwc<<<512, 256, 0, stream>>>((const ushortT*)C2, (ushortT*)PAD3);
    conv_mfma<64, 128, 64, 64, 1><<<1024, 256, 0, stream>>>(PAD3, WP3, b3, PAD4);
    conv_mfma<128, 128, 64, 64, 2><<<1024, 256, 0, stream>>>(PAD4, WP4, b4, FICH);

    // BN (scale-only; mean cancels in d2)
    bnsum_nhwc<<<256, 256, 0, stream>>>(FICH, PBN);
    stats_fin<<<128, 256, 0, stream>>>(PBN, ST);
    scale_fich<<<2048, 256, 0, stream>>>(FICH, ST);

    // image branch
    norm_transpose_i_k<<<256, 256, 0, stream>>>(images, ST + 256, IT);
    avgpool2_k<<<512, 256, 0, stream>>>(seg, DS, 131072);

    // modularity terms -> per-block partials -> tree reduce
    modularity64_v4<<<256, 256, 0, stream>>>(FICH, DS, P64);
    modularity128_v3<<<1024, 64, 0, stream>>>(IT, seg, P128);
    reduce_mod<<<64, 256, 0, stream>>>(P64, P128, RED);

    finalize_k<<<1, 64, 0, stream>>>(RED, out);
}

// Round 14
// 211.043 us; speedup vs baseline: 2.1748x; 1.0758x over previous
//
#include <hip/hip_runtime.h>
#include <hip/hip_bf16.h>
#include <math.h>

typedef __attribute__((ext_vector_type(8))) short short8;
typedef __attribute__((ext_vector_type(4))) float floatx4;
typedef unsigned short ushortT;

__device__ inline short f2bf(float v) {
    __hip_bfloat16 h = __float2bfloat16(v);
    union { __hip_bfloat16 h; short s; } u; u.h = h; return u.s;
}

// ---------------- workspace layout (bytes), all disjoint ----------------
#define OFF_C2    0
#define OFF_PAD4  8388608
#define OFF_FICH  12849152
#define OFF_PAD2  21237760
#define OFF_PAD3  29890560
#define OFF_WP2   32120832
#define OFF_WP3   32194560
#define OFF_WP4   32342016
#define OFF_ST    33947648   // [0..127] rstdF; [256..261] img mean(3)+rstd(3)
#define OFF_P64   33951744   // 256 x 16 floats mod64 partials
#define OFF_P128  33968128   // 1024 x 16 floats mod128 partials
#define OFF_PBN   34033664   // 256 x 256 floats bnsum partials
#define OFF_PIMG  34295808   // 192 x 2 floats image bn partials

// ---------------- halo zero: only pad borders (interiors fully overwritten) --
__global__ __launch_bounds__(256) void halo_zero(char* ws)
{
    int t = blockIdx.x * 256 + threadIdx.x;
    short* base; int Hp, Wp, C; int idx;
    if (t < 16512)      { base = (short*)(ws + OFF_PAD2); Hp = 130; Wp = 130; C = 64;  idx = t; }
    else if (t < 24832) { base = (short*)(ws + OFF_PAD3); Hp = 66;  Wp = 66;  C = 64;  idx = t - 16512; }
    else if (t < 41472) { base = (short*)(ws + OFF_PAD4); Hp = 66;  Wp = 66;  C = 128; idx = t - 24832; }
    else return;
    int c8 = idx % (C / 8); int rest = idx / (C / 8);
    int haloPx = 2 * Wp + 2 * (Hp - 2);
    int p = rest % haloPx; int n = rest / haloPx;
    int y, x;
    if (p < Wp)          { y = 0;      x = p; }
    else if (p < 2 * Wp) { y = Hp - 1; x = p - Wp; }
    else { int j = p - 2 * Wp; y = 1 + (j >> 1); x = (j & 1) ? (Wp - 1) : 0; }
    short8 z = {0, 0, 0, 0, 0, 0, 0, 0};
    *(short8*)&base[((size_t)((n * Hp + y) * Wp) + x) * C + c8 * 8] = z;
}

// ---------------- conv1: fp32 direct (Cin=3), writes bf16 NHWC padded --------
__global__ __launch_bounds__(256) void conv1_bf16(
    const float* __restrict__ in, const float* __restrict__ w,
    const float* __restrict__ b, short* __restrict__ outp)
{
    int bid = blockIdx.x;                 // 4n x 8ocg x 8ty x 8tx
    int txt = bid & 7; bid >>= 3;
    int tyt = bid & 7; bid >>= 3;
    int ocg = bid & 7; bid >>= 3;
    int n = bid;
    int x0 = txt * 16, y0 = tyt * 16;
    int tid = threadIdx.x;
    int tx = tid & 15, ty = tid >> 4;

    __shared__ float lds[3 * 720];
    for (int i = tid; i < 972; i += 256) {
        int cc = i / 324; int rem = i - cc * 324;
        int r = rem / 18, c = rem - r * 18;
        int y = y0 - 1 + r, x = x0 - 1 + c;
        float v = 0.f;
        if ((unsigned)y < 128u && (unsigned)x < 128u)
            v = in[((size_t)(n * 3 + cc) * 128 + y) * 128 + x];
        lds[cc * 720 + r * 40 + c] = v;
    }
    __syncthreads();

    float acc[8];
#pragma unroll
    for (int oc = 0; oc < 8; ++oc) acc[oc] = 0.f;
    const float* w_g = w + (size_t)(ocg * 8) * 27;
#pragma unroll
    for (int cc = 0; cc < 3; ++cc) {
        const float* base = &lds[cc * 720 + ty * 40 + tx];
        float i00 = base[0],  i01 = base[1],  i02 = base[2];
        float i10 = base[40], i11 = base[41], i12 = base[42];
        float i20 = base[80], i21 = base[81], i22 = base[82];
        const float* wp = w_g + cc * 9;
#pragma unroll
        for (int oc = 0; oc < 8; ++oc) {
            const float* wq = wp + oc * 27;
            float a = acc[oc];
            a = fmaf(wq[0], i00, a); a = fmaf(wq[1], i01, a); a = fmaf(wq[2], i02, a);
            a = fmaf(wq[3], i10, a); a = fmaf(wq[4], i11, a); a = fmaf(wq[5], i12, a);
            a = fmaf(wq[6], i20, a); a = fmaf(wq[7], i21, a); a = fmaf(wq[8], i22, a);
            acc[oc] = a;
        }
    }
    int oy = y0 + ty, ox = x0 + tx;
    short* o = outp + ((size_t)(n * 130 + oy + 1) * 130 + ox + 1) * 64 + ocg * 8;
#pragma unroll
    for (int oc = 0; oc < 8; ++oc) {
        float v = fmaxf(acc[oc] + b[ocg * 8 + oc], 0.f);
        o[oc] = f2bf(v);
    }
}

// ---------------- weight prepack (all three convs in one launch) -------------
__global__ void prepack_all(const float* __restrict__ w2, const float* __restrict__ w3,
                            const float* __restrict__ w4, short* __restrict__ wp2,
                            short* __restrict__ wp3, short* __restrict__ wp4)
{
    int e = blockIdx.x * 256 + threadIdx.x;
    const float* w; short* wp; int CIN, NTALL;
    if (e < 36864)       { w = w2; wp = wp2; CIN = 64;  NTALL = 4; }
    else if (e < 110592) { e -= 36864;  w = w3; wp = wp3; CIN = 64;  NTALL = 8; }
    else if (e < 258048) { e -= 110592; w = w4; wp = wp4; CIN = 128; NTALL = 8; }
    else return;
    int j = e & 7; int L = (e >> 3) & 63; int rest = e >> 9;
    int nt = rest % NTALL; int rest2 = rest / NTALL;
    int KT = CIN / 32;
    int kt = rest2 % KT; int t = rest2 / KT;
    int oc = nt * 16 + (L & 15);
    int ci = kt * 32 + (L >> 4) * 8 + j;
    wp[e] = f2bf(w[((size_t)oc * CIN + ci) * 9 + t]);
}

// ---------------- MFMA implicit-GEMM 3x3 conv --------------------------------
template<int CIN, int COUT, int H, int W, int OUTMODE>
__global__ __launch_bounds__(256) void conv_mfma(
    const short* __restrict__ inp, const short* __restrict__ wp,
    const float* __restrict__ bias, void* __restrict__ outv)
{
    constexpr int KT = CIN / 32;
    constexpr int NTALL = COUT / 16;
    constexpr int NTB = COUT / 64;
    constexpr int TPR = W / 32;
    constexpr int Hp = H + 2, Wp = W + 2;

    int bm = blockIdx.x / NTB;
    int bn = blockIdx.x - bm * NTB;
    int n = bm / (H * TPR);
    int rem = bm - n * (H * TPR);
    int y = rem / TPR;
    int x0 = (rem - y * TPR) * 32;

    int tid = threadIdx.x;
    int wv = tid >> 6, lane = tid & 63;
    int lm = lane & 15, q = lane >> 4;
    int px0 = x0 + 16 * (wv & 1);
    int ntb = bn * 4 + (wv >> 1) * 2;

    floatx4 acc0 = {0.f, 0.f, 0.f, 0.f};
    floatx4 acc1 = {0.f, 0.f, 0.f, 0.f};

    const short* a_m = inp + lm * CIN + q * 8;
    const short* wbase = wp + ((size_t)ntb * 64 + lane) * 8;

    for (int kt = 0; kt < KT; ++kt) {
        int kofs = kt * 32;
#pragma unroll
        for (int r = 0; r < 3; ++r) {
            const short* arow = a_m + (size_t)((n * Hp + y + r) * Wp + px0) * CIN + kofs;
#pragma unroll
            for (int s = 0; s < 3; ++s) {
                short8 av = *(const short8*)(arow + s * CIN);
                const short* bp = wbase + (size_t)(((r * 3 + s) * KT + kt) * NTALL) * 512;
                short8 b0 = *(const short8*)bp;
                short8 b1 = *(const short8*)(bp + 512);
                acc0 = __builtin_amdgcn_mfma_f32_16x16x32_bf16(av, b0, acc0, 0, 0, 0);
                acc1 = __builtin_amdgcn_mfma_f32_16x16x32_bf16(av, b1, acc1, 0, 0, 0);
            }
        }
    }

#pragma unroll
    for (int half = 0; half < 2; ++half) {
        floatx4 a = half ? acc1 : acc0;
        int oc = (ntb + half) * 16 + lm;
        float bs = bias[oc];
#pragma unroll
        for (int i = 0; i < 4; ++i) {
            int px = px0 + q * 4 + i;
            float v = fmaxf(a[i] + bs, 0.f);
            if constexpr (OUTMODE == 0) {
                ((short*)outv)[((size_t)(n * H + y) * W + px) * COUT + oc] = f2bf(v);
            } else if constexpr (OUTMODE == 1) {
                ((short*)outv)[((size_t)(n * Hp + y + 1) * Wp + px + 1) * COUT + oc] = f2bf(v);
            } else {
                ((float*)outv)[((size_t)(n * H + y) * W + px) * COUT + oc] = v;
            }
        }
    }
}

// ---------------- 2x2 maxpool, bf16 NHWC -> padded NHWC ----------------------
__global__ __launch_bounds__(256) void maxpool_nhwc(const ushortT* __restrict__ in,
                                                    ushortT* __restrict__ outp)
{
    int gid = blockIdx.x * 256 + threadIdx.x;   // 131072
    int c8 = gid & 7; int rest = gid >> 3;
    int xo = rest & 63, yo = (rest >> 6) & 63, n = rest >> 12;
    const ushortT* p = in + ((size_t)(n * 128 + yo * 2) * 128 + xo * 2) * 64 + c8 * 8;
    const ushortT* p01 = p + 64;
    const ushortT* p10 = p + 128 * 64;
    const ushortT* p11 = p10 + 64;
    ushortT* o = outp + ((size_t)(n * 66 + yo + 1) * 66 + xo + 1) * 64 + c8 * 8;
#pragma unroll
    for (int j = 0; j < 8; ++j) {
        ushortT a = p[j] > p01[j] ? p[j] : p01[j];
        ushortT b = p10[j] > p11[j] ? p10[j] : p11[j];
        o[j] = a > b ? a : b;
    }
}

// ---------------- BN over NHWC fich: per-block partials ----------------------
__global__ __launch_bounds__(256) void bnsum_nhwc(const float* __restrict__ x,
                                                  float* __restrict__ part)
{
    int tid = threadIdx.x;
    int c = tid & 127;
    int h = tid >> 7;
    int p0 = blockIdx.x * 64 + h * 32;
    float s = 0.f, s2 = 0.f;
    for (int p = p0; p < p0 + 32; ++p) {
        float v = x[(size_t)p * 128 + c];
        s += v; s2 = fmaf(v, v, s2);
    }
    __shared__ float rs[256], rs2[256];
    rs[tid] = s; rs2[tid] = s2;
    __syncthreads();
    if (tid < 128) {
        part[(size_t)blockIdx.x * 256 + tid] = rs[tid] + rs[tid + 128];
        part[(size_t)blockIdx.x * 256 + 128 + tid] = rs2[tid] + rs2[tid + 128];
    }
}

__global__ __launch_bounds__(256) void stats_fin(const float* __restrict__ part,
                                                 float* __restrict__ st)
{
    int c = blockIdx.x;     // 128
    int t = threadIdx.x;    // 256
    float s  = part[(size_t)t * 256 + c];
    float s2 = part[(size_t)t * 256 + 128 + c];
    __shared__ float rs[256], rs2[256];
    rs[t] = s; rs2[t] = s2;
    __syncthreads();
    for (int k = 128; k > 0; k >>= 1) {
        if (t < k) { rs[t] += rs[t + k]; rs2[t] += rs2[t + k]; }
        __syncthreads();
    }
    if (t == 0) {
        float mean = rs[0] * (1.f / 16384.f);
        float var = rs2[0] * (1.f / 16384.f) - mean * mean;
        st[c] = 1.f / sqrtf(var + 1e-5f);
    }
}

// ---------------- image BN: parallel partials --------------------------------
__global__ __launch_bounds__(256) void bnsum_img(const float* __restrict__ x,
                                                 float* __restrict__ part)
{
    int b = blockIdx.x;          // c(3) x chunk(64)
    int c = b >> 6, chunk = b & 63;
    int t = threadIdx.x;
    int base = chunk * 1024 + t;
    float s = 0.f, s2 = 0.f;
#pragma unroll
    for (int k = 0; k < 4; ++k) {
        int i = base + k * 256;
        int n = i >> 14, hw = i & 16383;
        float v = x[(((size_t)(n * 3 + c)) << 14) + hw];
        s += v; s2 = fmaf(v, v, s2);
    }
    __shared__ float rs[256], rs2[256];
    rs[t] = s; rs2[t] = s2;
    __syncthreads();
    for (int k = 128; k > 0; k >>= 1) {
        if (t < k) { rs[t] += rs[t + k]; rs2[t] += rs2[t + k]; }
        __syncthreads();
    }
    if (t == 0) { part[b * 2] = rs[0]; part[b * 2 + 1] = rs2[0]; }
}

__global__ void stats_img_fin(const float* __restrict__ part, float* __restrict__ st)
{
    int t = threadIdx.x;          // 192 = 3 waves
    int c = t >> 6, idx = t & 63;
    float s  = part[(c * 64 + idx) * 2];
    float s2 = part[(c * 64 + idx) * 2 + 1];
#pragma unroll
    for (int sh = 32; sh > 0; sh >>= 1) {
        s += __shfl_xor(s, sh, 64);
        s2 += __shfl_xor(s2, sh, 64);
    }
    if (idx == 0) {
        float mean = s * (1.f / 65536.f);
        float var = s2 * (1.f / 65536.f) - mean * mean;
        st[c] = mean;
        st[3 + c] = 1.f / sqrtf(var + 1e-5f);
    }
}

// ---------------- modularity on VGG features v5 ------------------------------
// v4 structure + BN scale folded into feature staging (FICH stays raw) +
// seg 2x2-avgpool folded into seg staging (no DS buffer / avgpool kernel).
__global__ __launch_bounds__(256) void modularity64_v5(
    const float* __restrict__ xt,   // (4,64,64,128) RAW fich
    const float* __restrict__ seg,  // (4,8,128,128) full-res seg
    const float* __restrict__ st,   // [0..127] rstd
    float* __restrict__ part)       // [256][16]
{
    __shared__ float fl[4 * 2880];
    __shared__ float sl[8][12][14];

    int tid = threadIdx.x;
    int w = tid >> 6, lane = tid & 63;
    int tx = lane & 7, ty = lane >> 3;
    int obid = blockIdx.x;
    int bid = obid;
    int bx = bid & 7; bid >>= 3;
    int by = bid & 7; bid >>= 3;
    int n = bid;
    int x0 = bx * 8, y0 = by * 8;

    // stage seg tile with inline 2x2 avgpool (downsample 128 -> 64)
    for (int i = tid; i < 8 * 144; i += 256) {
        int k = i / 144;
        int rem = i - k * 144;
        int r = rem / 12, c = rem - r * 12;
        int y = y0 - 2 + r, x = x0 - 2 + c;
        float v = 0.f;
        if ((unsigned)y < 64u && (unsigned)x < 64u) {
            const float* p = seg + ((size_t)(n * 8 + k) * 128 + 2 * y) * 128 + 2 * x;
            float2 a = *(const float2*)p;
            float2 b = *(const float2*)(p + 128);
            v = 0.25f * ((a.x + a.y) + (b.x + b.y));
        }
        sl[k][r][c] = v;
    }

    float* slab = fl + w * 2880;

    float d2p[25];
#pragma unroll
    for (int di = 0; di < 5; ++di)
#pragma unroll
        for (int dj = 0; dj < 5; ++dj) {
            int y2 = y0 + ty + di - 2, x2 = x0 + tx + dj - 2;
            float bias = ((unsigned)y2 < 64u && (unsigned)x2 < 64u) ? 0.f : 1e30f;
            d2p[di * 5 + dj] = (w == 0) ? bias : 0.f;
        }

    for (int r8 = 0; r8 < 2; ++r8) {
        int ch0 = w * 32 + r8 * 16;
        for (int i = lane; i < 576; i += 64) {
            int pix = i >> 2, q = i & 3;
            int r = pix / 12, c = pix - r * 12;
            int y = y0 - 2 + r, x = x0 - 2 + c;
            float4 v = make_float4(0.f, 0.f, 0.f, 0.f);
            if ((unsigned)y < 64u && (unsigned)x < 64u) {
                v = *(const float4*)&xt[((size_t)((n * 64 + y) * 64 + x)) * 128 + ch0 + q * 4];
                float4 sv = *(const float4*)&st[ch0 + q * 4];
                v.x *= sv.x; v.y *= sv.y; v.z *= sv.z; v.w *= sv.w;
            }
            *(float4*)&slab[(r * 12 + c) * 20 + q * 4] = v;
        }

        const float* ctr = &slab[((ty + 2) * 12 + tx + 2) * 20];
        float4 c0 = *(const float4*)(ctr + 0);
        float4 c1 = *(const float4*)(ctr + 4);
        float4 c2 = *(const float4*)(ctr + 8);
        float4 c3 = *(const float4*)(ctr + 12);
#pragma unroll
        for (int di = 0; di < 5; ++di)
#pragma unroll
            for (int dj = 0; dj < 5; ++dj) {
                const float* np = &slab[((ty + di) * 12 + tx + dj) * 20];
                float4 v0 = *(const float4*)(np + 0);
                float4 v1 = *(const float4*)(np + 4);
                float4 v2 = *(const float4*)(np + 8);
                float4 v3 = *(const float4*)(np + 12);
                float d = d2p[di * 5 + dj];
                float e;
                e = c0.x - v0.x; d = fmaf(e, e, d);
                e = c0.y - v0.y; d = fmaf(e, e, d);
                e = c0.z - v0.z; d = fmaf(e, e, d);
                e = c0.w - v0.w; d = fmaf(e, e, d);
                e = c1.x - v1.x; d = fmaf(e, e, d);
                e = c1.y - v1.y; d = fmaf(e, e, d);
                e = c1.z - v1.z; d = fmaf(e, e, d);
                e = c1.w - v1.w; d = fmaf(e, e, d);
                e = c2.x - v2.x; d = fmaf(e, e, d);
                e = c2.y - v2.y; d = fmaf(e, e, d);
                e = c2.z - v2.z; d = fmaf(e, e, d);
                e = c2.w - v2.w; d = fmaf(e, e, d);
                e = c3.x - v3.x; d = fmaf(e, e, d);
                e = c3.y - v3.y; d = fmaf(e, e, d);
                e = c3.z - v3.z; d = fmaf(e, e, d);
                e = c3.w - v3.w; d = fmaf(e, e, d);
                d2p[di * 5 + dj] = d;
            }
    }

#pragma unroll
    for (int j = 0; j < 25; ++j) slab[lane * 25 + j] = d2p[j];
    __syncthreads();

    const float minus_inv2s2 = -1.0f / (2.0f * 0.02f * 0.02f); // -1250
    for (int i = tid; i < 1600; i += 256) {
        float d = fl[i] + fl[2880 + i] + fl[5760 + i] + fl[8640 + i];
        fl[i] = expf(d * minus_inv2s2);
    }
    __syncthreads();

    float wgt[25];
    float w1 = 0.f;
#pragma unroll
    for (int j = 0; j < 25; ++j) { wgt[j] = fl[lane * 25 + j]; w1 += wgt[j]; }
#pragma unroll
    for (int kk = 0; kk < 2; ++kk) {
        int k = w * 2 + kk;
        float s = 0.f;
#pragma unroll
        for (int di = 0; di < 5; ++di)
#pragma unroll
            for (int dj = 0; dj < 5; ++dj)
                s = fmaf(wgt[di * 5 + dj], sl[k][ty + di][tx + dj], s);
        float sc = sl[k][ty + 2][tx + 2];
        float numk = s * sc;
        float denk = w1 * sc;
#pragma unroll
        for (int sh = 32; sh > 0; sh >>= 1) {
            numk += __shfl_xor(numk, sh, 64);
            denk += __shfl_xor(denk, sh, 64);
        }
        if (lane == 0) {
            part[(size_t)obid * 16 + k * 2] = numk;
            part[(size_t)obid * 16 + k * 2 + 1] = denk;
        }
    }
}

// ---------------- modularity on images v4: normalization folded in ----------
__global__ __launch_bounds__(64) void modularity128_v4(
    const float* __restrict__ img,  // (4,3,128,128) raw
    const float* __restrict__ stm,  // [0..2] mean, [3..5] rstd
    const float* __restrict__ seg,  // (4,8,128,128)
    float* __restrict__ part)       // [1024][16]
{
    __shared__ float il[12][12][4];
    __shared__ float sl[8][12][14];

    int t = threadIdx.x;
    int tx = t & 7, ty = t >> 3;
    int obid = blockIdx.x;
    int bid = obid;                    // n(4) x by(16) x bx(16)
    int bx = bid & 15; bid >>= 4;
    int by = bid & 15; bid >>= 4;
    int n = bid;
    int x0 = bx * 8, y0 = by * 8;

    float mn0 = stm[0], mn1 = stm[1], mn2 = stm[2];
    float rs0 = stm[3], rs1 = stm[4], rs2 = stm[5];

    for (int i = t; i < 432; i += 64) {
        int ch = i / 144; int pix = i - ch * 144;
        int r = pix / 12, c = pix - r * 12;
        int y = y0 - 2 + r, x = x0 - 2 + c;
        float v = 0.f;
        if ((unsigned)y < 128u && (unsigned)x < 128u) {
            float raw = img[(((size_t)(n * 3 + ch)) << 14) + y * 128 + x];
            float mn = ch == 0 ? mn0 : (ch == 1 ? mn1 : mn2);
            float rs = ch == 0 ? rs0 : (ch == 1 ? rs1 : rs2);
            v = (raw - mn) * rs;
        }
        il[r][c][ch] = v;
    }
    for (int i = t; i < 8 * 144; i += 64) {
        int k = i / 144;
        int rem = i - k * 144;
        int r = rem / 12, c = rem - r * 12;
        int y = y0 - 2 + r, x = x0 - 2 + c;
        float v = 0.f;
        if ((unsigned)y < 128u && (unsigned)x < 128u)
            v = seg[((size_t)(n * 8 + k) * 128 + y) * 128 + x];
        sl[k][r][c] = v;
    }
    __syncthreads();

    const float minus_inv2s2 = -1.0f / (2.0f * 0.2f * 0.2f); // -12.5
    float c0 = il[ty + 2][tx + 2][0];
    float c1 = il[ty + 2][tx + 2][1];
    float c2 = il[ty + 2][tx + 2][2];

    float wgt[25];
    float w1 = 0.f;
#pragma unroll
    for (int di = 0; di < 5; ++di)
#pragma unroll
        for (int dj = 0; dj < 5; ++dj) {
            int y2 = y0 + ty + di - 2, x2 = x0 + tx + dj - 2;
            float bias = ((unsigned)y2 < 128u && (unsigned)x2 < 128u) ? 0.f : 1e30f;
            const float* np = &il[ty + di][tx + dj][0];
            float e0 = c0 - np[0], e1 = c1 - np[1], e2 = c2 - np[2];
            float d = bias + fmaf(e2, e2, fmaf(e1, e1, e0 * e0));
            float wv = expf(d * minus_inv2s2);
            wgt[di * 5 + dj] = wv;
            w1 += wv;
        }

#pragma unroll
    for (int k = 0; k < 8; ++k) {
        float s = 0.f;
#pragma unroll
        for (int di = 0; di < 5; ++di)
#pragma unroll
            for (int dj = 0; dj < 5; ++dj)
                s = fmaf(wgt[di * 5 + dj], sl[k][ty + di][tx + dj], s);
        float sc = sl[k][ty + 2][tx + 2];
        float numk = s * sc;
        float denk = w1 * sc;
#pragma unroll
        for (int sft = 32; sft > 0; sft >>= 1) {
            numk += __shfl_xor(numk, sft, 64);
            denk += __shfl_xor(denk, sft, 64);
        }
        if (t == 0) {
            part[(size_t)obid * 16 + k * 2] = numk;
            part[(size_t)obid * 16 + k * 2 + 1] = denk;
        }
    }
}

// ---------------- reduce partials + finalize in one dispatch -----------------
__global__ __launch_bounds__(1024) void reduce_finalize(
    const float* __restrict__ p64, const float* __restrict__ p128,
    float* __restrict__ out)
{
    int t = threadIdx.x;          // 1024
    int j = t >> 4, s = t & 15;   // 64 groups x 16 threads
    float num = 0.f, den = 0.f;
    if (j < 32) {
        int n = j >> 3, k = j & 7;
#pragma unroll
        for (int i = 0; i < 4; ++i) {
            int b = s * 4 + i;
            const float* p = p64 + ((size_t)(n * 64 + b)) * 16 + k * 2;
            num += p[0]; den += p[1];
        }
    } else {
        int jj = j - 32; int n = jj >> 3, k = jj & 7;
#pragma unroll
        for (int i = 0; i < 16; ++i) {
            int b = s * 16 + i;
            const float* p = p128 + ((size_t)(n * 256 + b)) * 16 + k * 2;
            num += p[0]; den += p[1];
        }
    }
#pragma unroll
    for (int sh = 8; sh > 0; sh >>= 1) {
        num += __shfl_xor(num, sh, 16);
        den += __shfl_xor(den, sh, 16);
    }
    __shared__ float rn[64], rd[64];
    if (s == 0) { rn[j] = num; rd[j] = den; }
    __syncthreads();
    if (t < 64) {
        float v = rn[t] / rd[t];
#pragma unroll
        for (int sh = 32; sh > 0; sh >>= 1) v += __shfl_xor(v, sh, 64);
        if (t == 0) out[0] = v * (1.0f / 64.0f);
    }
}

extern "C" void kernel_launch(void* const* d_in, const int* in_sizes, int n_in,
                              void* d_out, int out_size, void* d_ws, size_t ws_size,
                              hipStream_t stream)
{
    const float* images = (const float*)d_in[0];
    const float* seg    = (const float*)d_in[1];
    const float* w1 = (const float*)d_in[2]; const float* b1 = (const float*)d_in[3];
    const float* w2 = (const float*)d_in[4]; const float* b2 = (const float*)d_in[5];
    const float* w3 = (const float*)d_in[6]; const float* b3 = (const float*)d_in[7];
    const float* w4 = (const float*)d_in[8]; const float* b4 = (const float*)d_in[9];
    float* out = (float*)d_out;
    char* ws = (char*)d_ws;
    short* C2   = (short*)(ws + OFF_C2);
    short* PAD2 = (short*)(ws + OFF_PAD2);
    short* PAD3 = (short*)(ws + OFF_PAD3);
    short* PAD4 = (short*)(ws + OFF_PAD4);
    float* FICH = (float*)(ws + OFF_FICH);
    short* WP2  = (short*)(ws + OFF_WP2);
    short* WP3  = (short*)(ws + OFF_WP3);
    short* WP4  = (short*)(ws + OFF_WP4);
    float* ST   = (float*)(ws + OFF_ST);
    float* P64  = (float*)(ws + OFF_P64);
    float* P128 = (float*)(ws + OFF_P128);
    float* PBN  = (float*)(ws + OFF_PBN);
    float* PIMG = (float*)(ws + OFF_PIMG);

    // pad halos (interiors fully written by conv1/maxpool/conv3)
    halo_zero<<<162, 256, 0, stream>>>(ws);

    // weight prepack (one launch)
    prepack_all<<<1008, 256, 0, stream>>>(w2, w3, w4, WP2, WP3, WP4);

    // image BN stats (overlap-ready, cheap)
    bnsum_img<<<192, 256, 0, stream>>>(images, PIMG);
    stats_img_fin<<<1, 192, 0, stream>>>(PIMG, ST + 256);

    // VGG stem
    conv1_bf16<<<2048, 256, 0, stream>>>(images, w1, b1, PAD2);
    conv_mfma<64, 64, 128, 128, 0><<<2048, 256, 0, stream>>>(PAD2, WP2, b2, C2);
    maxpool_nhwc<<<512, 256, 0, stream>>>((const ushortT*)C2, (ushortT*)PAD3);
    conv_mfma<64, 128, 64, 64, 1><<<1024, 256, 0, stream>>>(PAD3, WP3, b3, PAD4);
    conv_mfma<128, 128, 64, 64, 2><<<1024, 256, 0, stream>>>(PAD4, WP4, b4, FICH);

    // fich BN stats (scale applied inside modularity64)
    bnsum_nhwc<<<256, 256, 0, stream>>>(FICH, PBN);
    stats_fin<<<128, 256, 0, stream>>>(PBN, ST);

    // modularity terms -> per-block partials -> single reduce+finalize
    modularity64_v5<<<256, 256, 0, stream>>>(FICH, seg, ST, P64);
    modularity128_v4<<<1024, 64, 0, stream>>>(images, ST + 256, seg, P128);
    reduce_finalize<<<1, 1024, 0, stream>>>(P64, P128, out);
}

// Round 15
// 208.740 us; speedup vs baseline: 2.1988x; 1.0110x over previous
//
#include <hip/hip_runtime.h>
#include <hip/hip_bf16.h>
#include <math.h>

typedef __attribute__((ext_vector_type(8))) short short8;
typedef __attribute__((ext_vector_type(4))) float floatx4;
typedef unsigned short ushortT;

__device__ inline short f2bf(float v) {
    __hip_bfloat16 h = __float2bfloat16(v);
    union { __hip_bfloat16 h; short s; } u; u.h = h; return u.s;
}

// ---------------- workspace layout (bytes), all disjoint ----------------
#define OFF_C2    0
#define OFF_PAD4  8388608
#define OFF_FICH  12849152
#define OFF_PAD2  21237760
#define OFF_PAD3  29890560
#define OFF_WP2   32120832
#define OFF_WP3   32194560
#define OFF_WP4   32342016
#define OFF_ST    33947648   // [0..127] rstdF
#define OFF_P64   33951744   // 256 x 16 floats mod64 partials
#define OFF_P128  33968128   // 1024 x 16 floats mod128 partials
#define OFF_PBN   34033664   // 256 x 256 floats fich bnsum partials
#define OFF_PIMG  34295808   // 192 x 2 floats image bn partials

// ---------------- prologue: halo-zero + weight prepack + image bnsum ---------
// blocks [0,162): zero pad halos; [162,1170): prepack w2/w3/w4; [1170,1362):
// image BN partial sums. All independent.
__global__ __launch_bounds__(256) void prologue(
    char* ws, const float* __restrict__ images,
    const float* __restrict__ w2, const float* __restrict__ w3,
    const float* __restrict__ w4)
{
    int b = blockIdx.x;
    int tid = threadIdx.x;

    if (b < 162) {
        int t = b * 256 + tid;
        short* base; int Hp, Wp, C; int idx;
        if (t < 16512)      { base = (short*)(ws + OFF_PAD2); Hp = 130; Wp = 130; C = 64;  idx = t; }
        else if (t < 24832) { base = (short*)(ws + OFF_PAD3); Hp = 66;  Wp = 66;  C = 64;  idx = t - 16512; }
        else if (t < 41472) { base = (short*)(ws + OFF_PAD4); Hp = 66;  Wp = 66;  C = 128; idx = t - 24832; }
        else return;
        int c8 = idx % (C / 8); int rest = idx / (C / 8);
        int haloPx = 2 * Wp + 2 * (Hp - 2);
        int p = rest % haloPx; int n = rest / haloPx;
        int y, x;
        if (p < Wp)          { y = 0;      x = p; }
        else if (p < 2 * Wp) { y = Hp - 1; x = p - Wp; }
        else { int j = p - 2 * Wp; y = 1 + (j >> 1); x = (j & 1) ? (Wp - 1) : 0; }
        short8 z = {0, 0, 0, 0, 0, 0, 0, 0};
        *(short8*)&base[((size_t)((n * Hp + y) * Wp) + x) * C + c8 * 8] = z;
        return;
    }
    if (b < 1170) {
        int e = (b - 162) * 256 + tid;
        const float* w; short* wp; int CIN, NTALL;
        if (e < 36864)       { w = w2; wp = (short*)(ws + OFF_WP2); CIN = 64;  NTALL = 4; }
        else if (e < 110592) { e -= 36864;  w = w3; wp = (short*)(ws + OFF_WP3); CIN = 64;  NTALL = 8; }
        else if (e < 258048) { e -= 110592; w = w4; wp = (short*)(ws + OFF_WP4); CIN = 128; NTALL = 8; }
        else return;
        int j = e & 7; int L = (e >> 3) & 63; int rest = e >> 9;
        int nt = rest % NTALL; int rest2 = rest / NTALL;
        int KT = CIN / 32;
        int kt = rest2 % KT; int t = rest2 / KT;
        int oc = nt * 16 + (L & 15);
        int ci = kt * 32 + (L >> 4) * 8 + j;
        wp[e] = f2bf(w[((size_t)oc * CIN + ci) * 9 + t]);
        return;
    }
    {
        float* part = (float*)(ws + OFF_PIMG);
        int bb = b - 1170;           // c(3) x chunk(64)
        int c = bb >> 6, chunk = bb & 63;
        int base = chunk * 1024 + tid;
        float s = 0.f, s2 = 0.f;
#pragma unroll
        for (int k = 0; k < 4; ++k) {
            int i = base + k * 256;
            int n = i >> 14, hw = i & 16383;
            float v = images[(((size_t)(n * 3 + c)) << 14) + hw];
            s += v; s2 = fmaf(v, v, s2);
        }
        __shared__ float rs[256], rs2[256];
        rs[tid] = s; rs2[tid] = s2;
        __syncthreads();
        for (int k = 128; k > 0; k >>= 1) {
            if (tid < k) { rs[tid] += rs[tid + k]; rs2[tid] += rs2[tid + k]; }
            __syncthreads();
        }
        if (tid == 0) { part[bb * 2] = rs[0]; part[bb * 2 + 1] = rs2[0]; }
    }
}

// ---------------- conv1: fp32 direct (Cin=3), writes bf16 NHWC padded --------
__global__ __launch_bounds__(256) void conv1_bf16(
    const float* __restrict__ in, const float* __restrict__ w,
    const float* __restrict__ b, short* __restrict__ outp)
{
    int bid = blockIdx.x;                 // 4n x 8ocg x 8ty x 8tx
    int txt = bid & 7; bid >>= 3;
    int tyt = bid & 7; bid >>= 3;
    int ocg = bid & 7; bid >>= 3;
    int n = bid;
    int x0 = txt * 16, y0 = tyt * 16;
    int tid = threadIdx.x;
    int tx = tid & 15, ty = tid >> 4;

    __shared__ float lds[3 * 720];
    for (int i = tid; i < 972; i += 256) {
        int cc = i / 324; int rem = i - cc * 324;
        int r = rem / 18, c = rem - r * 18;
        int y = y0 - 1 + r, x = x0 - 1 + c;
        float v = 0.f;
        if ((unsigned)y < 128u && (unsigned)x < 128u)
            v = in[((size_t)(n * 3 + cc) * 128 + y) * 128 + x];
        lds[cc * 720 + r * 40 + c] = v;
    }
    __syncthreads();

    float acc[8];
#pragma unroll
    for (int oc = 0; oc < 8; ++oc) acc[oc] = 0.f;
    const float* w_g = w + (size_t)(ocg * 8) * 27;
#pragma unroll
    for (int cc = 0; cc < 3; ++cc) {
        const float* base = &lds[cc * 720 + ty * 40 + tx];
        float i00 = base[0],  i01 = base[1],  i02 = base[2];
        float i10 = base[40], i11 = base[41], i12 = base[42];
        float i20 = base[80], i21 = base[81], i22 = base[82];
        const float* wp = w_g + cc * 9;
#pragma unroll
        for (int oc = 0; oc < 8; ++oc) {
            const float* wq = wp + oc * 27;
            float a = acc[oc];
            a = fmaf(wq[0], i00, a); a = fmaf(wq[1], i01, a); a = fmaf(wq[2], i02, a);
            a = fmaf(wq[3], i10, a); a = fmaf(wq[4], i11, a); a = fmaf(wq[5], i12, a);
            a = fmaf(wq[6], i20, a); a = fmaf(wq[7], i21, a); a = fmaf(wq[8], i22, a);
            acc[oc] = a;
        }
    }
    int oy = y0 + ty, ox = x0 + tx;
    short* o = outp + ((size_t)(n * 130 + oy + 1) * 130 + ox + 1) * 64 + ocg * 8;
#pragma unroll
    for (int oc = 0; oc < 8; ++oc) {
        float v = fmaxf(acc[oc] + b[ocg * 8 + oc], 0.f);
        o[oc] = f2bf(v);
    }
}

// ---------------- MFMA implicit-GEMM 3x3 conv --------------------------------
template<int CIN, int COUT, int H, int W, int OUTMODE>
__global__ __launch_bounds__(256) void conv_mfma(
    const short* __restrict__ inp, const short* __restrict__ wp,
    const float* __restrict__ bias, void* __restrict__ outv)
{
    constexpr int KT = CIN / 32;
    constexpr int NTALL = COUT / 16;
    constexpr int NTB = COUT / 64;
    constexpr int TPR = W / 32;
    constexpr int Hp = H + 2, Wp = W + 2;

    int bm = blockIdx.x / NTB;
    int bn = blockIdx.x - bm * NTB;
    int n = bm / (H * TPR);
    int rem = bm - n * (H * TPR);
    int y = rem / TPR;
    int x0 = (rem - y * TPR) * 32;

    int tid = threadIdx.x;
    int wv = tid >> 6, lane = tid & 63;
    int lm = lane & 15, q = lane >> 4;
    int px0 = x0 + 16 * (wv & 1);
    int ntb = bn * 4 + (wv >> 1) * 2;

    floatx4 acc0 = {0.f, 0.f, 0.f, 0.f};
    floatx4 acc1 = {0.f, 0.f, 0.f, 0.f};

    const short* a_m = inp + lm * CIN + q * 8;
    const short* wbase = wp + ((size_t)ntb * 64 + lane) * 8;

    for (int kt = 0; kt < KT; ++kt) {
        int kofs = kt * 32;
#pragma unroll
        for (int r = 0; r < 3; ++r) {
            const short* arow = a_m + (size_t)((n * Hp + y + r) * Wp + px0) * CIN + kofs;
#pragma unroll
            for (int s = 0; s < 3; ++s) {
                short8 av = *(const short8*)(arow + s * CIN);
                const short* bp = wbase + (size_t)(((r * 3 + s) * KT + kt) * NTALL) * 512;
                short8 b0 = *(const short8*)bp;
                short8 b1 = *(const short8*)(bp + 512);
                acc0 = __builtin_amdgcn_mfma_f32_16x16x32_bf16(av, b0, acc0, 0, 0, 0);
                acc1 = __builtin_amdgcn_mfma_f32_16x16x32_bf16(av, b1, acc1, 0, 0, 0);
            }
        }
    }

#pragma unroll
    for (int half = 0; half < 2; ++half) {
        floatx4 a = half ? acc1 : acc0;
        int oc = (ntb + half) * 16 + lm;
        float bs = bias[oc];
#pragma unroll
        for (int i = 0; i < 4; ++i) {
            int px = px0 + q * 4 + i;
            float v = fmaxf(a[i] + bs, 0.f);
            if constexpr (OUTMODE == 0) {
                ((short*)outv)[((size_t)(n * H + y) * W + px) * COUT + oc] = f2bf(v);
            } else if constexpr (OUTMODE == 1) {
                ((short*)outv)[((size_t)(n * Hp + y + 1) * Wp + px + 1) * COUT + oc] = f2bf(v);
            } else {
                ((float*)outv)[((size_t)(n * H + y) * W + px) * COUT + oc] = v;
            }
        }
    }
}

// ---------------- 2x2 maxpool, bf16 NHWC -> padded NHWC ----------------------
__global__ __launch_bounds__(256) void maxpool_nhwc(const ushortT* __restrict__ in,
                                                    ushortT* __restrict__ outp)
{
    int gid = blockIdx.x * 256 + threadIdx.x;   // 131072
    int c8 = gid & 7; int rest = gid >> 3;
    int xo = rest & 63, yo = (rest >> 6) & 63, n = rest >> 12;
    const ushortT* p = in + ((size_t)(n * 128 + yo * 2) * 128 + xo * 2) * 64 + c8 * 8;
    const ushortT* p01 = p + 64;
    const ushortT* p10 = p + 128 * 64;
    const ushortT* p11 = p10 + 64;
    ushortT* o = outp + ((size_t)(n * 66 + yo + 1) * 66 + xo + 1) * 64 + c8 * 8;
#pragma unroll
    for (int j = 0; j < 8; ++j) {
        ushortT a = p[j] > p01[j] ? p[j] : p01[j];
        ushortT b = p10[j] > p11[j] ? p10[j] : p11[j];
        o[j] = a > b ? a : b;
    }
}

// ---------------- BN over NHWC fich: per-block partials ----------------------
__global__ __launch_bounds__(256) void bnsum_nhwc(const float* __restrict__ x,
                                                  float* __restrict__ part)
{
    int tid = threadIdx.x;
    int c = tid & 127;
    int h = tid >> 7;
    int p0 = blockIdx.x * 64 + h * 32;
    float s = 0.f, s2 = 0.f;
    for (int p = p0; p < p0 + 32; ++p) {
        float v = x[(size_t)p * 128 + c];
        s += v; s2 = fmaf(v, v, s2);
    }
    __shared__ float rs[256], rs2[256];
    rs[tid] = s; rs2[tid] = s2;
    __syncthreads();
    if (tid < 128) {
        part[(size_t)blockIdx.x * 256 + tid] = rs[tid] + rs[tid + 128];
        part[(size_t)blockIdx.x * 256 + 128 + tid] = rs2[tid] + rs2[tid + 128];
    }
}

__global__ __launch_bounds__(256) void stats_fin(const float* __restrict__ part,
                                                 float* __restrict__ st)
{
    int c = blockIdx.x;     // 128
    int t = threadIdx.x;    // 256
    float s  = part[(size_t)t * 256 + c];
    float s2 = part[(size_t)t * 256 + 128 + c];
    __shared__ float rs[256], rs2[256];
    rs[t] = s; rs2[t] = s2;
    __syncthreads();
    for (int k = 128; k > 0; k >>= 1) {
        if (t < k) { rs[t] += rs[t + k]; rs2[t] += rs2[t + k]; }
        __syncthreads();
    }
    if (t == 0) {
        float mean = rs[0] * (1.f / 16384.f);
        float var = rs2[0] * (1.f / 16384.f) - mean * mean;
        st[c] = 1.f / sqrtf(var + 1e-5f);
    }
}

// ---------------- modularity on VGG features v5 ------------------------------
__global__ __launch_bounds__(256) void modularity64_v5(
    const float* __restrict__ xt,   // (4,64,64,128) RAW fich
    const float* __restrict__ seg,  // (4,8,128,128) full-res seg
    const float* __restrict__ st,   // [0..127] rstd
    float* __restrict__ part)       // [256][16]
{
    __shared__ float fl[4 * 2880];
    __shared__ float sl[8][12][14];

    int tid = threadIdx.x;
    int w = tid >> 6, lane = tid & 63;
    int tx = lane & 7, ty = lane >> 3;
    int obid = blockIdx.x;
    int bid = obid;
    int bx = bid & 7; bid >>= 3;
    int by = bid & 7; bid >>= 3;
    int n = bid;
    int x0 = bx * 8, y0 = by * 8;

    // stage seg tile with inline 2x2 avgpool (downsample 128 -> 64)
    for (int i = tid; i < 8 * 144; i += 256) {
        int k = i / 144;
        int rem = i - k * 144;
        int r = rem / 12, c = rem - r * 12;
        int y = y0 - 2 + r, x = x0 - 2 + c;
        float v = 0.f;
        if ((unsigned)y < 64u && (unsigned)x < 64u) {
            const float* p = seg + ((size_t)(n * 8 + k) * 128 + 2 * y) * 128 + 2 * x;
            float2 a = *(const float2*)p;
            float2 b = *(const float2*)(p + 128);
            v = 0.25f * ((a.x + a.y) + (b.x + b.y));
        }
        sl[k][r][c] = v;
    }

    float* slab = fl + w * 2880;

    float d2p[25];
#pragma unroll
    for (int di = 0; di < 5; ++di)
#pragma unroll
        for (int dj = 0; dj < 5; ++dj) {
            int y2 = y0 + ty + di - 2, x2 = x0 + tx + dj - 2;
            float bias = ((unsigned)y2 < 64u && (unsigned)x2 < 64u) ? 0.f : 1e30f;
            d2p[di * 5 + dj] = (w == 0) ? bias : 0.f;
        }

    for (int r8 = 0; r8 < 2; ++r8) {
        int ch0 = w * 32 + r8 * 16;
        for (int i = lane; i < 576; i += 64) {
            int pix = i >> 2, q = i & 3;
            int r = pix / 12, c = pix - r * 12;
            int y = y0 - 2 + r, x = x0 - 2 + c;
            float4 v = make_float4(0.f, 0.f, 0.f, 0.f);
            if ((unsigned)y < 64u && (unsigned)x < 64u) {
                v = *(const float4*)&xt[((size_t)((n * 64 + y) * 64 + x)) * 128 + ch0 + q * 4];
                float4 sv = *(const float4*)&st[ch0 + q * 4];
                v.x *= sv.x; v.y *= sv.y; v.z *= sv.z; v.w *= sv.w;
            }
            *(float4*)&slab[(r * 12 + c) * 20 + q * 4] = v;
        }

        const float* ctr = &slab[((ty + 2) * 12 + tx + 2) * 20];
        float4 c0 = *(const float4*)(ctr + 0);
        float4 c1 = *(const float4*)(ctr + 4);
        float4 c2 = *(const float4*)(ctr + 8);
        float4 c3 = *(const float4*)(ctr + 12);
#pragma unroll
        for (int di = 0; di < 5; ++di)
#pragma unroll
            for (int dj = 0; dj < 5; ++dj) {
                const float* np = &slab[((ty + di) * 12 + tx + dj) * 20];
                float4 v0 = *(const float4*)(np + 0);
                float4 v1 = *(const float4*)(np + 4);
                float4 v2 = *(const float4*)(np + 8);
                float4 v3 = *(const float4*)(np + 12);
                float d = d2p[di * 5 + dj];
                float e;
                e = c0.x - v0.x; d = fmaf(e, e, d);
                e = c0.y - v0.y; d = fmaf(e, e, d);
                e = c0.z - v0.z; d = fmaf(e, e, d);
                e = c0.w - v0.w; d = fmaf(e, e, d);
                e = c1.x - v1.x; d = fmaf(e, e, d);
                e = c1.y - v1.y; d = fmaf(e, e, d);
                e = c1.z - v1.z; d = fmaf(e, e, d);
                e = c1.w - v1.w; d = fmaf(e, e, d);
                e = c2.x - v2.x; d = fmaf(e, e, d);
                e = c2.y - v2.y; d = fmaf(e, e, d);
                e = c2.z - v2.z; d = fmaf(e, e, d);
                e = c2.w - v2.w; d = fmaf(e, e, d);
                e = c3.x - v3.x; d = fmaf(e, e, d);
                e = c3.y - v3.y; d = fmaf(e, e, d);
                e = c3.z - v3.z; d = fmaf(e, e, d);
                e = c3.w - v3.w; d = fmaf(e, e, d);
                d2p[di * 5 + dj] = d;
            }
    }

#pragma unroll
    for (int j = 0; j < 25; ++j) slab[lane * 25 + j] = d2p[j];
    __syncthreads();

    const float minus_inv2s2 = -1.0f / (2.0f * 0.02f * 0.02f); // -1250
    for (int i = tid; i < 1600; i += 256) {
        float d = fl[i] + fl[2880 + i] + fl[5760 + i] + fl[8640 + i];
        fl[i] = expf(d * minus_inv2s2);
    }
    __syncthreads();

    float wgt[25];
    float w1 = 0.f;
#pragma unroll
    for (int j = 0; j < 25; ++j) { wgt[j] = fl[lane * 25 + j]; w1 += wgt[j]; }
#pragma unroll
    for (int kk = 0; kk < 2; ++kk) {
        int k = w * 2 + kk;
        float s = 0.f;
#pragma unroll
        for (int di = 0; di < 5; ++di)
#pragma unroll
            for (int dj = 0; dj < 5; ++dj)
                s = fmaf(wgt[di * 5 + dj], sl[k][ty + di][tx + dj], s);
        float sc = sl[k][ty + 2][tx + 2];
        float numk = s * sc;
        float denk = w1 * sc;
#pragma unroll
        for (int sh = 32; sh > 0; sh >>= 1) {
            numk += __shfl_xor(numk, sh, 64);
            denk += __shfl_xor(denk, sh, 64);
        }
        if (lane == 0) {
            part[(size_t)obid * 16 + k * 2] = numk;
            part[(size_t)obid * 16 + k * 2 + 1] = denk;
        }
    }
}

// ---------------- modularity on images v5: img stats computed inline ---------
__global__ __launch_bounds__(64) void modularity128_v5(
    const float* __restrict__ img,  // (4,3,128,128) raw
    const float* __restrict__ pimg, // [192][2] bn partials
    const float* __restrict__ seg,  // (4,8,128,128)
    float* __restrict__ part)       // [1024][16]
{
    __shared__ float il[12][12][4];
    __shared__ float sl[8][12][14];
    __shared__ float stm[6];

    int t = threadIdx.x;
    int tx = t & 7, ty = t >> 3;

    // inline image BN stats from 192 partials (3 wave-reductions)
#pragma unroll
    for (int ch = 0; ch < 3; ++ch) {
        float s  = pimg[(ch * 64 + t) * 2];
        float s2 = pimg[(ch * 64 + t) * 2 + 1];
#pragma unroll
        for (int sh = 32; sh > 0; sh >>= 1) {
            s += __shfl_xor(s, sh, 64);
            s2 += __shfl_xor(s2, sh, 64);
        }
        if (t == 0) {
            float mean = s * (1.f / 65536.f);
            float var = s2 * (1.f / 65536.f) - mean * mean;
            stm[ch] = mean;
            stm[3 + ch] = 1.f / sqrtf(var + 1e-5f);
        }
    }
    __syncthreads();

    int obid = blockIdx.x;
    int bid = obid;                    // n(4) x by(16) x bx(16)
    int bx = bid & 15; bid >>= 4;
    int by = bid & 15; bid >>= 4;
    int n = bid;
    int x0 = bx * 8, y0 = by * 8;

    float mn0 = stm[0], mn1 = stm[1], mn2 = stm[2];
    float rs0 = stm[3], rs1 = stm[4], rs2 = stm[5];

    for (int i = t; i < 432; i += 64) {
        int ch = i / 144; int pix = i - ch * 144;
        int r = pix / 12, c = pix - r * 12;
        int y = y0 - 2 + r, x = x0 - 2 + c;
        float v = 0.f;
        if ((unsigned)y < 128u && (unsigned)x < 128u) {
            float raw = img[(((size_t)(n * 3 + ch)) << 14) + y * 128 + x];
            float mn = ch == 0 ? mn0 : (ch == 1 ? mn1 : mn2);
            float rs = ch == 0 ? rs0 : (ch == 1 ? rs1 : rs2);
            v = (raw - mn) * rs;
        }
        il[r][c][ch] = v;
    }
    for (int i = t; i < 8 * 144; i += 64) {
        int k = i / 144;
        int rem = i - k * 144;
        int r = rem / 12, c = rem - r * 12;
        int y = y0 - 2 + r, x = x0 - 2 + c;
        float v = 0.f;
        if ((unsigned)y < 128u && (unsigned)x < 128u)
            v = seg[((size_t)(n * 8 + k) * 128 + y) * 128 + x];
        sl[k][r][c] = v;
    }
    __syncthreads();

    const float minus_inv2s2 = -1.0f / (2.0f * 0.2f * 0.2f); // -12.5
    float c0 = il[ty + 2][tx + 2][0];
    float c1 = il[ty + 2][tx + 2][1];
    float c2 = il[ty + 2][tx + 2][2];

    float wgt[25];
    float w1 = 0.f;
#pragma unroll
    for (int di = 0; di < 5; ++di)
#pragma unroll
        for (int dj = 0; dj < 5; ++dj) {
            int y2 = y0 + ty + di - 2, x2 = x0 + tx + dj - 2;
            float bias = ((unsigned)y2 < 128u && (unsigned)x2 < 128u) ? 0.f : 1e30f;
            const float* np = &il[ty + di][tx + dj][0];
            float e0 = c0 - np[0], e1 = c1 - np[1], e2 = c2 - np[2];
            float d = bias + fmaf(e2, e2, fmaf(e1, e1, e0 * e0));
            float wv = expf(d * minus_inv2s2);
            wgt[di * 5 + dj] = wv;
            w1 += wv;
        }

#pragma unroll
    for (int k = 0; k < 8; ++k) {
        float s = 0.f;
#pragma unroll
        for (int di = 0; di < 5; ++di)
#pragma unroll
            for (int dj = 0; dj < 5; ++dj)
                s = fmaf(wgt[di * 5 + dj], sl[k][ty + di][tx + dj], s);
        float sc = sl[k][ty + 2][tx + 2];
        float numk = s * sc;
        float denk = w1 * sc;
#pragma unroll
        for (int sft = 32; sft > 0; sft >>= 1) {
            numk += __shfl_xor(numk, sft, 64);
            denk += __shfl_xor(denk, sft, 64);
        }
        if (t == 0) {
            part[(size_t)obid * 16 + k * 2] = numk;
            part[(size_t)obid * 16 + k * 2 + 1] = denk;
        }
    }
}

// ---------------- reduce partials + finalize in one dispatch -----------------
__global__ __launch_bounds__(1024) void reduce_finalize(
    const float* __restrict__ p64, const float* __restrict__ p128,
    float* __restrict__ out)
{
    int t = threadIdx.x;          // 1024
    int j = t >> 4, s = t & 15;   // 64 groups x 16 threads
    float num = 0.f, den = 0.f;
    if (j < 32) {
        int n = j >> 3, k = j & 7;
#pragma unroll
        for (int i = 0; i < 4; ++i) {
            int b = s * 4 + i;
            const float* p = p64 + ((size_t)(n * 64 + b)) * 16 + k * 2;
            num += p[0]; den += p[1];
        }
    } else {
        int jj = j - 32; int n = jj >> 3, k = jj & 7;
#pragma unroll
        for (int i = 0; i < 16; ++i) {
            int b = s * 16 + i;
            const float* p = p128 + ((size_t)(n * 256 + b)) * 16 + k * 2;
            num += p[0]; den += p[1];
        }
    }
#pragma unroll
    for (int sh = 8; sh > 0; sh >>= 1) {
        num += __shfl_xor(num, sh, 16);
        den += __shfl_xor(den, sh, 16);
    }
    __shared__ float rn[64], rd[64];
    if (s == 0) { rn[j] = num; rd[j] = den; }
    __syncthreads();
    if (t < 64) {
        float v = rn[t] / rd[t];
#pragma unroll
        for (int sh = 32; sh > 0; sh >>= 1) v += __shfl_xor(v, sh, 64);
        if (t == 0) out[0] = v * (1.0f / 64.0f);
    }
}

extern "C" void kernel_launch(void* const* d_in, const int* in_sizes, int n_in,
                              void* d_out, int out_size, void* d_ws, size_t ws_size,
                              hipStream_t stream)
{
    const float* images = (const float*)d_in[0];
    const float* seg    = (const float*)d_in[1];
    const float* w1 = (const float*)d_in[2]; const float* b1 = (const float*)d_in[3];
    const float* w2 = (const float*)d_in[4]; const float* b2 = (const float*)d_in[5];
    const float* w3 = (const float*)d_in[6]; const float* b3 = (const float*)d_in[7];
    const float* w4 = (const float*)d_in[8]; const float* b4 = (const float*)d_in[9];
    float* out = (float*)d_out;
    char* ws = (char*)d_ws;
    short* C2   = (short*)(ws + OFF_C2);
    short* PAD2 = (short*)(ws + OFF_PAD2);
    short* PAD3 = (short*)(ws + OFF_PAD3);
    short* PAD4 = (short*)(ws + OFF_PAD4);
    float* FICH = (float*)(ws + OFF_FICH);
    short* WP2  = (short*)(ws + OFF_WP2);
    short* WP3  = (short*)(ws + OFF_WP3);
    short* WP4  = (short*)(ws + OFF_WP4);
    float* ST   = (float*)(ws + OFF_ST);
    float* P64  = (float*)(ws + OFF_P64);
    float* P128 = (float*)(ws + OFF_P128);
    float* PBN  = (float*)(ws + OFF_PBN);
    float* PIMG = (float*)(ws + OFF_PIMG);

    // prologue: pad halos + weight prepack + image BN partials (one launch)
    prologue<<<1362, 256, 0, stream>>>(ws, images, w2, w3, w4);

    // VGG stem
    conv1_bf16<<<2048, 256, 0, stream>>>(images, w1, b1, PAD2);
    conv_mfma<64, 64, 128, 128, 0><<<2048, 256, 0, stream>>>(PAD2, WP2, b2, C2);
    maxpool_nhwc<<<512, 256, 0, stream>>>((const ushortT*)C2, (ushortT*)PAD3);
    conv_mfma<64, 128, 64, 64, 1><<<1024, 256, 0, stream>>>(PAD3, WP3, b3, PAD4);
    conv_mfma<128, 128, 64, 64, 2><<<1024, 256, 0, stream>>>(PAD4, WP4, b4, FICH);

    // fich BN stats (scale applied inside modularity64)
    bnsum_nhwc<<<256, 256, 0, stream>>>(FICH, PBN);
    stats_fin<<<128, 256, 0, stream>>>(PBN, ST);

    // modularity terms -> per-block partials -> single reduce+finalize
    modularity64_v5<<<256, 256, 0, stream>>>(FICH, seg, ST, P64);
    modularity128_v5<<<1024, 64, 0, stream>>>(images, PIMG, seg, P128);
    reduce_finalize<<<1, 1024, 0, stream>>>(P64, P128, out);
}

// Round 16
// 191.556 us; speedup vs baseline: 2.3960x; 1.0897x over previous
//
#include <hip/hip_runtime.h>
#include <hip/hip_bf16.h>
#include <math.h>

typedef __attribute__((ext_vector_type(8))) short short8;
typedef __attribute__((ext_vector_type(4))) float floatx4;
typedef unsigned short ushortT;

__device__ inline short f2bf(float v) {
    __hip_bfloat16 h = __float2bfloat16(v);
    union { __hip_bfloat16 h; short s; } u; u.h = h; return u.s;
}

// ---------------- workspace layout (bytes), all disjoint ----------------
#define OFF_C2    0
#define OFF_PAD4  8388608
#define OFF_FICH  12849152
#define OFF_PAD2  21237760
#define OFF_PAD3  29890560
#define OFF_WP2   32120832
#define OFF_WP3   32194560
#define OFF_WP4   32342016
#define OFF_ST    33947648   // [0..127] rstdF
#define OFF_P64   33951744   // 256 x 16 floats mod64 partials
#define OFF_P128  33968128   // 1024 x 16 floats mod128 partials
#define OFF_PBN   34033664   // 256 x 256 floats fich bnsum partials
#define OFF_PIMG  34295808   // 192 x 2 floats image bn partials

// ---------------- prologue: halo-zero + weight prepack + image bnsum ---------
__global__ __launch_bounds__(256) void prologue(
    char* ws, const float* __restrict__ images,
    const float* __restrict__ w2, const float* __restrict__ w3,
    const float* __restrict__ w4)
{
    int b = blockIdx.x;
    int tid = threadIdx.x;

    if (b < 162) {
        int t = b * 256 + tid;
        short* base; int Hp, Wp, C; int idx;
        if (t < 16512)      { base = (short*)(ws + OFF_PAD2); Hp = 130; Wp = 130; C = 64;  idx = t; }
        else if (t < 24832) { base = (short*)(ws + OFF_PAD3); Hp = 66;  Wp = 66;  C = 64;  idx = t - 16512; }
        else if (t < 41472) { base = (short*)(ws + OFF_PAD4); Hp = 66;  Wp = 66;  C = 128; idx = t - 24832; }
        else return;
        int c8 = idx % (C / 8); int rest = idx / (C / 8);
        int haloPx = 2 * Wp + 2 * (Hp - 2);
        int p = rest % haloPx; int n = rest / haloPx;
        int y, x;
        if (p < Wp)          { y = 0;      x = p; }
        else if (p < 2 * Wp) { y = Hp - 1; x = p - Wp; }
        else { int j = p - 2 * Wp; y = 1 + (j >> 1); x = (j & 1) ? (Wp - 1) : 0; }
        short8 z = {0, 0, 0, 0, 0, 0, 0, 0};
        *(short8*)&base[((size_t)((n * Hp + y) * Wp) + x) * C + c8 * 8] = z;
        return;
    }
    if (b < 1170) {
        int e = (b - 162) * 256 + tid;
        const float* w; short* wp; int CIN, NTALL;
        if (e < 36864)       { w = w2; wp = (short*)(ws + OFF_WP2); CIN = 64;  NTALL = 4; }
        else if (e < 110592) { e -= 36864;  w = w3; wp = (short*)(ws + OFF_WP3); CIN = 64;  NTALL = 8; }
        else if (e < 258048) { e -= 110592; w = w4; wp = (short*)(ws + OFF_WP4); CIN = 128; NTALL = 8; }
        else return;
        int j = e & 7; int L = (e >> 3) & 63; int rest = e >> 9;
        int nt = rest % NTALL; int rest2 = rest / NTALL;
        int KT = CIN / 32;
        int kt = rest2 % KT; int t = rest2 / KT;
        int oc = nt * 16 + (L & 15);
        int ci = kt * 32 + (L >> 4) * 8 + j;
        wp[e] = f2bf(w[((size_t)oc * CIN + ci) * 9 + t]);
        return;
    }
    {
        float* part = (float*)(ws + OFF_PIMG);
        int bb = b - 1170;           // c(3) x chunk(64)
        int c = bb >> 6, chunk = bb & 63;
        int base = chunk * 1024 + tid;
        float s = 0.f, s2 = 0.f;
#pragma unroll
        for (int k = 0; k < 4; ++k) {
            int i = base + k * 256;
            int n = i >> 14, hw = i & 16383;
            float v = images[(((size_t)(n * 3 + c)) << 14) + hw];
            s += v; s2 = fmaf(v, v, s2);
        }
        __shared__ float rs[256], rs2[256];
        rs[tid] = s; rs2[tid] = s2;
        __syncthreads();
        for (int k = 128; k > 0; k >>= 1) {
            if (tid < k) { rs[tid] += rs[tid + k]; rs2[tid] += rs2[tid + k]; }
            __syncthreads();
        }
        if (tid == 0) { part[bb * 2] = rs[0]; part[bb * 2 + 1] = rs2[0]; }
    }
}

// ---------------- conv1: fp32 direct (Cin=3), writes bf16 NHWC padded --------
__global__ __launch_bounds__(256) void conv1_bf16(
    const float* __restrict__ in, const float* __restrict__ w,
    const float* __restrict__ b, short* __restrict__ outp)
{
    int bid = blockIdx.x;                 // 4n x 8ocg x 8ty x 8tx
    int txt = bid & 7; bid >>= 3;
    int tyt = bid & 7; bid >>= 3;
    int ocg = bid & 7; bid >>= 3;
    int n = bid;
    int x0 = txt * 16, y0 = tyt * 16;
    int tid = threadIdx.x;
    int tx = tid & 15, ty = tid >> 4;

    __shared__ float lds[3 * 720];
    for (int i = tid; i < 972; i += 256) {
        int cc = i / 324; int rem = i - cc * 324;
        int r = rem / 18, c = rem - r * 18;
        int y = y0 - 1 + r, x = x0 - 1 + c;
        float v = 0.f;
        if ((unsigned)y < 128u && (unsigned)x < 128u)
            v = in[((size_t)(n * 3 + cc) * 128 + y) * 128 + x];
        lds[cc * 720 + r * 40 + c] = v;
    }
    __syncthreads();

    float acc[8];
#pragma unroll
    for (int oc = 0; oc < 8; ++oc) acc[oc] = 0.f;
    const float* w_g = w + (size_t)(ocg * 8) * 27;
#pragma unroll
    for (int cc = 0; cc < 3; ++cc) {
        const float* base = &lds[cc * 720 + ty * 40 + tx];
        float i00 = base[0],  i01 = base[1],  i02 = base[2];
        float i10 = base[40], i11 = base[41], i12 = base[42];
        float i20 = base[80], i21 = base[81], i22 = base[82];
        const float* wp = w_g + cc * 9;
#pragma unroll
        for (int oc = 0; oc < 8; ++oc) {
            const float* wq = wp + oc * 27;
            float a = acc[oc];
            a = fmaf(wq[0], i00, a); a = fmaf(wq[1], i01, a); a = fmaf(wq[2], i02, a);
            a = fmaf(wq[3], i10, a); a = fmaf(wq[4], i11, a); a = fmaf(wq[5], i12, a);
            a = fmaf(wq[6], i20, a); a = fmaf(wq[7], i21, a); a = fmaf(wq[8], i22, a);
            acc[oc] = a;
        }
    }
    int oy = y0 + ty, ox = x0 + tx;
    short* o = outp + ((size_t)(n * 130 + oy + 1) * 130 + ox + 1) * 64 + ocg * 8;
#pragma unroll
    for (int oc = 0; oc < 8; ++oc) {
        float v = fmaxf(acc[oc] + b[ocg * 8 + oc], 0.f);
        o[oc] = f2bf(v);
    }
}

// ---------------- MFMA implicit-GEMM 3x3 conv v2 -----------------------------
// Wave = 16 px x 64 oc: per tap 1 A-load + 4 B-loads + 4 independent MFMA
// chains (2x compute per A-load vs v1). Block = 4 waves = 64-px strip x 64 oc.
// Grids: conv2 = 1024, conv3/4 = 512.
template<int CIN, int COUT, int H, int W, int OUTMODE>
__global__ __launch_bounds__(256) void conv_mfma2(
    const short* __restrict__ inp, const short* __restrict__ wp,
    const float* __restrict__ bias, void* __restrict__ outv)
{
    constexpr int KT = CIN / 32;
    constexpr int NTALL = COUT / 16;
    constexpr int NTB = COUT / 64;
    constexpr int TPR = W / 64;
    constexpr int Hp = H + 2, Wp = W + 2;

    int bm = blockIdx.x / NTB;
    int bn = blockIdx.x - bm * NTB;
    int n = bm / (H * TPR);
    int rem = bm - n * (H * TPR);
    int y = rem / TPR;
    int x0 = (rem - y * TPR) * 64;

    int tid = threadIdx.x;
    int wv = tid >> 6, lane = tid & 63;
    int lm = lane & 15, q = lane >> 4;
    int px0 = x0 + 16 * wv;
    int ntb = bn * 4;                    // 4 nt tiles per block (64 oc)

    floatx4 acc[4];
#pragma unroll
    for (int t = 0; t < 4; ++t) acc[t] = (floatx4){0.f, 0.f, 0.f, 0.f};

    const short* a_m = inp + lm * CIN + q * 8;
    const short* wbase = wp + ((size_t)ntb * 64 + lane) * 8;

    for (int kt = 0; kt < KT; ++kt) {
        int kofs = kt * 32;
#pragma unroll
        for (int r = 0; r < 3; ++r) {
            const short* arow = a_m + (size_t)((n * Hp + y + r) * Wp + px0) * CIN + kofs;
#pragma unroll
            for (int s = 0; s < 3; ++s) {
                short8 av = *(const short8*)(arow + s * CIN);
                const short* bp = wbase + (size_t)(((r * 3 + s) * KT + kt) * NTALL) * 512;
                short8 b0 = *(const short8*)bp;
                short8 b1 = *(const short8*)(bp + 512);
                short8 b2 = *(const short8*)(bp + 1024);
                short8 b3 = *(const short8*)(bp + 1536);
                acc[0] = __builtin_amdgcn_mfma_f32_16x16x32_bf16(av, b0, acc[0], 0, 0, 0);
                acc[1] = __builtin_amdgcn_mfma_f32_16x16x32_bf16(av, b1, acc[1], 0, 0, 0);
                acc[2] = __builtin_amdgcn_mfma_f32_16x16x32_bf16(av, b2, acc[2], 0, 0, 0);
                acc[3] = __builtin_amdgcn_mfma_f32_16x16x32_bf16(av, b3, acc[3], 0, 0, 0);
            }
        }
    }

#pragma unroll
    for (int t = 0; t < 4; ++t) {
        int oc = (ntb + t) * 16 + lm;
        float bs = bias[oc];
#pragma unroll
        for (int i = 0; i < 4; ++i) {
            int px = px0 + q * 4 + i;
            float v = fmaxf(acc[t][i] + bs, 0.f);
            if constexpr (OUTMODE == 0) {
                ((short*)outv)[((size_t)(n * H + y) * W + px) * COUT + oc] = f2bf(v);
            } else if constexpr (OUTMODE == 1) {
                ((short*)outv)[((size_t)(n * Hp + y + 1) * Wp + px + 1) * COUT + oc] = f2bf(v);
            } else {
                ((float*)outv)[((size_t)(n * H + y) * W + px) * COUT + oc] = v;
            }
        }
    }
}

// ---------------- 2x2 maxpool, bf16 NHWC -> padded NHWC ----------------------
__global__ __launch_bounds__(256) void maxpool_nhwc(const ushortT* __restrict__ in,
                                                    ushortT* __restrict__ outp)
{
    int gid = blockIdx.x * 256 + threadIdx.x;   // 131072
    int c8 = gid & 7; int rest = gid >> 3;
    int xo = rest & 63, yo = (rest >> 6) & 63, n = rest >> 12;
    const ushortT* p = in + ((size_t)(n * 128 + yo * 2) * 128 + xo * 2) * 64 + c8 * 8;
    const ushortT* p01 = p + 64;
    const ushortT* p10 = p + 128 * 64;
    const ushortT* p11 = p10 + 64;
    ushortT* o = outp + ((size_t)(n * 66 + yo + 1) * 66 + xo + 1) * 64 + c8 * 8;
#pragma unroll
    for (int j = 0; j < 8; ++j) {
        ushortT a = p[j] > p01[j] ? p[j] : p01[j];
        ushortT b = p10[j] > p11[j] ? p10[j] : p11[j];
        o[j] = a > b ? a : b;
    }
}

// ---------------- BN over NHWC fich: per-block partials ----------------------
__global__ __launch_bounds__(256) void bnsum_nhwc(const float* __restrict__ x,
                                                  float* __restrict__ part)
{
    int tid = threadIdx.x;
    int c = tid & 127;
    int h = tid >> 7;
    int p0 = blockIdx.x * 64 + h * 32;
    float s = 0.f, s2 = 0.f;
    for (int p = p0; p < p0 + 32; ++p) {
        float v = x[(size_t)p * 128 + c];
        s += v; s2 = fmaf(v, v, s2);
    }
    __shared__ float rs[256], rs2[256];
    rs[tid] = s; rs2[tid] = s2;
    __syncthreads();
    if (tid < 128) {
        part[(size_t)blockIdx.x * 256 + tid] = rs[tid] + rs[tid + 128];
        part[(size_t)blockIdx.x * 256 + 128 + tid] = rs2[tid] + rs2[tid + 128];
    }
}

__global__ __launch_bounds__(256) void stats_fin(const float* __restrict__ part,
                                                 float* __restrict__ st)
{
    int c = blockIdx.x;     // 128
    int t = threadIdx.x;    // 256
    float s  = part[(size_t)t * 256 + c];
    float s2 = part[(size_t)t * 256 + 128 + c];
    __shared__ float rs[256], rs2[256];
    rs[t] = s; rs2[t] = s2;
    __syncthreads();
    for (int k = 128; k > 0; k >>= 1) {
        if (t < k) { rs[t] += rs[t + k]; rs2[t] += rs2[t + k]; }
        __syncthreads();
    }
    if (t == 0) {
        float mean = rs[0] * (1.f / 16384.f);
        float var = rs2[0] * (1.f / 16384.f) - mean * mean;
        st[c] = 1.f / sqrtf(var + 1e-5f);
    }
}

// ---------------- modularity on VGG features v5 ------------------------------
__global__ __launch_bounds__(256) void modularity64_v5(
    const float* __restrict__ xt,   // (4,64,64,128) RAW fich
    const float* __restrict__ seg,  // (4,8,128,128) full-res seg
    const float* __restrict__ st,   // [0..127] rstd
    float* __restrict__ part)       // [256][16]
{
    __shared__ float fl[4 * 2880];
    __shared__ float sl[8][12][14];

    int tid = threadIdx.x;
    int w = tid >> 6, lane = tid & 63;
    int tx = lane & 7, ty = lane >> 3;
    int obid = blockIdx.x;
    int bid = obid;
    int bx = bid & 7; bid >>= 3;
    int by = bid & 7; bid >>= 3;
    int n = bid;
    int x0 = bx * 8, y0 = by * 8;

    // stage seg tile with inline 2x2 avgpool (downsample 128 -> 64)
    for (int i = tid; i < 8 * 144; i += 256) {
        int k = i / 144;
        int rem = i - k * 144;
        int r = rem / 12, c = rem - r * 12;
        int y = y0 - 2 + r, x = x0 - 2 + c;
        float v = 0.f;
        if ((unsigned)y < 64u && (unsigned)x < 64u) {
            const float* p = seg + ((size_t)(n * 8 + k) * 128 + 2 * y) * 128 + 2 * x;
            float2 a = *(const float2*)p;
            float2 b = *(const float2*)(p + 128);
            v = 0.25f * ((a.x + a.y) + (b.x + b.y));
        }
        sl[k][r][c] = v;
    }

    float* slab = fl + w * 2880;

    float d2p[25];
#pragma unroll
    for (int di = 0; di < 5; ++di)
#pragma unroll
        for (int dj = 0; dj < 5; ++dj) {
            int y2 = y0 + ty + di - 2, x2 = x0 + tx + dj - 2;
            float bias = ((unsigned)y2 < 64u && (unsigned)x2 < 64u) ? 0.f : 1e30f;
            d2p[di * 5 + dj] = (w == 0) ? bias : 0.f;
        }

    for (int r8 = 0; r8 < 2; ++r8) {
        int ch0 = w * 32 + r8 * 16;
        for (int i = lane; i < 576; i += 64) {
            int pix = i >> 2, q = i & 3;
            int r = pix / 12, c = pix - r * 12;
            int y = y0 - 2 + r, x = x0 - 2 + c;
            float4 v = make_float4(0.f, 0.f, 0.f, 0.f);
            if ((unsigned)y < 64u && (unsigned)x < 64u) {
                v = *(const float4*)&xt[((size_t)((n * 64 + y) * 64 + x)) * 128 + ch0 + q * 4];
                float4 sv = *(const float4*)&st[ch0 + q * 4];
                v.x *= sv.x; v.y *= sv.y; v.z *= sv.z; v.w *= sv.w;
            }
            *(float4*)&slab[(r * 12 + c) * 20 + q * 4] = v;
        }

        const float* ctr = &slab[((ty + 2) * 12 + tx + 2) * 20];
        float4 c0 = *(const float4*)(ctr + 0);
        float4 c1 = *(const float4*)(ctr + 4);
        float4 c2 = *(const float4*)(ctr + 8);
        float4 c3 = *(const float4*)(ctr + 12);
#pragma unroll
        for (int di = 0; di < 5; ++di)
#pragma unroll
            for (int dj = 0; dj < 5; ++dj) {
                const float* np = &slab[((ty + di) * 12 + tx + dj) * 20];
                float4 v0 = *(const float4*)(np + 0);
                float4 v1 = *(const float4*)(np + 4);
                float4 v2 = *(const float4*)(np + 8);
                float4 v3 = *(const float4*)(np + 12);
                float d = d2p[di * 5 + dj];
                float e;
                e = c0.x - v0.x; d = fmaf(e, e, d);
                e = c0.y - v0.y; d = fmaf(e, e, d);
                e = c0.z - v0.z; d = fmaf(e, e, d);
                e = c0.w - v0.w; d = fmaf(e, e, d);
                e = c1.x - v1.x; d = fmaf(e, e, d);
                e = c1.y - v1.y; d = fmaf(e, e, d);
                e = c1.z - v1.z; d = fmaf(e, e, d);
                e = c1.w - v1.w; d = fmaf(e, e, d);
                e = c2.x - v2.x; d = fmaf(e, e, d);
                e = c2.y - v2.y; d = fmaf(e, e, d);
                e = c2.z - v2.z; d = fmaf(e, e, d);
                e = c2.w - v2.w; d = fmaf(e, e, d);
                e = c3.x - v3.x; d = fmaf(e, e, d);
                e = c3.y - v3.y; d = fmaf(e, e, d);
                e = c3.z - v3.z; d = fmaf(e, e, d);
                e = c3.w - v3.w; d = fmaf(e, e, d);
                d2p[di * 5 + dj] = d;
            }
    }

#pragma unroll
    for (int j = 0; j < 25; ++j) slab[lane * 25 + j] = d2p[j];
    __syncthreads();

    const float minus_inv2s2 = -1.0f / (2.0f * 0.02f * 0.02f); // -1250
    for (int i = tid; i < 1600; i += 256) {
        float d = fl[i] + fl[2880 + i] + fl[5760 + i] + fl[8640 + i];
        fl[i] = expf(d * minus_inv2s2);
    }
    __syncthreads();

    float wgt[25];
    float w1 = 0.f;
#pragma unroll
    for (int j = 0; j < 25; ++j) { wgt[j] = fl[lane * 25 + j]; w1 += wgt[j]; }
#pragma unroll
    for (int kk = 0; kk < 2; ++kk) {
        int k = w * 2 + kk;
        float s = 0.f;
#pragma unroll
        for (int di = 0; di < 5; ++di)
#pragma unroll
            for (int dj = 0; dj < 5; ++dj)
                s = fmaf(wgt[di * 5 + dj], sl[k][ty + di][tx + dj], s);
        float sc = sl[k][ty + 2][tx + 2];
        float numk = s * sc;
        float denk = w1 * sc;
#pragma unroll
        for (int sh = 32; sh > 0; sh >>= 1) {
            numk += __shfl_xor(numk, sh, 64);
            denk += __shfl_xor(denk, sh, 64);
        }
        if (lane == 0) {
            part[(size_t)obid * 16 + k * 2] = numk;
            part[(size_t)obid * 16 + k * 2 + 1] = denk;
        }
    }
}

// ---------------- modularity on images v5: img stats computed inline ---------
__global__ __launch_bounds__(64) void modularity128_v5(
    const float* __restrict__ img,  // (4,3,128,128) raw
    const float* __restrict__ pimg, // [192][2] bn partials
    const float* __restrict__ seg,  // (4,8,128,128)
    float* __restrict__ part)       // [1024][16]
{
    __shared__ float il[12][12][4];
    __shared__ float sl[8][12][14];
    __shared__ float stm[6];

    int t = threadIdx.x;
    int tx = t & 7, ty = t >> 3;

#pragma unroll
    for (int ch = 0; ch < 3; ++ch) {
        float s  = pimg[(ch * 64 + t) * 2];
        float s2 = pimg[(ch * 64 + t) * 2 + 1];
#pragma unroll
        for (int sh = 32; sh > 0; sh >>= 1) {
            s += __shfl_xor(s, sh, 64);
            s2 += __shfl_xor(s2, sh, 64);
        }
        if (t == 0) {
            float mean = s * (1.f / 65536.f);
            float var = s2 * (1.f / 65536.f) - mean * mean;
            stm[ch] = mean;
            stm[3 + ch] = 1.f / sqrtf(var + 1e-5f);
        }
    }
    __syncthreads();

    int obid = blockIdx.x;
    int bid = obid;                    // n(4) x by(16) x bx(16)
    int bx = bid & 15; bid >>= 4;
    int by = bid & 15; bid >>= 4;
    int n = bid;
    int x0 = bx * 8, y0 = by * 8;

    float mn0 = stm[0], mn1 = stm[1], mn2 = stm[2];
    float rs0 = stm[3], rs1 = stm[4], rs2 = stm[5];

    for (int i = t; i < 432; i += 64) {
        int ch = i / 144; int pix = i - ch * 144;
        int r = pix / 12, c = pix - r * 12;
        int y = y0 - 2 + r, x = x0 - 2 + c;
        float v = 0.f;
        if ((unsigned)y < 128u && (unsigned)x < 128u) {
            float raw = img[(((size_t)(n * 3 + ch)) << 14) + y * 128 + x];
            float mn = ch == 0 ? mn0 : (ch == 1 ? mn1 : mn2);
            float rs = ch == 0 ? rs0 : (ch == 1 ? rs1 : rs2);
            v = (raw - mn) * rs;
        }
        il[r][c][ch] = v;
    }
    for (int i = t; i < 8 * 144; i += 64) {
        int k = i / 144;
        int rem = i - k * 144;
        int r = rem / 12, c = rem - r * 12;
        int y = y0 - 2 + r, x = x0 - 2 + c;
        float v = 0.f;
        if ((unsigned)y < 128u && (unsigned)x < 128u)
            v = seg[((size_t)(n * 8 + k) * 128 + y) * 128 + x];
        sl[k][r][c] = v;
    }
    __syncthreads();

    const float minus_inv2s2 = -1.0f / (2.0f * 0.2f * 0.2f); // -12.5
    float c0 = il[ty + 2][tx + 2][0];
    float c1 = il[ty + 2][tx + 2][1];
    float c2 = il[ty + 2][tx + 2][2];

    float wgt[25];
    float w1 = 0.f;
#pragma unroll
    for (int di = 0; di < 5; ++di)
#pragma unroll
        for (int dj = 0; dj < 5; ++dj) {
            int y2 = y0 + ty + di - 2, x2 = x0 + tx + dj - 2;
            float bias = ((unsigned)y2 < 128u && (unsigned)x2 < 128u) ? 0.f : 1e30f;
            const float* np = &il[ty + di][tx + dj][0];
            float e0 = c0 - np[0], e1 = c1 - np[1], e2 = c2 - np[2];
            float d = bias + fmaf(e2, e2, fmaf(e1, e1, e0 * e0));
            float wv = expf(d * minus_inv2s2);
            wgt[di * 5 + dj] = wv;
            w1 += wv;
        }

#pragma unroll
    for (int k = 0; k < 8; ++k) {
        float s = 0.f;
#pragma unroll
        for (int di = 0; di < 5; ++di)
#pragma unroll
            for (int dj = 0; dj < 5; ++dj)
                s = fmaf(wgt[di * 5 + dj], sl[k][ty + di][tx + dj], s);
        float sc = sl[k][ty + 2][tx + 2];
        float numk = s * sc;
        float denk = w1 * sc;
#pragma unroll
        for (int sft = 32; sft > 0; sft >>= 1) {
            numk += __shfl_xor(numk, sft, 64);
            denk += __shfl_xor(denk, sft, 64);
        }
        if (t == 0) {
            part[(size_t)obid * 16 + k * 2] = numk;
            part[(size_t)obid * 16 + k * 2 + 1] = denk;
        }
    }
}

// ---------------- reduce partials + finalize in one dispatch -----------------
__global__ __launch_bounds__(1024) void reduce_finalize(
    const float* __restrict__ p64, const float* __restrict__ p128,
    float* __restrict__ out)
{
    int t = threadIdx.x;          // 1024
    int j = t >> 4, s = t & 15;   // 64 groups x 16 threads
    float num = 0.f, den = 0.f;
    if (j < 32) {
        int n = j >> 3, k = j & 7;
#pragma unroll
        for (int i = 0; i < 4; ++i) {
            int b = s * 4 + i;
            const float* p = p64 + ((size_t)(n * 64 + b)) * 16 + k * 2;
            num += p[0]; den += p[1];
        }
    } else {
        int jj = j - 32; int n = jj >> 3, k = jj & 7;
#pragma unroll
        for (int i = 0; i < 16; ++i) {
            int b = s * 16 + i;
            const float* p = p128 + ((size_t)(n * 256 + b)) * 16 + k * 2;
            num += p[0]; den += p[1];
        }
    }
#pragma unroll
    for (int sh = 8; sh > 0; sh >>= 1) {
        num += __shfl_xor(num, sh, 16);
        den += __shfl_xor(den, sh, 16);
    }
    __shared__ float rn[64], rd[64];
    if (s == 0) { rn[j] = num; rd[j] = den; }
    __syncthreads();
    if (t < 64) {
        float v = rn[t] / rd[t];
#pragma unroll
        for (int sh = 32; sh > 0; sh >>= 1) v += __shfl_xor(v, sh, 64);
        if (t == 0) out[0] = v * (1.0f / 64.0f);
    }
}

extern "C" void kernel_launch(void* const* d_in, const int* in_sizes, int n_in,
                              void* d_out, int out_size, void* d_ws, size_t ws_size,
                              hipStream_t stream)
{
    const float* images = (const float*)d_in[0];
    const float* seg    = (const float*)d_in[1];
    const float* w1 = (const float*)d_in[2]; const float* b1 = (const float*)d_in[3];
    const float* w2 = (const float*)d_in[4]; const float* b2 = (const float*)d_in[5];
    const float* w3 = (const float*)d_in[6]; const float* b3 = (const float*)d_in[7];
    const float* w4 = (const float*)d_in[8]; const float* b4 = (const float*)d_in[9];
    float* out = (float*)d_out;
    char* ws = (char*)d_ws;
    short* C2   = (short*)(ws + OFF_C2);
    short* PAD2 = (short*)(ws + OFF_PAD2);
    short* PAD3 = (short*)(ws + OFF_PAD3);
    short* PAD4 = (short*)(ws + OFF_PAD4);
    float* FICH = (float*)(ws + OFF_FICH);
    short* WP2  = (short*)(ws + OFF_WP2);
    short* WP3  = (short*)(ws + OFF_WP3);
    short* WP4  = (short*)(ws + OFF_WP4);
    float* ST   = (float*)(ws + OFF_ST);
    float* P64  = (float*)(ws + OFF_P64);
    float* P128 = (float*)(ws + OFF_P128);
    float* PBN  = (float*)(ws + OFF_PBN);
    float* PIMG = (float*)(ws + OFF_PIMG);

    // prologue: pad halos + weight prepack + image BN partials (one launch)
    prologue<<<1362, 256, 0, stream>>>(ws, images, w2, w3, w4);

    // VGG stem (conv_mfma2: 64-px strip x 64 oc per block)
    conv1_bf16<<<2048, 256, 0, stream>>>(images, w1, b1, PAD2);
    conv_mfma2<64, 64, 128, 128, 0><<<1024, 256, 0, stream>>>(PAD2, WP2, b2, C2);
    maxpool_nhwc<<<512, 256, 0, stream>>>((const ushortT*)C2, (ushortT*)PAD3);
    conv_mfma2<64, 128, 64, 64, 1><<<512, 256, 0, stream>>>(PAD3, WP3, b3, PAD4);
    conv_mfma2<128, 128, 64, 64, 2><<<512, 256, 0, stream>>>(PAD4, WP4, b4, FICH);

    // fich BN stats (scale applied inside modularity64)
    bnsum_nhwc<<<256, 256, 0, stream>>>(FICH, PBN);
    stats_fin<<<128, 256, 0, stream>>>(PBN, ST);

    // modularity terms -> per-block partials -> single reduce+finalize
    modularity64_v5<<<256, 256, 0, stream>>>(FICH, seg, ST, P64);
    modularity128_v5<<<1024, 64, 0, stream>>>(images, PIMG, seg, P128);
    reduce_finalize<<<1, 1024, 0, stream>>>(P64, P128, out);
}

// Round 17
// 184.068 us; speedup vs baseline: 2.4935x; 1.0407x over previous
//
#include <hip/hip_runtime.h>
#include <hip/hip_bf16.h>
#include <math.h>

typedef __attribute__((ext_vector_type(8))) short short8;
typedef __attribute__((ext_vector_type(4))) float floatx4;
typedef unsigned short ushortT;

__device__ inline short f2bf(float v) {
    __hip_bfloat16 h = __float2bfloat16(v);
    union { __hip_bfloat16 h; short s; } u; u.h = h; return u.s;
}

// ---------------- workspace layout (bytes), all disjoint ----------------
#define OFF_C2    0
#define OFF_PAD4  8388608
#define OFF_FICH  12849152
#define OFF_PAD2  21237760
#define OFF_PAD3  29890560
#define OFF_WP2   32120832
#define OFF_WP3   32194560
#define OFF_WP4   32342016
#define OFF_ST    33947648   // [0..127] rstdF
#define OFF_P64   33951744   // 256 x 16 floats mod64 partials
#define OFF_P128  33968128   // 1024 x 16 floats mod128 partials
#define OFF_PBN   34033664   // 256 x 256 floats fich bnsum partials
#define OFF_PIMG  34295808   // 192 x 2 floats image bn partials

// ---------------- prologue: halo-zero + weight prepack + image bnsum ---------
__global__ __launch_bounds__(256) void prologue(
    char* ws, const float* __restrict__ images,
    const float* __restrict__ w2, const float* __restrict__ w3,
    const float* __restrict__ w4)
{
    int b = blockIdx.x;
    int tid = threadIdx.x;

    if (b < 162) {
        int t = b * 256 + tid;
        short* base; int Hp, Wp, C; int idx;
        if (t < 16512)      { base = (short*)(ws + OFF_PAD2); Hp = 130; Wp = 130; C = 64;  idx = t; }
        else if (t < 24832) { base = (short*)(ws + OFF_PAD3); Hp = 66;  Wp = 66;  C = 64;  idx = t - 16512; }
        else if (t < 41472) { base = (short*)(ws + OFF_PAD4); Hp = 66;  Wp = 66;  C = 128; idx = t - 24832; }
        else return;
        int c8 = idx % (C / 8); int rest = idx / (C / 8);
        int haloPx = 2 * Wp + 2 * (Hp - 2);
        int p = rest % haloPx; int n = rest / haloPx;
        int y, x;
        if (p < Wp)          { y = 0;      x = p; }
        else if (p < 2 * Wp) { y = Hp - 1; x = p - Wp; }
        else { int j = p - 2 * Wp; y = 1 + (j >> 1); x = (j & 1) ? (Wp - 1) : 0; }
        short8 z = {0, 0, 0, 0, 0, 0, 0, 0};
        *(short8*)&base[((size_t)((n * Hp + y) * Wp) + x) * C + c8 * 8] = z;
        return;
    }
    if (b < 1170) {
        int e = (b - 162) * 256 + tid;
        const float* w; short* wp; int CIN, NTALL;
        if (e < 36864)       { w = w2; wp = (short*)(ws + OFF_WP2); CIN = 64;  NTALL = 4; }
        else if (e < 110592) { e -= 36864;  w = w3; wp = (short*)(ws + OFF_WP3); CIN = 64;  NTALL = 8; }
        else if (e < 258048) { e -= 110592; w = w4; wp = (short*)(ws + OFF_WP4); CIN = 128; NTALL = 8; }
        else return;
        int j = e & 7; int L = (e >> 3) & 63; int rest = e >> 9;
        int nt = rest % NTALL; int rest2 = rest / NTALL;
        int KT = CIN / 32;
        int kt = rest2 % KT; int t = rest2 / KT;
        int oc = nt * 16 + (L & 15);
        int ci = kt * 32 + (L >> 4) * 8 + j;
        wp[e] = f2bf(w[((size_t)oc * CIN + ci) * 9 + t]);
        return;
    }
    {
        float* part = (float*)(ws + OFF_PIMG);
        int bb = b - 1170;           // c(3) x chunk(64)
        int c = bb >> 6, chunk = bb & 63;
        int base = chunk * 1024 + tid;
        float s = 0.f, s2 = 0.f;
#pragma unroll
        for (int k = 0; k < 4; ++k) {
            int i = base + k * 256;
            int n = i >> 14, hw = i & 16383;
            float v = images[(((size_t)(n * 3 + c)) << 14) + hw];
            s += v; s2 = fmaf(v, v, s2);
        }
        __shared__ float rs[256], rs2[256];
        rs[tid] = s; rs2[tid] = s2;
        __syncthreads();
        for (int k = 128; k > 0; k >>= 1) {
            if (tid < k) { rs[tid] += rs[tid + k]; rs2[tid] += rs2[tid + k]; }
            __syncthreads();
        }
        if (tid == 0) { part[bb * 2] = rs[0]; part[bb * 2 + 1] = rs2[0]; }
    }
}

// ---------------- conv1: fp32 direct (Cin=3), writes bf16 NHWC padded --------
__global__ __launch_bounds__(256) void conv1_bf16(
    const float* __restrict__ in, const float* __restrict__ w,
    const float* __restrict__ b, short* __restrict__ outp)
{
    int bid = blockIdx.x;                 // 4n x 8ocg x 8ty x 8tx
    int txt = bid & 7; bid >>= 3;
    int tyt = bid & 7; bid >>= 3;
    int ocg = bid & 7; bid >>= 3;
    int n = bid;
    int x0 = txt * 16, y0 = tyt * 16;
    int tid = threadIdx.x;
    int tx = tid & 15, ty = tid >> 4;

    __shared__ float lds[3 * 720];
    for (int i = tid; i < 972; i += 256) {
        int cc = i / 324; int rem = i - cc * 324;
        int r = rem / 18, c = rem - r * 18;
        int y = y0 - 1 + r, x = x0 - 1 + c;
        float v = 0.f;
        if ((unsigned)y < 128u && (unsigned)x < 128u)
            v = in[((size_t)(n * 3 + cc) * 128 + y) * 128 + x];
        lds[cc * 720 + r * 40 + c] = v;
    }
    __syncthreads();

    float acc[8];
#pragma unroll
    for (int oc = 0; oc < 8; ++oc) acc[oc] = 0.f;
    const float* w_g = w + (size_t)(ocg * 8) * 27;
#pragma unroll
    for (int cc = 0; cc < 3; ++cc) {
        const float* base = &lds[cc * 720 + ty * 40 + tx];
        float i00 = base[0],  i01 = base[1],  i02 = base[2];
        float i10 = base[40], i11 = base[41], i12 = base[42];
        float i20 = base[80], i21 = base[81], i22 = base[82];
        const float* wp = w_g + cc * 9;
#pragma unroll
        for (int oc = 0; oc < 8; ++oc) {
            const float* wq = wp + oc * 27;
            float a = acc[oc];
            a = fmaf(wq[0], i00, a); a = fmaf(wq[1], i01, a); a = fmaf(wq[2], i02, a);
            a = fmaf(wq[3], i10, a); a = fmaf(wq[4], i11, a); a = fmaf(wq[5], i12, a);
            a = fmaf(wq[6], i20, a); a = fmaf(wq[7], i21, a); a = fmaf(wq[8], i22, a);
            acc[oc] = a;
        }
    }
    int oy = y0 + ty, ox = x0 + tx;
    short* o = outp + ((size_t)(n * 130 + oy + 1) * 130 + ox + 1) * 64 + ocg * 8;
#pragma unroll
    for (int oc = 0; oc < 8; ++oc) {
        float v = fmaxf(acc[oc] + b[ocg * 8 + oc], 0.f);
        o[oc] = f2bf(v);
    }
}

// ---------------- MFMA implicit-GEMM 3x3 conv v2 -----------------------------
template<int CIN, int COUT, int H, int W, int OUTMODE>
__global__ __launch_bounds__(256) void conv_mfma2(
    const short* __restrict__ inp, const short* __restrict__ wp,
    const float* __restrict__ bias, void* __restrict__ outv)
{
    constexpr int KT = CIN / 32;
    constexpr int NTALL = COUT / 16;
    constexpr int NTB = COUT / 64;
    constexpr int TPR = W / 64;
    constexpr int Hp = H + 2, Wp = W + 2;

    int bm = blockIdx.x / NTB;
    int bn = blockIdx.x - bm * NTB;
    int n = bm / (H * TPR);
    int rem = bm - n * (H * TPR);
    int y = rem / TPR;
    int x0 = (rem - y * TPR) * 64;

    int tid = threadIdx.x;
    int wv = tid >> 6, lane = tid & 63;
    int lm = lane & 15, q = lane >> 4;
    int px0 = x0 + 16 * wv;
    int ntb = bn * 4;

    floatx4 acc[4];
#pragma unroll
    for (int t = 0; t < 4; ++t) acc[t] = (floatx4){0.f, 0.f, 0.f, 0.f};

    const short* a_m = inp + lm * CIN + q * 8;
    const short* wbase = wp + ((size_t)ntb * 64 + lane) * 8;

    for (int kt = 0; kt < KT; ++kt) {
        int kofs = kt * 32;
#pragma unroll
        for (int r = 0; r < 3; ++r) {
            const short* arow = a_m + (size_t)((n * Hp + y + r) * Wp + px0) * CIN + kofs;
#pragma unroll
            for (int s = 0; s < 3; ++s) {
                short8 av = *(const short8*)(arow + s * CIN);
                const short* bp = wbase + (size_t)(((r * 3 + s) * KT + kt) * NTALL) * 512;
                short8 b0 = *(const short8*)bp;
                short8 b1 = *(const short8*)(bp + 512);
                short8 b2 = *(const short8*)(bp + 1024);
                short8 b3 = *(const short8*)(bp + 1536);
                acc[0] = __builtin_amdgcn_mfma_f32_16x16x32_bf16(av, b0, acc[0], 0, 0, 0);
                acc[1] = __builtin_amdgcn_mfma_f32_16x16x32_bf16(av, b1, acc[1], 0, 0, 0);
                acc[2] = __builtin_amdgcn_mfma_f32_16x16x32_bf16(av, b2, acc[2], 0, 0, 0);
                acc[3] = __builtin_amdgcn_mfma_f32_16x16x32_bf16(av, b3, acc[3], 0, 0, 0);
            }
        }
    }

#pragma unroll
    for (int t = 0; t < 4; ++t) {
        int oc = (ntb + t) * 16 + lm;
        float bs = bias[oc];
#pragma unroll
        for (int i = 0; i < 4; ++i) {
            int px = px0 + q * 4 + i;
            float v = fmaxf(acc[t][i] + bs, 0.f);
            if constexpr (OUTMODE == 0) {
                ((short*)outv)[((size_t)(n * H + y) * W + px) * COUT + oc] = f2bf(v);
            } else if constexpr (OUTMODE == 1) {
                ((short*)outv)[((size_t)(n * Hp + y + 1) * Wp + px + 1) * COUT + oc] = f2bf(v);
            } else {
                ((float*)outv)[((size_t)(n * H + y) * W + px) * COUT + oc] = v;
            }
        }
    }
}

// ---------------- 2x2 maxpool, bf16 NHWC -> padded NHWC ----------------------
__global__ __launch_bounds__(256) void maxpool_nhwc(const ushortT* __restrict__ in,
                                                    ushortT* __restrict__ outp)
{
    int gid = blockIdx.x * 256 + threadIdx.x;   // 131072
    int c8 = gid & 7; int rest = gid >> 3;
    int xo = rest & 63, yo = (rest >> 6) & 63, n = rest >> 12;
    const ushortT* p = in + ((size_t)(n * 128 + yo * 2) * 128 + xo * 2) * 64 + c8 * 8;
    const ushortT* p01 = p + 64;
    const ushortT* p10 = p + 128 * 64;
    const ushortT* p11 = p10 + 64;
    ushortT* o = outp + ((size_t)(n * 66 + yo + 1) * 66 + xo + 1) * 64 + c8 * 8;
#pragma unroll
    for (int j = 0; j < 8; ++j) {
        ushortT a = p[j] > p01[j] ? p[j] : p01[j];
        ushortT b = p10[j] > p11[j] ? p10[j] : p11[j];
        o[j] = a > b ? a : b;
    }
}

// ---------------- BN over NHWC fich: per-block partials ----------------------
__global__ __launch_bounds__(256) void bnsum_nhwc(const float* __restrict__ x,
                                                  float* __restrict__ part)
{
    int tid = threadIdx.x;
    int c = tid & 127;
    int h = tid >> 7;
    int p0 = blockIdx.x * 64 + h * 32;
    float s = 0.f, s2 = 0.f;
    for (int p = p0; p < p0 + 32; ++p) {
        float v = x[(size_t)p * 128 + c];
        s += v; s2 = fmaf(v, v, s2);
    }
    __shared__ float rs[256], rs2[256];
    rs[tid] = s; rs2[tid] = s2;
    __syncthreads();
    if (tid < 128) {
        part[(size_t)blockIdx.x * 256 + tid] = rs[tid] + rs[tid + 128];
        part[(size_t)blockIdx.x * 256 + 128 + tid] = rs2[tid] + rs2[tid + 128];
    }
}

__global__ __launch_bounds__(256) void stats_fin(const float* __restrict__ part,
                                                 float* __restrict__ st)
{
    int c = blockIdx.x;     // 128
    int t = threadIdx.x;    // 256
    float s  = part[(size_t)t * 256 + c];
    float s2 = part[(size_t)t * 256 + 128 + c];
    __shared__ float rs[256], rs2[256];
    rs[t] = s; rs2[t] = s2;
    __syncthreads();
    for (int k = 128; k > 0; k >>= 1) {
        if (t < k) { rs[t] += rs[t + k]; rs2[t] += rs2[t + k]; }
        __syncthreads();
    }
    if (t == 0) {
        float mean = rs[0] * (1.f / 16384.f);
        float var = rs2[0] * (1.f / 16384.f) - mean * mean;
        st[c] = 1.f / sqrtf(var + 1e-5f);
    }
}

// ---------------- modularity on VGG features v5 ------------------------------
__global__ __launch_bounds__(256) void modularity64_v5(
    const float* __restrict__ xt,   // (4,64,64,128) RAW fich
    const float* __restrict__ seg,  // (4,8,128,128) full-res seg
    const float* __restrict__ st,   // [0..127] rstd
    float* __restrict__ part)       // [256][16]
{
    __shared__ float fl[4 * 2880];
    __shared__ float sl[8][12][14];

    int tid = threadIdx.x;
    int w = tid >> 6, lane = tid & 63;
    int tx = lane & 7, ty = lane >> 3;
    int obid = blockIdx.x;
    int bid = obid;
    int bx = bid & 7; bid >>= 3;
    int by = bid & 7; bid >>= 3;
    int n = bid;
    int x0 = bx * 8, y0 = by * 8;

    for (int i = tid; i < 8 * 144; i += 256) {
        int k = i / 144;
        int rem = i - k * 144;
        int r = rem / 12, c = rem - r * 12;
        int y = y0 - 2 + r, x = x0 - 2 + c;
        float v = 0.f;
        if ((unsigned)y < 64u && (unsigned)x < 64u) {
            const float* p = seg + ((size_t)(n * 8 + k) * 128 + 2 * y) * 128 + 2 * x;
            float2 a = *(const float2*)p;
            float2 b = *(const float2*)(p + 128);
            v = 0.25f * ((a.x + a.y) + (b.x + b.y));
        }
        sl[k][r][c] = v;
    }

    float* slab = fl + w * 2880;

    float d2p[25];
#pragma unroll
    for (int di = 0; di < 5; ++di)
#pragma unroll
        for (int dj = 0; dj < 5; ++dj) {
            int y2 = y0 + ty + di - 2, x2 = x0 + tx + dj - 2;
            float bias = ((unsigned)y2 < 64u && (unsigned)x2 < 64u) ? 0.f : 1e30f;
            d2p[di * 5 + dj] = (w == 0) ? bias : 0.f;
        }

    for (int r8 = 0; r8 < 2; ++r8) {
        int ch0 = w * 32 + r8 * 16;
        for (int i = lane; i < 576; i += 64) {
            int pix = i >> 2, q = i & 3;
            int r = pix / 12, c = pix - r * 12;
            int y = y0 - 2 + r, x = x0 - 2 + c;
            float4 v = make_float4(0.f, 0.f, 0.f, 0.f);
            if ((unsigned)y < 64u && (unsigned)x < 64u) {
                v = *(const float4*)&xt[((size_t)((n * 64 + y) * 64 + x)) * 128 + ch0 + q * 4];
                float4 sv = *(const float4*)&st[ch0 + q * 4];
                v.x *= sv.x; v.y *= sv.y; v.z *= sv.z; v.w *= sv.w;
            }
            *(float4*)&slab[(r * 12 + c) * 20 + q * 4] = v;
        }

        const float* ctr = &slab[((ty + 2) * 12 + tx + 2) * 20];
        float4 c0 = *(const float4*)(ctr + 0);
        float4 c1 = *(const float4*)(ctr + 4);
        float4 c2 = *(const float4*)(ctr + 8);
        float4 c3 = *(const float4*)(ctr + 12);
#pragma unroll
        for (int di = 0; di < 5; ++di)
#pragma unroll
            for (int dj = 0; dj < 5; ++dj) {
                const float* np = &slab[((ty + di) * 12 + tx + dj) * 20];
                float4 v0 = *(const float4*)(np + 0);
                float4 v1 = *(const float4*)(np + 4);
                float4 v2 = *(const float4*)(np + 8);
                float4 v3 = *(const float4*)(np + 12);
                float d = d2p[di * 5 + dj];
                float e;
                e = c0.x - v0.x; d = fmaf(e, e, d);
                e = c0.y - v0.y; d = fmaf(e, e, d);
                e = c0.z - v0.z; d = fmaf(e, e, d);
                e = c0.w - v0.w; d = fmaf(e, e, d);
                e = c1.x - v1.x; d = fmaf(e, e, d);
                e = c1.y - v1.y; d = fmaf(e, e, d);
                e = c1.z - v1.z; d = fmaf(e, e, d);
                e = c1.w - v1.w; d = fmaf(e, e, d);
                e = c2.x - v2.x; d = fmaf(e, e, d);
                e = c2.y - v2.y; d = fmaf(e, e, d);
                e = c2.z - v2.z; d = fmaf(e, e, d);
                e = c2.w - v2.w; d = fmaf(e, e, d);
                e = c3.x - v3.x; d = fmaf(e, e, d);
                e = c3.y - v3.y; d = fmaf(e, e, d);
                e = c3.z - v3.z; d = fmaf(e, e, d);
                e = c3.w - v3.w; d = fmaf(e, e, d);
                d2p[di * 5 + dj] = d;
            }
    }

#pragma unroll
    for (int j = 0; j < 25; ++j) slab[lane * 25 + j] = d2p[j];
    __syncthreads();

    const float minus_inv2s2 = -1.0f / (2.0f * 0.02f * 0.02f); // -1250
    for (int i = tid; i < 1600; i += 256) {
        float d = fl[i] + fl[2880 + i] + fl[5760 + i] + fl[8640 + i];
        fl[i] = expf(d * minus_inv2s2);
    }
    __syncthreads();

    float wgt[25];
    float w1 = 0.f;
#pragma unroll
    for (int j = 0; j < 25; ++j) { wgt[j] = fl[lane * 25 + j]; w1 += wgt[j]; }
#pragma unroll
    for (int kk = 0; kk < 2; ++kk) {
        int k = w * 2 + kk;
        float s = 0.f;
#pragma unroll
        for (int di = 0; di < 5; ++di)
#pragma unroll
            for (int dj = 0; dj < 5; ++dj)
                s = fmaf(wgt[di * 5 + dj], sl[k][ty + di][tx + dj], s);
        float sc = sl[k][ty + 2][tx + 2];
        float numk = s * sc;
        float denk = w1 * sc;
#pragma unroll
        for (int sh = 32; sh > 0; sh >>= 1) {
            numk += __shfl_xor(numk, sh, 64);
            denk += __shfl_xor(denk, sh, 64);
        }
        if (lane == 0) {
            part[(size_t)obid * 16 + k * 2] = numk;
            part[(size_t)obid * 16 + k * 2 + 1] = denk;
        }
    }
}

// ---------------- modularity on images v6: 256 thr, class-split waves --------
// All 4 waves cooperatively stage il/sl; each thread (lane = pixel) computes
// its 25 weights redundantly per wave; wave w reduces classes 2w, 2w+1.
// 16 waves/CU vs v5's 4.
__global__ __launch_bounds__(256) void modularity128_v6(
    const float* __restrict__ img,  // (4,3,128,128) raw
    const float* __restrict__ pimg, // [192][2] bn partials
    const float* __restrict__ seg,  // (4,8,128,128)
    float* __restrict__ part)       // [1024][16]
{
    __shared__ float il[12][12][4];
    __shared__ float sl[8][12][14];
    __shared__ float stm[6];

    int t = threadIdx.x;            // 256
    int w = t >> 6, lane = t & 63;
    int tx = lane & 7, ty = lane >> 3;

    // image BN stats from 192 partials (wave 0 only)
    if (t < 64) {
#pragma unroll
        for (int ch = 0; ch < 3; ++ch) {
            float s  = pimg[(ch * 64 + t) * 2];
            float s2 = pimg[(ch * 64 + t) * 2 + 1];
#pragma unroll
            for (int sh = 32; sh > 0; sh >>= 1) {
                s += __shfl_xor(s, sh, 64);
                s2 += __shfl_xor(s2, sh, 64);
            }
            if (t == 0) {
                float mean = s * (1.f / 65536.f);
                float var = s2 * (1.f / 65536.f) - mean * mean;
                stm[ch] = mean;
                stm[3 + ch] = 1.f / sqrtf(var + 1e-5f);
            }
        }
    }

    int obid = blockIdx.x;
    int bid = obid;                    // n(4) x by(16) x bx(16)
    int bx = bid & 15; bid >>= 4;
    int by = bid & 15; bid >>= 4;
    int n = bid;
    int x0 = bx * 8, y0 = by * 8;

    // stage seg tile with all 256 threads (no dependence on stm)
    for (int i = t; i < 8 * 144; i += 256) {
        int k = i / 144;
        int rem = i - k * 144;
        int r = rem / 12, c = rem - r * 12;
        int y = y0 - 2 + r, x = x0 - 2 + c;
        float v = 0.f;
        if ((unsigned)y < 128u && (unsigned)x < 128u)
            v = seg[((size_t)(n * 8 + k) * 128 + y) * 128 + x];
        sl[k][r][c] = v;
    }
    __syncthreads();   // stm ready

    float mn0 = stm[0], mn1 = stm[1], mn2 = stm[2];
    float rs0 = stm[3], rs1 = stm[4], rs2 = stm[5];

    // stage il with all 256 threads (432 elems)
    for (int i = t; i < 432; i += 256) {
        int ch = i / 144; int pix = i - ch * 144;
        int r = pix / 12, c = pix - r * 12;
        int y = y0 - 2 + r, x = x0 - 2 + c;
        float v = 0.f;
        if ((unsigned)y < 128u && (unsigned)x < 128u) {
            float raw = img[(((size_t)(n * 3 + ch)) << 14) + y * 128 + x];
            float mn = ch == 0 ? mn0 : (ch == 1 ? mn1 : mn2);
            float rs = ch == 0 ? rs0 : (ch == 1 ? rs1 : rs2);
            v = (raw - mn) * rs;
        }
        il[r][c][ch] = v;
    }
    __syncthreads();

    const float minus_inv2s2 = -1.0f / (2.0f * 0.2f * 0.2f); // -12.5
    float c0 = il[ty + 2][tx + 2][0];
    float c1 = il[ty + 2][tx + 2][1];
    float c2 = il[ty + 2][tx + 2][2];

    float wgt[25];
    float w1 = 0.f;
#pragma unroll
    for (int di = 0; di < 5; ++di)
#pragma unroll
        for (int dj = 0; dj < 5; ++dj) {
            int y2 = y0 + ty + di - 2, x2 = x0 + tx + dj - 2;
            float bias = ((unsigned)y2 < 128u && (unsigned)x2 < 128u) ? 0.f : 1e30f;
            const float* np = &il[ty + di][tx + dj][0];
            float e0 = c0 - np[0], e1 = c1 - np[1], e2 = c2 - np[2];
            float d = bias + fmaf(e2, e2, fmaf(e1, e1, e0 * e0));
            float wv = expf(d * minus_inv2s2);
            wgt[di * 5 + dj] = wv;
            w1 += wv;
        }

    // wave w reduces classes 2w, 2w+1
#pragma unroll
    for (int kk = 0; kk < 2; ++kk) {
        int k = w * 2 + kk;
        float s = 0.f;
#pragma unroll
        for (int di = 0; di < 5; ++di)
#pragma unroll
            for (int dj = 0; dj < 5; ++dj)
                s = fmaf(wgt[di * 5 + dj], sl[k][ty + di][tx + dj], s);
        float sc = sl[k][ty + 2][tx + 2];
        float numk = s * sc;
        float denk = w1 * sc;
#pragma unroll
        for (int sft = 32; sft > 0; sft >>= 1) {
            numk += __shfl_xor(numk, sft, 64);
            denk += __shfl_xor(denk, sft, 64);
        }
        if (lane == 0) {
            part[(size_t)obid * 16 + k * 2] = numk;
            part[(size_t)obid * 16 + k * 2 + 1] = denk;
        }
    }
}

// ---------------- reduce partials + finalize in one dispatch -----------------
__global__ __launch_bounds__(1024) void reduce_finalize(
    const float* __restrict__ p64, const float* __restrict__ p128,
    float* __restrict__ out)
{
    int t = threadIdx.x;          // 1024
    int j = t >> 4, s = t & 15;   // 64 groups x 16 threads
    float num = 0.f, den = 0.f;
    if (j < 32) {
        int n = j >> 3, k = j & 7;
#pragma unroll
        for (int i = 0; i < 4; ++i) {
            int b = s * 4 + i;
            const float* p = p64 + ((size_t)(n * 64 + b)) * 16 + k * 2;
            num += p[0]; den += p[1];
        }
    } else {
        int jj = j - 32; int n = jj >> 3, k = jj & 7;
#pragma unroll
        for (int i = 0; i < 16; ++i) {
            int b = s * 16 + i;
            const float* p = p128 + ((size_t)(n * 256 + b)) * 16 + k * 2;
            num += p[0]; den += p[1];
        }
    }
#pragma unroll
    for (int sh = 8; sh > 0; sh >>= 1) {
        num += __shfl_xor(num, sh, 16);
        den += __shfl_xor(den, sh, 16);
    }
    __shared__ float rn[64], rd[64];
    if (s == 0) { rn[j] = num; rd[j] = den; }
    __syncthreads();
    if (t < 64) {
        float v = rn[t] / rd[t];
#pragma unroll
        for (int sh = 32; sh > 0; sh >>= 1) v += __shfl_xor(v, sh, 64);
        if (t == 0) out[0] = v * (1.0f / 64.0f);
    }
}

extern "C" void kernel_launch(void* const* d_in, const int* in_sizes, int n_in,
                              void* d_out, int out_size, void* d_ws, size_t ws_size,
                              hipStream_t stream)
{
    const float* images = (const float*)d_in[0];
    const float* seg    = (const float*)d_in[1];
    const float* w1 = (const float*)d_in[2]; const float* b1 = (const float*)d_in[3];
    const float* w2 = (const float*)d_in[4]; const float* b2 = (const float*)d_in[5];
    const float* w3 = (const float*)d_in[6]; const float* b3 = (const float*)d_in[7];
    const float* w4 = (const float*)d_in[8]; const float* b4 = (const float*)d_in[9];
    float* out = (float*)d_out;
    char* ws = (char*)d_ws;
    short* C2   = (short*)(ws + OFF_C2);
    short* PAD2 = (short*)(ws + OFF_PAD2);
    short* PAD3 = (short*)(ws + OFF_PAD3);
    short* PAD4 = (short*)(ws + OFF_PAD4);
    float* FICH = (float*)(ws + OFF_FICH);
    short* WP2  = (short*)(ws + OFF_WP2);
    short* WP3  = (short*)(ws + OFF_WP3);
    short* WP4  = (short*)(ws + OFF_WP4);
    float* ST   = (float*)(ws + OFF_ST);
    float* P64  = (float*)(ws + OFF_P64);
    float* P128 = (float*)(ws + OFF_P128);
    float* PBN  = (float*)(ws + OFF_PBN);
    float* PIMG = (float*)(ws + OFF_PIMG);

    // prologue: pad halos + weight prepack + image BN partials (one launch)
    prologue<<<1362, 256, 0, stream>>>(ws, images, w2, w3, w4);

    // VGG stem
    conv1_bf16<<<2048, 256, 0, stream>>>(images, w1, b1, PAD2);
    conv_mfma2<64, 64, 128, 128, 0><<<1024, 256, 0, stream>>>(PAD2, WP2, b2, C2);
    maxpool_nhwc<<<512, 256, 0, stream>>>((const ushortT*)C2, (ushortT*)PAD3);
    conv_mfma2<64, 128, 64, 64, 1><<<512, 256, 0, stream>>>(PAD3, WP3, b3, PAD4);
    conv_mfma2<128, 128, 64, 64, 2><<<512, 256, 0, stream>>>(PAD4, WP4, b4, FICH);

    // fich BN stats (scale applied inside modularity64)
    bnsum_nhwc<<<256, 256, 0, stream>>>(FICH, PBN);
    stats_fin<<<128, 256, 0, stream>>>(PBN, ST);

    // modularity terms -> per-block partials -> single reduce+finalize
    modularity64_v5<<<256, 256, 0, stream>>>(FICH, seg, ST, P64);
    modularity128_v6<<<1024, 256, 0, stream>>>(images, PIMG, seg, P128);
    reduce_finalize<<<1, 1024, 0, stream>>>(P64, P128, out);
}